// Round 1
// baseline (699.497 us; speedup 1.0000x reference)
//
#include <hip/hip_runtime.h>
#include <hip/hip_bf16.h>
#include <cstdint>
#include <cstddef>

#define NN 50000
#define NE 500000
#define GD 256
#define H1 128
#define H2 128
#define NREL 8
#define NBASES 30
#define XRLD (NREL * H1)   // 1024
#define NCHUNKS ((NN + 1023) / 1024)  // 49

__device__ __forceinline__ float lrelu(float x) { return x > 0.f ? x : 0.2f * x; }

// ---- K1: wrb[k][r*128+o] = sum_b comp[r][b] * basis[b][k][o] ----
__global__ void k_wr(const float* __restrict__ basis, const float* __restrict__ comp,
                     float* __restrict__ wrb) {
  int idx = blockIdx.x * 256 + threadIdx.x;   // 256*1024 total
  int k = idx >> 10;
  int c = idx & 1023;
  int r = c >> 7, o = c & 127;
  float acc = 0.f;
  #pragma unroll
  for (int b = 0; b < NBASES; b++)
    acc += comp[r * NBASES + b] * basis[((size_t)b * GD + k) * H1 + o];
  wrb[idx] = acc;
}

// ---- generic fp32 tiled GEMM: C[M][N] = A[M][K] @ B[K][N] (+ addend + bias) ----
// Requires: N % 128 == 0, K % 16 == 0. M arbitrary.
__global__ __launch_bounds__(256)
void k_gemm(const float* __restrict__ A, const float* __restrict__ B,
            float* __restrict__ C, const float* __restrict__ addend,
            const float* __restrict__ bias, int M, int N, int K) {
  __shared__ float As[16][128];   // transposed A tile: As[k][m]
  __shared__ float Bs[16][128];
  const int tid = threadIdx.x;
  const int tx = tid & 15;        // col group
  const int ty = tid >> 4;        // row group
  const int row0 = blockIdx.y * 128;
  const int col0 = blockIdx.x * 128;

  float acc[8][8];
  #pragma unroll
  for (int i = 0; i < 8; i++)
    #pragma unroll
    for (int j = 0; j < 8; j++) acc[i][j] = 0.f;

  const int ar = tid >> 1, ak = (tid & 1) * 8;   // A: row ar, cols ak..ak+7
  const int br = tid >> 4, bc = (tid & 15) * 8;  // B: row br, cols bc..bc+7

  for (int k0 = 0; k0 < K; k0 += 16) {
    int gm = row0 + ar;
    float4 a0, a1;
    if (gm < M) {
      const float* ap = A + (size_t)gm * K + k0 + ak;
      a0 = *(const float4*)ap;
      a1 = *(const float4*)(ap + 4);
    } else {
      a0 = make_float4(0.f, 0.f, 0.f, 0.f);
      a1 = a0;
    }
    As[ak + 0][ar] = a0.x; As[ak + 1][ar] = a0.y;
    As[ak + 2][ar] = a0.z; As[ak + 3][ar] = a0.w;
    As[ak + 4][ar] = a1.x; As[ak + 5][ar] = a1.y;
    As[ak + 6][ar] = a1.z; As[ak + 7][ar] = a1.w;

    const float* bp = B + (size_t)(k0 + br) * N + col0 + bc;
    *(float4*)&Bs[br][bc] = *(const float4*)bp;
    *(float4*)&Bs[br][bc + 4] = *(const float4*)(bp + 4);

    __syncthreads();
    #pragma unroll
    for (int kk = 0; kk < 16; kk++) {
      float a[8], b[8];
      float4 t0 = *(const float4*)&As[kk][ty * 8];
      float4 t1 = *(const float4*)&As[kk][ty * 8 + 4];
      a[0] = t0.x; a[1] = t0.y; a[2] = t0.z; a[3] = t0.w;
      a[4] = t1.x; a[5] = t1.y; a[6] = t1.z; a[7] = t1.w;
      float4 u0 = *(const float4*)&Bs[kk][tx * 4];
      float4 u1 = *(const float4*)&Bs[kk][tx * 4 + 64];
      b[0] = u0.x; b[1] = u0.y; b[2] = u0.z; b[3] = u0.w;
      b[4] = u1.x; b[5] = u1.y; b[6] = u1.z; b[7] = u1.w;
      #pragma unroll
      for (int i = 0; i < 8; i++)
        #pragma unroll
        for (int j = 0; j < 8; j++) acc[i][j] += a[i] * b[j];
    }
    __syncthreads();
  }

  const int ca = col0 + tx * 4, cb = ca + 64;
  #pragma unroll
  for (int i = 0; i < 8; i++) {
    int gm = row0 + ty * 8 + i;
    if (gm < M) {
      size_t base = (size_t)gm * N;
      float4 va = make_float4(acc[i][0], acc[i][1], acc[i][2], acc[i][3]);
      float4 vb = make_float4(acc[i][4], acc[i][5], acc[i][6], acc[i][7]);
      if (addend) {
        float4 xa = *(const float4*)(addend + base + ca);
        float4 xb = *(const float4*)(addend + base + cb);
        va.x += xa.x; va.y += xa.y; va.z += xa.z; va.w += xa.w;
        vb.x += xb.x; vb.y += xb.y; vb.z += xb.z; vb.w += xb.w;
      }
      if (bias) {
        float4 xa = *(const float4*)(bias + ca);
        float4 xb = *(const float4*)(bias + cb);
        va.x += xa.x; va.y += xa.y; va.z += xa.z; va.w += xa.w;
        vb.x += xb.x; vb.y += xb.y; vb.z += xb.z; vb.w += xb.w;
      }
      *(float4*)&C[base + ca] = va;
      *(float4*)&C[base + cb] = vb;
    }
  }
}

// ---- CSR build ----
__global__ void k_deg(const int* __restrict__ ei, int* __restrict__ deg) {
  int e = blockIdx.x * 256 + threadIdx.x;
  if (e < NE) atomicAdd(&deg[ei[NE + e]], 1);
}

__global__ void k_scan_a(const int* __restrict__ deg, int* __restrict__ parts) {
  __shared__ int lds[256];
  int t = threadIdx.x;
  int base = blockIdx.x * 1024 + t * 4;
  int s = 0;
  #pragma unroll
  for (int j = 0; j < 4; j++) s += (base + j < NN) ? deg[base + j] : 0;
  lds[t] = s;
  __syncthreads();
  for (int st = 128; st > 0; st >>= 1) {
    if (t < st) lds[t] += lds[t + st];
    __syncthreads();
  }
  if (t == 0) parts[blockIdx.x] = lds[0];
}

__global__ void k_scan_b(int* __restrict__ parts) {
  if (threadIdx.x == 0) {
    int run = 0;
    for (int i = 0; i < NCHUNKS; i++) { int v = parts[i]; parts[i] = run; run += v; }
  }
}

__global__ void k_scan_c(const int* __restrict__ deg, const int* __restrict__ parts,
                         int* __restrict__ rowptr) {
  __shared__ int lds[256];
  int t = threadIdx.x;
  int base = blockIdx.x * 1024 + t * 4;
  int v[4];
  int s = 0;
  #pragma unroll
  for (int j = 0; j < 4; j++) { v[j] = (base + j < NN) ? deg[base + j] : 0; s += v[j]; }
  lds[t] = s;
  __syncthreads();
  for (int st = 1; st < 256; st <<= 1) {
    int add = (t >= st) ? lds[t - st] : 0;
    __syncthreads();
    lds[t] += add;
    __syncthreads();
  }
  int excl = lds[t] - s;
  int off = parts[blockIdx.x];
  int run = 0;
  #pragma unroll
  for (int j = 0; j < 4; j++) {
    run += v[j];
    if (base + j < NN) rowptr[base + j + 1] = off + excl + run;
  }
  if (blockIdx.x == 0 && t == 0) rowptr[0] = 0;
}

__global__ void k_scatter(const int* __restrict__ ei, const int* __restrict__ rowptr,
                          int* __restrict__ cursor, int* __restrict__ csr) {
  int e = blockIdx.x * 256 + threadIdx.x;
  if (e < NE) {
    int d = ei[NE + e];
    int pos = atomicAdd(&cursor[d], 1);
    csr[rowptr[d] + pos] = e;
  }
}

// ---- RGCN aggregation: one wave per dst ----
__global__ __launch_bounds__(256)
void k_rgcn(const float* __restrict__ xr, const int* __restrict__ ei,
            const int* __restrict__ et, const int* __restrict__ rowptr,
            const int* __restrict__ csr, float* __restrict__ agg) {
  int wid = (blockIdx.x * 256 + threadIdx.x) >> 6;
  int lane = threadIdx.x & 63;
  if (wid >= NN) return;
  int c0 = lane * 2;
  float acc0[NREL], acc1[NREL], cnt[NREL];
  #pragma unroll
  for (int r = 0; r < NREL; r++) { acc0[r] = 0.f; acc1[r] = 0.f; cnt[r] = 0.f; }
  int beg = rowptr[wid], end = rowptr[wid + 1];
  for (int j = beg; j < end; j++) {
    int e = csr[j];
    int s = ei[e];
    int r = et[e];
    float2 v = *(const float2*)(xr + (size_t)s * XRLD + r * H1 + c0);
    #pragma unroll
    for (int rr = 0; rr < NREL; rr++) {
      if (r == rr) { acc0[rr] += v.x; acc1[rr] += v.y; cnt[rr] += 1.f; }
    }
  }
  float o0 = 0.f, o1 = 0.f;
  #pragma unroll
  for (int rr = 0; rr < NREL; rr++) {
    float inv = 1.f / fmaxf(cnt[rr], 1.f);
    o0 += acc0[rr] * inv;
    o1 += acc1[rr] * inv;
  }
  agg[(size_t)wid * H1 + c0] = o0;
  agg[(size_t)wid * H1 + c0 + 1] = o1;
}

// ---- wcat[k][0:128]=w_l[k], wcat[k][128:256]=w_r[k] ----
__global__ void k_wcat(const float* __restrict__ w_l, const float* __restrict__ w_r,
                       float* __restrict__ wcat) {
  int idx = blockIdx.x * 256 + threadIdx.x;   // 128*256
  int k = idx >> 8;
  int o = idx & 255;
  wcat[idx] = (o < H2) ? w_l[k * H2 + o] : w_r[k * H2 + (o - H2)];
}

// ---- GATv2: one wave per dst, online softmax incl. self loop ----
__global__ __launch_bounds__(256)
void k_gat(const float* __restrict__ xlr, const int* __restrict__ ei,
           const int* __restrict__ rowptr, const int* __restrict__ csr,
           const float* __restrict__ att, const float* __restrict__ bias2,
           float* __restrict__ out) {
  int wid = (blockIdx.x * 256 + threadIdx.x) >> 6;
  int lane = threadIdx.x & 63;
  if (wid >= NN) return;
  int c0 = lane * 2;
  float att0 = att[c0], att1 = att[c0 + 1];
  float2 xrt = *(const float2*)(xlr + (size_t)wid * 256 + 128 + c0);
  // self loop first
  float2 v = *(const float2*)(xlr + (size_t)wid * 256 + c0);
  float ep = lrelu(v.x + xrt.x) * att0 + lrelu(v.y + xrt.y) * att1;
  #pragma unroll
  for (int off = 32; off > 0; off >>= 1) ep += __shfl_xor(ep, off, 64);
  float m = ep, s = 1.f, a0 = v.x, a1 = v.y;
  int beg = rowptr[wid], end = rowptr[wid + 1];
  for (int j = beg; j < end; j++) {
    int e = csr[j];
    int src = ei[e];
    float2 u = *(const float2*)(xlr + (size_t)src * 256 + c0);
    float p = lrelu(u.x + xrt.x) * att0 + lrelu(u.y + xrt.y) * att1;
    #pragma unroll
    for (int off = 32; off > 0; off >>= 1) p += __shfl_xor(p, off, 64);
    float mn = fmaxf(m, p);
    float sc = __expf(m - mn), w = __expf(p - mn);
    s = s * sc + w;
    a0 = a0 * sc + w * u.x;
    a1 = a1 * sc + w * u.y;
    m = mn;
  }
  float inv = 1.f / s;
  out[(size_t)wid * H1 + c0] = a0 * inv + bias2[c0];
  out[(size_t)wid * H1 + c0 + 1] = a1 * inv + bias2[c0 + 1];
}

extern "C" void kernel_launch(void* const* d_in, const int* in_sizes, int n_in,
                              void* d_out, int out_size, void* d_ws, size_t ws_size,
                              hipStream_t stream) {
  const float* nf    = (const float*)d_in[0];
  const int*   ei    = (const int*)d_in[1];   // [2][E]: src row then dst row
  const int*   et    = (const int*)d_in[3];
  const float* basis = (const float*)d_in[4];
  const float* comp  = (const float*)d_in[5];
  const float* root  = (const float*)d_in[6];
  const float* bias1 = (const float*)d_in[7];
  const float* w_l   = (const float*)d_in[8];
  const float* w_r   = (const float*)d_in[9];
  const float* att   = (const float*)d_in[10];
  const float* bias2 = (const float*)d_in[11];
  float* out = (float*)d_out;

  // workspace layout (~234 MB)
  float* xr   = (float*)d_ws;                       // [NN][1024]
  float* wrb  = xr + (size_t)NN * XRLD;             // [256][1024]
  float* agg  = wrb + (size_t)GD * XRLD;            // [NN][128]
  float* wcat = agg + (size_t)NN * H1;              // [128][256]
  int*   deg    = (int*)(wcat + H1 * 2 * H2);       // [NN]
  int*   cursor = deg + NN;                         // [NN]
  int*   rowptr = cursor + NN;                      // [NN+1]
  int*   csr    = rowptr + (NN + 1);                // [NE]
  int*   parts  = csr + NE;                         // [NCHUNKS]
  // reuse xr region once it is dead (after k_rgcn)
  float* x1  = xr;                                  // [NN][128]
  float* xlr = xr + (size_t)NN * H1;                // [NN][256] = [xl|xrt]

  hipMemsetAsync(deg, 0, 2 * NN * sizeof(int), stream);  // deg + cursor

  k_wr<<<(GD * XRLD) / 256, 256, 0, stream>>>(basis, comp, wrb);

  dim3 g2(XRLD / 128, (NN + 127) / 128);
  k_gemm<<<g2, 256, 0, stream>>>(nf, wrb, xr, nullptr, nullptr, NN, XRLD, GD);

  k_deg<<<(NE + 255) / 256, 256, 0, stream>>>(ei, deg);
  k_scan_a<<<NCHUNKS, 256, 0, stream>>>(deg, parts);
  k_scan_b<<<1, 64, 0, stream>>>(parts);
  k_scan_c<<<NCHUNKS, 256, 0, stream>>>(deg, parts, rowptr);
  k_scatter<<<(NE + 255) / 256, 256, 0, stream>>>(ei, rowptr, cursor, csr);

  k_rgcn<<<(NN + 3) / 4, 256, 0, stream>>>(xr, ei, et, rowptr, csr, agg);

  k_wcat<<<(H1 * 2 * H2) / 256, 256, 0, stream>>>(w_l, w_r, wcat);

  dim3 g5(1, (NN + 127) / 128);
  k_gemm<<<g5, 256, 0, stream>>>(nf, root, x1, agg, bias1, NN, H1, GD);

  dim3 g6(2, (NN + 127) / 128);
  k_gemm<<<g6, 256, 0, stream>>>(x1, wcat, xlr, nullptr, nullptr, NN, 2 * H2, H1);

  k_gat<<<(NN + 3) / 4, 256, 0, stream>>>(xlr, ei, rowptr, csr, att, bias2, out);
}

// Round 2
// 475.547 us; speedup vs baseline: 1.4709x; 1.4709x over previous
//
#include <hip/hip_runtime.h>
#include <hip/hip_bf16.h>
#include <cstdint>
#include <cstddef>

#define NN 50000
#define NE 500000
#define GD 256
#define H1 128
#define H2 128
#define NREL 8
#define NBASES 30
#define XRLD (NREL * H1)   // 1024
#define NCHUNKS ((NN + 1023) / 1024)  // 49

typedef __attribute__((ext_vector_type(8))) short bf16x8;
typedef __attribute__((ext_vector_type(4))) float f32x4;
typedef __attribute__((ext_vector_type(8))) unsigned short u16x8;

__device__ __forceinline__ float lrelu(float x) { return x > 0.f ? x : 0.2f * x; }

__device__ __forceinline__ unsigned short f2bf(float x) {
  union { float f; uint32_t u; } v; v.f = x;
  uint32_t r = v.u + 0x7FFF + ((v.u >> 16) & 1);   // round to nearest even
  return (unsigned short)(r >> 16);
}
__device__ __forceinline__ float bf2f(unsigned short u) {
  union { uint32_t u; float f; } v; v.u = ((uint32_t)u) << 16;
  return v.f;
}

// ---- cast nf fp32 -> bf16, 8 elems/thread ----
__global__ void k_cast(const float* __restrict__ in, unsigned short* __restrict__ out) {
  int i = blockIdx.x * 256 + threadIdx.x;   // NN*GD/8 = 1.6M threads
  const float4* p = (const float4*)(in + (size_t)i * 8);
  float4 a = p[0], b = p[1];
  u16x8 r;
  r[0] = f2bf(a.x); r[1] = f2bf(a.y); r[2] = f2bf(a.z); r[3] = f2bf(a.w);
  r[4] = f2bf(b.x); r[5] = f2bf(b.y); r[6] = f2bf(b.z); r[7] = f2bf(b.w);
  *(u16x8*)(out + (size_t)i * 8) = r;
}

// ---- wrb_t[n][k] (bf16, [1024][256]) = sum_b comp[r][b]*basis[b][k][o], n=r*128+o ----
__global__ void k_wr(const float* __restrict__ basis, const float* __restrict__ comp,
                     unsigned short* __restrict__ wrb_t) {
  int idx = blockIdx.x * 256 + threadIdx.x;   // 1024*256
  int n = idx >> 8;
  int k = idx & 255;
  int r = n >> 7, o = n & 127;
  float acc = 0.f;
  #pragma unroll
  for (int b = 0; b < NBASES; b++)
    acc += comp[r * NBASES + b] * basis[((size_t)b * GD + k) * H1 + o];
  wrb_t[idx] = f2bf(acc);
}

// ---- root_t[128][256] bf16 ; wcat_t[256][128] bf16 ([w_l|w_r] transposed) ----
__global__ void k_prep(const float* __restrict__ root, const float* __restrict__ w_l,
                       const float* __restrict__ w_r, unsigned short* __restrict__ root_t,
                       unsigned short* __restrict__ wcat_t) {
  int idx = blockIdx.x * 256 + threadIdx.x;   // 65536
  if (idx < 32768) {
    int n = idx >> 8, k = idx & 255;
    root_t[idx] = f2bf(root[k * H1 + n]);
  } else {
    int j = idx - 32768;
    int n = j >> 7, k = j & 127;
    wcat_t[j] = f2bf(n < H2 ? w_l[k * H2 + n] : w_r[k * H2 + (n - H2)]);
  }
}

// ---- bf16 MFMA GEMM: C[M][N] = A[M][K] @ Bt[N][K]^T  (+addend +bias) ----
// A,Bt bf16 row-major. N%128==0, K%32==0. 4 waves/block, 64x64 per wave.
__global__ __launch_bounds__(256)
void k_mgemm(const unsigned short* __restrict__ A, const unsigned short* __restrict__ Bt,
             void* __restrict__ Cv, const float* __restrict__ addend,
             const float* __restrict__ bias, int M, int N, int K, int outBf16) {
  const int lane = threadIdx.x & 63;
  const int wave = threadIdx.x >> 6;
  const int row0 = blockIdx.y * 128 + (wave >> 1) * 64;
  const int col0 = blockIdx.x * 128 + (wave & 1) * 64;
  const int lr = lane & 15;
  const int lkb = (lane >> 4) * 8;

  f32x4 acc[4][4];
  #pragma unroll
  for (int i = 0; i < 4; i++)
    #pragma unroll
    for (int j = 0; j < 4; j++) acc[i][j] = (f32x4){0.f, 0.f, 0.f, 0.f};

  const unsigned short* ap[4];
  const unsigned short* bp[4];
  #pragma unroll
  for (int mb = 0; mb < 4; mb++) {
    int r = row0 + mb * 16 + lr; if (r >= M) r = M - 1;   // clamp; rows discarded on store
    ap[mb] = A + (size_t)r * K + lkb;
  }
  #pragma unroll
  for (int nb = 0; nb < 4; nb++) {
    int c = col0 + nb * 16 + lr;
    bp[nb] = Bt + (size_t)c * K + lkb;
  }

  for (int k0 = 0; k0 < K; k0 += 32) {
    bf16x8 af[4], bfr[4];
    #pragma unroll
    for (int mb = 0; mb < 4; mb++) af[mb] = *(const bf16x8*)(ap[mb] + k0);
    #pragma unroll
    for (int nb = 0; nb < 4; nb++) bfr[nb] = *(const bf16x8*)(bp[nb] + k0);
    #pragma unroll
    for (int mb = 0; mb < 4; mb++)
      #pragma unroll
      for (int nb = 0; nb < 4; nb++)
        acc[mb][nb] = __builtin_amdgcn_mfma_f32_16x16x32_bf16(af[mb], bfr[nb], acc[mb][nb], 0, 0, 0);
  }

  const int orow = (lane >> 4) * 4;
  #pragma unroll
  for (int mb = 0; mb < 4; mb++) {
    #pragma unroll
    for (int i = 0; i < 4; i++) {
      int row = row0 + mb * 16 + orow + i;
      if (row < M) {
        size_t rbase = (size_t)row * N;
        #pragma unroll
        for (int nb = 0; nb < 4; nb++) {
          int col = col0 + nb * 16 + lr;
          float v = acc[mb][nb][i];
          if (addend) v += addend[rbase + col];
          if (bias) v += bias[col];
          if (outBf16) ((unsigned short*)Cv)[rbase + col] = f2bf(v);
          else ((float*)Cv)[rbase + col] = v;
        }
      }
    }
  }
}

// ---- CSR build ----
__global__ void k_deg(const int* __restrict__ ei, int* __restrict__ deg) {
  int e = blockIdx.x * 256 + threadIdx.x;
  if (e < NE) atomicAdd(&deg[ei[NE + e]], 1);
}

__global__ void k_scan_a(const int* __restrict__ deg, int* __restrict__ parts) {
  __shared__ int lds[256];
  int t = threadIdx.x;
  int base = blockIdx.x * 1024 + t * 4;
  int s = 0;
  #pragma unroll
  for (int j = 0; j < 4; j++) s += (base + j < NN) ? deg[base + j] : 0;
  lds[t] = s;
  __syncthreads();
  for (int st = 128; st > 0; st >>= 1) {
    if (t < st) lds[t] += lds[t + st];
    __syncthreads();
  }
  if (t == 0) parts[blockIdx.x] = lds[0];
}

__global__ void k_scan_b(int* __restrict__ parts) {
  if (threadIdx.x == 0) {
    int run = 0;
    for (int i = 0; i < NCHUNKS; i++) { int v = parts[i]; parts[i] = run; run += v; }
  }
}

__global__ void k_scan_c(const int* __restrict__ deg, const int* __restrict__ parts,
                         int* __restrict__ rowptr) {
  __shared__ int lds[256];
  int t = threadIdx.x;
  int base = blockIdx.x * 1024 + t * 4;
  int v[4];
  int s = 0;
  #pragma unroll
  for (int j = 0; j < 4; j++) { v[j] = (base + j < NN) ? deg[base + j] : 0; s += v[j]; }
  lds[t] = s;
  __syncthreads();
  for (int st = 1; st < 256; st <<= 1) {
    int add = (t >= st) ? lds[t - st] : 0;
    __syncthreads();
    lds[t] += add;
    __syncthreads();
  }
  int excl = lds[t] - s;
  int off = parts[blockIdx.x];
  int run = 0;
  #pragma unroll
  for (int j = 0; j < 4; j++) {
    run += v[j];
    if (base + j < NN) rowptr[base + j + 1] = off + excl + run;
  }
  if (blockIdx.x == 0 && t == 0) rowptr[0] = 0;
}

__global__ void k_scatter(const int* __restrict__ ei, const int* __restrict__ rowptr,
                          int* __restrict__ cursor, int* __restrict__ csr) {
  int e = blockIdx.x * 256 + threadIdx.x;
  if (e < NE) {
    int d = ei[NE + e];
    int pos = atomicAdd(&cursor[d], 1);
    csr[rowptr[d] + pos] = e;
  }
}

// ---- RGCN aggregation: one wave per dst (xr now bf16) ----
__global__ __launch_bounds__(256)
void k_rgcn(const unsigned short* __restrict__ xr, const int* __restrict__ ei,
            const int* __restrict__ et, const int* __restrict__ rowptr,
            const int* __restrict__ csr, float* __restrict__ agg) {
  int wid = (blockIdx.x * 256 + threadIdx.x) >> 6;
  int lane = threadIdx.x & 63;
  if (wid >= NN) return;
  int c0 = lane * 2;
  float acc0[NREL], acc1[NREL], cnt[NREL];
  #pragma unroll
  for (int r = 0; r < NREL; r++) { acc0[r] = 0.f; acc1[r] = 0.f; cnt[r] = 0.f; }
  int beg = rowptr[wid], end = rowptr[wid + 1];
  for (int j = beg; j < end; j++) {
    int e = csr[j];
    int s = ei[e];
    int r = et[e];
    uint32_t w = *(const uint32_t*)(xr + (size_t)s * XRLD + r * H1 + c0);
    float vx = bf2f((unsigned short)(w & 0xffff));
    float vy = bf2f((unsigned short)(w >> 16));
    #pragma unroll
    for (int rr = 0; rr < NREL; rr++) {
      if (r == rr) { acc0[rr] += vx; acc1[rr] += vy; cnt[rr] += 1.f; }
    }
  }
  float o0 = 0.f, o1 = 0.f;
  #pragma unroll
  for (int rr = 0; rr < NREL; rr++) {
    float inv = 1.f / fmaxf(cnt[rr], 1.f);
    o0 += acc0[rr] * inv;
    o1 += acc1[rr] * inv;
  }
  agg[(size_t)wid * H1 + c0] = o0;
  agg[(size_t)wid * H1 + c0 + 1] = o1;
}

// ---- GATv2: one wave per dst, online softmax incl. self loop ----
__global__ __launch_bounds__(256)
void k_gat(const float* __restrict__ xlr, const int* __restrict__ ei,
           const int* __restrict__ rowptr, const int* __restrict__ csr,
           const float* __restrict__ att, const float* __restrict__ bias2,
           float* __restrict__ out) {
  int wid = (blockIdx.x * 256 + threadIdx.x) >> 6;
  int lane = threadIdx.x & 63;
  if (wid >= NN) return;
  int c0 = lane * 2;
  float att0 = att[c0], att1 = att[c0 + 1];
  float2 xrt = *(const float2*)(xlr + (size_t)wid * 256 + 128 + c0);
  float2 v = *(const float2*)(xlr + (size_t)wid * 256 + c0);
  float ep = lrelu(v.x + xrt.x) * att0 + lrelu(v.y + xrt.y) * att1;
  #pragma unroll
  for (int off = 32; off > 0; off >>= 1) ep += __shfl_xor(ep, off, 64);
  float m = ep, s = 1.f, a0 = v.x, a1 = v.y;
  int beg = rowptr[wid], end = rowptr[wid + 1];
  for (int j = beg; j < end; j++) {
    int e = csr[j];
    int src = ei[e];
    float2 u = *(const float2*)(xlr + (size_t)src * 256 + c0);
    float p = lrelu(u.x + xrt.x) * att0 + lrelu(u.y + xrt.y) * att1;
    #pragma unroll
    for (int off = 32; off > 0; off >>= 1) p += __shfl_xor(p, off, 64);
    float mn = fmaxf(m, p);
    float sc = __expf(m - mn), w = __expf(p - mn);
    s = s * sc + w;
    a0 = a0 * sc + w * u.x;
    a1 = a1 * sc + w * u.y;
    m = mn;
  }
  float inv = 1.f / s;
  out[(size_t)wid * H1 + c0] = a0 * inv + bias2[c0];
  out[(size_t)wid * H1 + c0 + 1] = a1 * inv + bias2[c0 + 1];
}

extern "C" void kernel_launch(void* const* d_in, const int* in_sizes, int n_in,
                              void* d_out, int out_size, void* d_ws, size_t ws_size,
                              hipStream_t stream) {
  const float* nf    = (const float*)d_in[0];
  const int*   ei    = (const int*)d_in[1];   // [2][E]: src row then dst row
  const int*   et    = (const int*)d_in[3];
  const float* basis = (const float*)d_in[4];
  const float* comp  = (const float*)d_in[5];
  const float* root  = (const float*)d_in[6];
  const float* bias1 = (const float*)d_in[7];
  const float* w_l   = (const float*)d_in[8];
  const float* w_r   = (const float*)d_in[9];
  const float* att   = (const float*)d_in[10];
  const float* bias2 = (const float*)d_in[11];
  float* out = (float*)d_out;

  // workspace layout (~157 MB)
  char* ws = (char*)d_ws;
  unsigned short* xr_bf  = (unsigned short*)ws;                    // [NN][1024] bf16 = 102.4 MB
  unsigned short* nf_bf  = (unsigned short*)(ws + 102400000);      // [NN][256]  bf16 =  25.6 MB
  unsigned short* wrb_t  = (unsigned short*)(ws + 128000000);      // [1024][256] bf16
  unsigned short* root_t = (unsigned short*)(ws + 128524288);      // [128][256] bf16
  unsigned short* wcat_t = (unsigned short*)(ws + 128589824);      // [256][128] bf16
  float*          agg    = (float*)(ws + 128655360);               // [NN][128] fp32 = 25.6 MB
  int*            deg    = (int*)(ws + 154255360);
  int*            cursor = deg + NN;
  int*            rowptr = cursor + NN;
  int*            csr    = rowptr + NN + 1;
  int*            parts  = csr + NE;
  // overlays into xr region after k_rgcn (xr dead):
  unsigned short* x1_bf  = (unsigned short*)ws;                    // [NN][128] bf16 = 12.8 MB
  float*          xlr    = (float*)(ws + 12800000);                // [NN][256] fp32 = 51.2 MB

  hipMemsetAsync(deg, 0, 2 * NN * sizeof(int), stream);  // deg + cursor

  k_cast<<<(NN * GD / 8) / 256, 256, 0, stream>>>(nf, nf_bf);
  k_wr<<<(XRLD * GD) / 256, 256, 0, stream>>>(basis, comp, wrb_t);
  k_prep<<<65536 / 256, 256, 0, stream>>>(root, w_l, w_r, root_t, wcat_t);

  dim3 g2(XRLD / 128, (NN + 127) / 128);
  k_mgemm<<<g2, 256, 0, stream>>>(nf_bf, wrb_t, xr_bf, nullptr, nullptr, NN, XRLD, GD, 1);

  k_deg<<<(NE + 255) / 256, 256, 0, stream>>>(ei, deg);
  k_scan_a<<<NCHUNKS, 256, 0, stream>>>(deg, parts);
  k_scan_b<<<1, 64, 0, stream>>>(parts);
  k_scan_c<<<NCHUNKS, 256, 0, stream>>>(deg, parts, rowptr);
  k_scatter<<<(NE + 255) / 256, 256, 0, stream>>>(ei, rowptr, cursor, csr);

  k_rgcn<<<(NN + 3) / 4, 256, 0, stream>>>(xr_bf, ei, et, rowptr, csr, agg);

  dim3 g5(H1 / 128, (NN + 127) / 128);
  k_mgemm<<<g5, 256, 0, stream>>>(nf_bf, root_t, x1_bf, agg, bias1, NN, H1, GD, 1);

  dim3 g6(2 * H2 / 128, (NN + 127) / 128);
  k_mgemm<<<g6, 256, 0, stream>>>(x1_bf, wcat_t, xlr, nullptr, nullptr, NN, 2 * H2, H1, 0);

  k_gat<<<(NN + 3) / 4, 256, 0, stream>>>(xlr, ei, rowptr, csr, att, bias2, out);
}

// Round 3
// 464.195 us; speedup vs baseline: 1.5069x; 1.0245x over previous
//
#include <hip/hip_runtime.h>
#include <hip/hip_bf16.h>
#include <cstdint>
#include <cstddef>

#define NN 50000
#define NE 500000
#define GD 256
#define H1 128
#define H2 128
#define NREL 8
#define NBASES 30
#define XRLD (NREL * H1)   // 1024
#define NCHUNKS ((NN + 1023) / 1024)  // 49

typedef __attribute__((ext_vector_type(8))) short bf16x8;
typedef __attribute__((ext_vector_type(4))) float f32x4;
typedef __attribute__((ext_vector_type(8))) unsigned short u16x8;

__device__ __forceinline__ float lrelu(float x) { return x > 0.f ? x : 0.2f * x; }

__device__ __forceinline__ unsigned short f2bf(float x) {
  union { float f; uint32_t u; } v; v.f = x;
  uint32_t r = v.u + 0x7FFF + ((v.u >> 16) & 1);
  return (unsigned short)(r >> 16);
}
__device__ __forceinline__ float bf2f(unsigned short u) {
  union { uint32_t u; float f; } v; v.u = ((uint32_t)u) << 16;
  return v.f;
}

// ---- cast nf fp32 -> bf16 ----
__global__ void k_cast(const float* __restrict__ in, unsigned short* __restrict__ out) {
  int i = blockIdx.x * 256 + threadIdx.x;
  const float4* p = (const float4*)(in + (size_t)i * 8);
  float4 a = p[0], b = p[1];
  u16x8 r;
  r[0] = f2bf(a.x); r[1] = f2bf(a.y); r[2] = f2bf(a.z); r[3] = f2bf(a.w);
  r[4] = f2bf(b.x); r[5] = f2bf(b.y); r[6] = f2bf(b.z); r[7] = f2bf(b.w);
  *(u16x8*)(out + (size_t)i * 8) = r;
}

// ---- wrb_t[n][k] bf16 [1024][256] ----
__global__ void k_wr(const float* __restrict__ basis, const float* __restrict__ comp,
                     unsigned short* __restrict__ wrb_t) {
  int idx = blockIdx.x * 256 + threadIdx.x;
  int n = idx >> 8;
  int k = idx & 255;
  int r = n >> 7, o = n & 127;
  float acc = 0.f;
  #pragma unroll
  for (int b = 0; b < NBASES; b++)
    acc += comp[r * NBASES + b] * basis[((size_t)b * GD + k) * H1 + o];
  wrb_t[idx] = f2bf(acc);
}

// ---- root_t[128][256], wl_t[128][128], wr_t[128][128] (all bf16, Bt layout) ----
__global__ void k_prep(const float* __restrict__ root, const float* __restrict__ w_l,
                       const float* __restrict__ w_r, unsigned short* __restrict__ root_t,
                       unsigned short* __restrict__ wl_t, unsigned short* __restrict__ wr_t) {
  int idx = blockIdx.x * 256 + threadIdx.x;   // 65536
  if (idx < 32768) {
    int n = idx >> 8, k = idx & 255;
    root_t[idx] = f2bf(root[k * H1 + n]);
  } else if (idx < 49152) {
    int j = idx - 32768;
    int n = j >> 7, k = j & 127;
    wl_t[j] = f2bf(w_l[k * H2 + n]);
  } else {
    int j = idx - 49152;
    int n = j >> 7, k = j & 127;
    wr_t[j] = f2bf(w_r[k * H2 + n]);
  }
}

// ---- bf16 MFMA GEMM, LDS-staged A panel, XCD-swizzled grid ----
// C[M][N] = A[M][K] @ Bt[N][K]^T (+addend +bias). 1D grid nwg = gx*gy.
template <int K>
__global__ __launch_bounds__(256)
void k_mgemm(const unsigned short* __restrict__ A, const unsigned short* __restrict__ Bt,
             void* __restrict__ Cv, const float* __restrict__ addend,
             const float* __restrict__ bias, int M, int N, int gx, int outBf16) {
  extern __shared__ unsigned short As[];   // [128][K] bf16, XOR-swizzled chunks
  const int tid = threadIdx.x;
  const int lane = tid & 63;
  const int wave = tid >> 6;

  // bijective XCD swizzle (m204)
  const int nwg = gridDim.x;
  const int q = nwg >> 3, r = nwg & 7;
  const int xcd = blockIdx.x & 7, bi = blockIdx.x >> 3;
  const int wg = (xcd < r ? xcd * (q + 1) : r * (q + 1) + (xcd - r) * q) + bi;
  const int bx = wg % gx;
  const int by = wg / gx;
  const int row0 = by * 128;
  const int col0 = bx * 128 + (wave & 1) * 64;
  const int wrow = (wave >> 1) * 64;

  // ---- stage A tile [128][K], coalesced global, swizzled LDS write ----
  constexpr int CPR = K / 8;          // 16B chunks per row
  #pragma unroll
  for (int it = 0; it < K / 16; it++) {
    int off = it * 256 + tid;         // chunk-granular linear offset
    int row = off / CPR;
    int jb = off % CPR;
    int gm = row0 + row;
    u16x8 val;
    if (gm < M) {
      val = *(const u16x8*)(A + (size_t)gm * K + jb * 8);
    } else {
      #pragma unroll
      for (int z = 0; z < 8; z++) val[z] = 0;
    }
    int jbS = jb ^ (row & 7);
    *(u16x8*)&As[row * K + jbS * 8] = val;
  }
  __syncthreads();

  f32x4 acc[4][4];
  #pragma unroll
  for (int i = 0; i < 4; i++)
    #pragma unroll
    for (int j = 0; j < 4; j++) acc[i][j] = (f32x4){0.f, 0.f, 0.f, 0.f};

  const int lr = lane & 15;
  const int lko = lane >> 4;          // k-octet group 0..3
  const unsigned short* bp[4];
  #pragma unroll
  for (int nb = 0; nb < 4; nb++)
    bp[nb] = Bt + (size_t)(col0 + nb * 16 + lr) * K + lko * 8;

  #pragma unroll
  for (int k0 = 0; k0 < K; k0 += 32) {
    bf16x8 af[4], bfr[4];
    #pragma unroll
    for (int nb = 0; nb < 4; nb++) bfr[nb] = *(const bf16x8*)(bp[nb] + k0);
    #pragma unroll
    for (int mb = 0; mb < 4; mb++) {
      int rowL = wrow + mb * 16 + lr;
      int chunk = (k0 >> 3) + lko;
      int chunkS = chunk ^ (rowL & 7);
      af[mb] = *(const bf16x8*)&As[rowL * K + chunkS * 8];
    }
    #pragma unroll
    for (int mb = 0; mb < 4; mb++)
      #pragma unroll
      for (int nb = 0; nb < 4; nb++)
        acc[mb][nb] = __builtin_amdgcn_mfma_f32_16x16x32_bf16(af[mb], bfr[nb], acc[mb][nb], 0, 0, 0);
  }

  const int orow = lko * 4;
  #pragma unroll
  for (int mb = 0; mb < 4; mb++) {
    #pragma unroll
    for (int i = 0; i < 4; i++) {
      int row = row0 + wrow + mb * 16 + orow + i;
      if (row < M) {
        size_t rbase = (size_t)row * N;
        #pragma unroll
        for (int nb = 0; nb < 4; nb++) {
          int col = col0 + nb * 16 + lr;
          float v = acc[mb][nb][i];
          if (addend) v += addend[rbase + col];
          if (bias) v += bias[col];
          if (outBf16) ((unsigned short*)Cv)[rbase + col] = f2bf(v);
          else ((float*)Cv)[rbase + col] = v;
        }
      }
    }
  }
}

// ---- CSR build ----
__global__ void k_deg(const int* __restrict__ ei, int* __restrict__ deg) {
  int e = blockIdx.x * 256 + threadIdx.x;
  if (e < NE) atomicAdd(&deg[ei[NE + e]], 1);
}

__global__ void k_scan_a(const int* __restrict__ deg, int* __restrict__ parts) {
  __shared__ int lds[256];
  int t = threadIdx.x;
  int base = blockIdx.x * 1024 + t * 4;
  int s = 0;
  #pragma unroll
  for (int j = 0; j < 4; j++) s += (base + j < NN) ? deg[base + j] : 0;
  lds[t] = s;
  __syncthreads();
  for (int st = 128; st > 0; st >>= 1) {
    if (t < st) lds[t] += lds[t + st];
    __syncthreads();
  }
  if (t == 0) parts[blockIdx.x] = lds[0];
}

__global__ void k_scan_b(int* __restrict__ parts) {
  if (threadIdx.x == 0) {
    int run = 0;
    for (int i = 0; i < NCHUNKS; i++) { int v = parts[i]; parts[i] = run; run += v; }
  }
}

__global__ void k_scan_c(const int* __restrict__ deg, const int* __restrict__ parts,
                         int* __restrict__ rowptr) {
  __shared__ int lds[256];
  int t = threadIdx.x;
  int base = blockIdx.x * 1024 + t * 4;
  int v[4];
  int s = 0;
  #pragma unroll
  for (int j = 0; j < 4; j++) { v[j] = (base + j < NN) ? deg[base + j] : 0; s += v[j]; }
  lds[t] = s;
  __syncthreads();
  for (int st = 1; st < 256; st <<= 1) {
    int add = (t >= st) ? lds[t - st] : 0;
    __syncthreads();
    lds[t] += add;
    __syncthreads();
  }
  int excl = lds[t] - s;
  int off = parts[blockIdx.x];
  int run = 0;
  #pragma unroll
  for (int j = 0; j < 4; j++) {
    run += v[j];
    if (base + j < NN) rowptr[base + j + 1] = off + excl + run;
  }
  if (blockIdx.x == 0 && t == 0) rowptr[0] = 0;
}

__global__ void k_scatter(const int* __restrict__ ei, const int* __restrict__ rowptr,
                          int* __restrict__ cursor, int* __restrict__ csr) {
  int e = blockIdx.x * 256 + threadIdx.x;
  if (e < NE) {
    int d = ei[NE + e];
    int pos = atomicAdd(&cursor[d], 1);
    csr[rowptr[d] + pos] = e;
  }
}

// ---- RGCN aggregation: one wave per dst (xr bf16) ----
__global__ __launch_bounds__(256)
void k_rgcn(const unsigned short* __restrict__ xr, const int* __restrict__ ei,
            const int* __restrict__ et, const int* __restrict__ rowptr,
            const int* __restrict__ csr, float* __restrict__ agg) {
  int wid = (blockIdx.x * 256 + threadIdx.x) >> 6;
  int lane = threadIdx.x & 63;
  if (wid >= NN) return;
  int c0 = lane * 2;
  float acc0[NREL], acc1[NREL], cnt[NREL];
  #pragma unroll
  for (int r = 0; r < NREL; r++) { acc0[r] = 0.f; acc1[r] = 0.f; cnt[r] = 0.f; }
  int beg = rowptr[wid], end = rowptr[wid + 1];
  for (int j = beg; j < end; j++) {
    int e = csr[j];
    int s = ei[e];
    int r = et[e];
    uint32_t w = *(const uint32_t*)(xr + (size_t)s * XRLD + r * H1 + c0);
    float vx = bf2f((unsigned short)(w & 0xffff));
    float vy = bf2f((unsigned short)(w >> 16));
    #pragma unroll
    for (int rr = 0; rr < NREL; rr++) {
      if (r == rr) { acc0[rr] += vx; acc1[rr] += vy; cnt[rr] += 1.f; }
    }
  }
  float o0 = 0.f, o1 = 0.f;
  #pragma unroll
  for (int rr = 0; rr < NREL; rr++) {
    float inv = 1.f / fmaxf(cnt[rr], 1.f);
    o0 += acc0[rr] * inv;
    o1 += acc1[rr] * inv;
  }
  agg[(size_t)wid * H1 + c0] = o0;
  agg[(size_t)wid * H1 + c0 + 1] = o1;
}

// ---- GATv2: one wave per dst, online softmax, bf16 xl gathers ----
__global__ __launch_bounds__(256)
void k_gat(const unsigned short* __restrict__ xl_bf, const float* __restrict__ xrt,
           const int* __restrict__ ei, const int* __restrict__ rowptr,
           const int* __restrict__ csr, const float* __restrict__ att,
           const float* __restrict__ bias2, float* __restrict__ out) {
  int wid = (blockIdx.x * 256 + threadIdx.x) >> 6;
  int lane = threadIdx.x & 63;
  if (wid >= NN) return;
  int c0 = lane * 2;
  float att0 = att[c0], att1 = att[c0 + 1];
  float2 xr2 = *(const float2*)(xrt + (size_t)wid * H1 + c0);
  uint32_t wv = *(const uint32_t*)(xl_bf + (size_t)wid * H1 + c0);
  float vx = bf2f((unsigned short)(wv & 0xffff));
  float vy = bf2f((unsigned short)(wv >> 16));
  float ep = lrelu(vx + xr2.x) * att0 + lrelu(vy + xr2.y) * att1;
  #pragma unroll
  for (int off = 32; off > 0; off >>= 1) ep += __shfl_xor(ep, off, 64);
  float m = ep, s = 1.f, a0 = vx, a1 = vy;
  int beg = rowptr[wid], end = rowptr[wid + 1];
  for (int j = beg; j < end; j++) {
    int e = csr[j];
    int src = ei[e];
    uint32_t wu = *(const uint32_t*)(xl_bf + (size_t)src * H1 + c0);
    float ux = bf2f((unsigned short)(wu & 0xffff));
    float uy = bf2f((unsigned short)(wu >> 16));
    float p = lrelu(ux + xr2.x) * att0 + lrelu(uy + xr2.y) * att1;
    #pragma unroll
    for (int off = 32; off > 0; off >>= 1) p += __shfl_xor(p, off, 64);
    float mn = fmaxf(m, p);
    float sc = __expf(m - mn), w = __expf(p - mn);
    s = s * sc + w;
    a0 = a0 * sc + w * ux;
    a1 = a1 * sc + w * uy;
    m = mn;
  }
  float inv = 1.f / s;
  out[(size_t)wid * H1 + c0] = a0 * inv + bias2[c0];
  out[(size_t)wid * H1 + c0 + 1] = a1 * inv + bias2[c0 + 1];
}

extern "C" void kernel_launch(void* const* d_in, const int* in_sizes, int n_in,
                              void* d_out, int out_size, void* d_ws, size_t ws_size,
                              hipStream_t stream) {
  const float* nf    = (const float*)d_in[0];
  const int*   ei    = (const int*)d_in[1];
  const int*   et    = (const int*)d_in[3];
  const float* basis = (const float*)d_in[4];
  const float* comp  = (const float*)d_in[5];
  const float* root  = (const float*)d_in[6];
  const float* bias1 = (const float*)d_in[7];
  const float* w_l   = (const float*)d_in[8];
  const float* w_r   = (const float*)d_in[9];
  const float* att   = (const float*)d_in[10];
  const float* bias2 = (const float*)d_in[11];
  float* out = (float*)d_out;

  char* ws = (char*)d_ws;
  unsigned short* xr_bf  = (unsigned short*)ws;                    // [NN][1024] 102.4 MB
  unsigned short* nf_bf  = (unsigned short*)(ws + 102400000);      // [NN][256]  25.6 MB
  unsigned short* wrb_t  = (unsigned short*)(ws + 128000000);      // [1024][256]
  unsigned short* root_t = (unsigned short*)(ws + 128524288);      // [128][256]
  unsigned short* wl_t   = (unsigned short*)(ws + 128589824);      // [128][128]
  unsigned short* wr_t   = (unsigned short*)(ws + 128622592);      // [128][128]
  float*          agg    = (float*)(ws + 128655360);               // [NN][128] fp32
  int*            deg    = (int*)(ws + 154255360);
  int*            cursor = deg + NN;
  int*            rowptr = cursor + NN;
  int*            csr    = rowptr + NN + 1;
  int*            parts  = csr + NE;
  // overlays into xr region (dead after k_rgcn):
  unsigned short* x1_bf  = (unsigned short*)ws;                    // [NN][128] bf16
  unsigned short* xl_bf  = (unsigned short*)(ws + 12800000);       // [NN][128] bf16
  float*          xrt    = (float*)(ws + 25600000);                // [NN][128] fp32

  hipMemsetAsync(deg, 0, 2 * NN * sizeof(int), stream);

  k_cast<<<(NN * GD / 8) / 256, 256, 0, stream>>>(nf, nf_bf);
  k_wr<<<(XRLD * GD) / 256, 256, 0, stream>>>(basis, comp, wrb_t);
  k_prep<<<65536 / 256, 256, 0, stream>>>(root, w_l, w_r, root_t, wl_t, wr_t);

  const int GY = (NN + 127) / 128;  // 391
  k_mgemm<256><<<8 * GY, 256, 128 * 256 * 2, stream>>>(
      nf_bf, wrb_t, xr_bf, nullptr, nullptr, NN, XRLD, 8, 1);

  k_deg<<<(NE + 255) / 256, 256, 0, stream>>>(ei, deg);
  k_scan_a<<<NCHUNKS, 256, 0, stream>>>(deg, parts);
  k_scan_b<<<1, 64, 0, stream>>>(parts);
  k_scan_c<<<NCHUNKS, 256, 0, stream>>>(deg, parts, rowptr);
  k_scatter<<<(NE + 255) / 256, 256, 0, stream>>>(ei, rowptr, cursor, csr);

  k_rgcn<<<(NN + 3) / 4, 256, 0, stream>>>(xr_bf, ei, et, rowptr, csr, agg);

  k_mgemm<256><<<GY, 256, 128 * 256 * 2, stream>>>(
      nf_bf, root_t, x1_bf, agg, bias1, NN, H1, 1, 1);

  k_mgemm<128><<<GY, 256, 128 * 128 * 2, stream>>>(
      x1_bf, wl_t, xl_bf, nullptr, nullptr, NN, H2, 1, 1);
  k_mgemm<128><<<GY, 256, 128 * 128 * 2, stream>>>(
      x1_bf, wr_t, xrt, nullptr, nullptr, NN, H2, 1, 0);

  k_gat<<<(NN + 3) / 4, 256, 0, stream>>>(xl_bf, xrt, ei, rowptr, csr, att, bias2, out);
}

// Round 4
// 369.751 us; speedup vs baseline: 1.8918x; 1.2554x over previous
//
#include <hip/hip_runtime.h>
#include <hip/hip_bf16.h>
#include <cstdint>
#include <cstddef>

#define NN 50000
#define NE 500000
#define GD 256
#define H1 128
#define H2 128
#define NREL 8
#define NBASES 30
#define XRLD (NREL * H1)   // 1024
#define NCHUNKS ((NN + 1023) / 1024)  // 49

typedef __attribute__((ext_vector_type(8))) short bf16x8;
typedef __attribute__((ext_vector_type(4))) float f32x4;
typedef __attribute__((ext_vector_type(8))) unsigned short u16x8;

__device__ __forceinline__ float lrelu(float x) { return x > 0.f ? x : 0.2f * x; }

__device__ __forceinline__ unsigned short f2bf(float x) {
  union { float f; uint32_t u; } v; v.f = x;
  uint32_t r = v.u + 0x7FFF + ((v.u >> 16) & 1);
  return (unsigned short)(r >> 16);
}
__device__ __forceinline__ float bf2f(unsigned short u) {
  union { uint32_t u; float f; } v; v.u = ((uint32_t)u) << 16;
  return v.f;
}

// ---- cast nf fp32 -> bf16 ----
__global__ void k_cast(const float* __restrict__ in, unsigned short* __restrict__ out) {
  int i = blockIdx.x * 256 + threadIdx.x;
  const float4* p = (const float4*)(in + (size_t)i * 8);
  float4 a = p[0], b = p[1];
  u16x8 r;
  r[0] = f2bf(a.x); r[1] = f2bf(a.y); r[2] = f2bf(a.z); r[3] = f2bf(a.w);
  r[4] = f2bf(b.x); r[5] = f2bf(b.y); r[6] = f2bf(b.z); r[7] = f2bf(b.w);
  *(u16x8*)(out + (size_t)i * 8) = r;
}

// ---- wrb_t[n][k] bf16 [1024][256] ----
__global__ void k_wr(const float* __restrict__ basis, const float* __restrict__ comp,
                     unsigned short* __restrict__ wrb_t) {
  int idx = blockIdx.x * 256 + threadIdx.x;
  int n = idx >> 8;
  int k = idx & 255;
  int r = n >> 7, o = n & 127;
  float acc = 0.f;
  #pragma unroll
  for (int b = 0; b < NBASES; b++)
    acc += comp[r * NBASES + b] * basis[((size_t)b * GD + k) * H1 + o];
  wrb_t[idx] = f2bf(acc);
}

// ---- root_t[128][256] bf16; wcat_t[256][128] bf16 ([w_l|w_r] as Bt) ----
__global__ void k_prep(const float* __restrict__ root, const float* __restrict__ w_l,
                       const float* __restrict__ w_r, unsigned short* __restrict__ root_t,
                       unsigned short* __restrict__ wcat_t) {
  int idx = blockIdx.x * 256 + threadIdx.x;   // 65536
  if (idx < 32768) {
    int n = idx >> 8, k = idx & 255;
    root_t[idx] = f2bf(root[k * H1 + n]);
  } else {
    int j = idx - 32768;
    int n = j >> 7, k = j & 127;
    wcat_t[j] = f2bf(n < H2 ? w_l[k * H2 + n] : w_r[k * H2 + (n - H2)]);
  }
}

// ---- bf16 MFMA GEMM, LDS-staged A, coalesced LDS-staged C-store ----
// C[M][N](bf16) = A[M][K] @ Bt[N][K]^T (+addend +bias). 1D grid nwg = gx*gy.
template <int K>
__global__ __launch_bounds__(256)
void k_mgemm(const unsigned short* __restrict__ A, const unsigned short* __restrict__ Bt,
             unsigned short* __restrict__ C, const float* __restrict__ addend,
             const float* __restrict__ bias, int M, int N, int gx) {
  extern __shared__ unsigned short As[];   // [128][K] swizzled; reused as Cs[128][128]
  const int tid = threadIdx.x;
  const int lane = tid & 63;
  const int wave = tid >> 6;

  // bijective XCD swizzle (m204)
  const int nwg = gridDim.x;
  const int q = nwg >> 3, r = nwg & 7;
  const int xcd = blockIdx.x & 7, bi = blockIdx.x >> 3;
  const int wg = (xcd < r ? xcd * (q + 1) : r * (q + 1) + (xcd - r) * q) + bi;
  const int bx = wg % gx;
  const int by = wg / gx;
  const int row0 = by * 128;
  const int colb = bx * 128;
  const int wcol = (wave & 1) * 64;
  const int wrow = (wave >> 1) * 64;

  // ---- stage A tile [128][K], coalesced global, swizzled LDS write ----
  constexpr int CPR = K / 8;          // 16B chunks per row
  #pragma unroll
  for (int it = 0; it < K / 16; it++) {
    int off = it * 256 + tid;
    int row = off / CPR;
    int jb = off % CPR;
    int gm = row0 + row;
    u16x8 val;
    if (gm < M) {
      val = *(const u16x8*)(A + (size_t)gm * K + jb * 8);
    } else {
      #pragma unroll
      for (int z = 0; z < 8; z++) val[z] = 0;
    }
    int jbS = jb ^ (row & 7);
    *(u16x8*)&As[row * K + jbS * 8] = val;
  }
  __syncthreads();

  f32x4 acc[4][4];
  #pragma unroll
  for (int i = 0; i < 4; i++)
    #pragma unroll
    for (int j = 0; j < 4; j++) acc[i][j] = (f32x4){0.f, 0.f, 0.f, 0.f};

  const int lr = lane & 15;
  const int lko = lane >> 4;
  const unsigned short* bp[4];
  #pragma unroll
  for (int nb = 0; nb < 4; nb++)
    bp[nb] = Bt + (size_t)(colb + wcol + nb * 16 + lr) * K + lko * 8;

  #pragma unroll
  for (int k0 = 0; k0 < K; k0 += 32) {
    bf16x8 af[4], bfr[4];
    #pragma unroll
    for (int nb = 0; nb < 4; nb++) bfr[nb] = *(const bf16x8*)(bp[nb] + k0);
    #pragma unroll
    for (int mb = 0; mb < 4; mb++) {
      int rowL = wrow + mb * 16 + lr;
      int chunk = (k0 >> 3) + lko;
      int chunkS = chunk ^ (rowL & 7);
      af[mb] = *(const bf16x8*)&As[rowL * K + chunkS * 8];
    }
    #pragma unroll
    for (int mb = 0; mb < 4; mb++)
      #pragma unroll
      for (int nb = 0; nb < 4; nb++)
        acc[mb][nb] = __builtin_amdgcn_mfma_f32_16x16x32_bf16(af[mb], bfr[nb], acc[mb][nb], 0, 0, 0);
  }

  // ---- epilogue: acc (+addend +bias) -> swizzled Cs -> coalesced store ----
  __syncthreads();                     // all As reads done
  unsigned short* Cs = As;             // [128][128] bf16, 32 KB
  const int orow = lko * 4;
  #pragma unroll
  for (int mb = 0; mb < 4; mb++) {
    #pragma unroll
    for (int i = 0; i < 4; i++) {
      int row = wrow + mb * 16 + orow + i;
      int grow = row0 + row;
      #pragma unroll
      for (int nb = 0; nb < 4; nb++) {
        int col = wcol + nb * 16 + lr;
        float v = acc[mb][nb][i];
        if (addend && grow < M) v += addend[(size_t)grow * N + colb + col];
        if (bias) v += bias[colb + col];
        int idx = row * 128 + col;
        Cs[idx ^ (((row >> 2) & 7) << 4)] = f2bf(v);
      }
    }
  }
  __syncthreads();
  #pragma unroll
  for (int it = 0; it < 8; it++) {
    int off = it * 256 + tid;          // 0..2047
    int row = off >> 4, jb = off & 15;
    int grow = row0 + row;
    if (grow < M) {
      int idx = (row * 128 + jb * 8) ^ (((row >> 2) & 7) << 4);
      *(u16x8*)&C[(size_t)grow * N + colb + jb * 8] = *(const u16x8*)&Cs[idx];
    }
  }
}

// ---- CSR build ----
__global__ void k_deg(const int* __restrict__ ei, int* __restrict__ deg) {
  int e = blockIdx.x * 256 + threadIdx.x;
  if (e < NE) atomicAdd(&deg[ei[NE + e]], 1);
}

__global__ void k_scan_a(const int* __restrict__ deg, int* __restrict__ parts) {
  __shared__ int lds[256];
  int t = threadIdx.x;
  int base = blockIdx.x * 1024 + t * 4;
  int s = 0;
  #pragma unroll
  for (int j = 0; j < 4; j++) s += (base + j < NN) ? deg[base + j] : 0;
  lds[t] = s;
  __syncthreads();
  for (int st = 128; st > 0; st >>= 1) {
    if (t < st) lds[t] += lds[t + st];
    __syncthreads();
  }
  if (t == 0) parts[blockIdx.x] = lds[0];
}

__global__ void k_scan_b(int* __restrict__ parts) {
  if (threadIdx.x == 0) {
    int run = 0;
    for (int i = 0; i < NCHUNKS; i++) { int v = parts[i]; parts[i] = run; run += v; }
  }
}

__global__ void k_scan_c(const int* __restrict__ deg, const int* __restrict__ parts,
                         int* __restrict__ rowptr) {
  __shared__ int lds[256];
  int t = threadIdx.x;
  int base = blockIdx.x * 1024 + t * 4;
  int v[4];
  int s = 0;
  #pragma unroll
  for (int j = 0; j < 4; j++) { v[j] = (base + j < NN) ? deg[base + j] : 0; s += v[j]; }
  lds[t] = s;
  __syncthreads();
  for (int st = 1; st < 256; st <<= 1) {
    int add = (t >= st) ? lds[t - st] : 0;
    __syncthreads();
    lds[t] += add;
    __syncthreads();
  }
  int excl = lds[t] - s;
  int off = parts[blockIdx.x];
  int run = 0;
  #pragma unroll
  for (int j = 0; j < 4; j++) {
    run += v[j];
    if (base + j < NN) rowptr[base + j + 1] = off + excl + run;
  }
  if (blockIdx.x == 0 && t == 0) rowptr[0] = 0;
}

// pack (src | type<<20) into csr entries
__global__ void k_scatter(const int* __restrict__ ei, const int* __restrict__ et,
                          const int* __restrict__ rowptr, int* __restrict__ cursor,
                          int* __restrict__ csr) {
  int e = blockIdx.x * 256 + threadIdx.x;
  if (e < NE) {
    int d = ei[NE + e];
    int pos = atomicAdd(&cursor[d], 1);
    csr[rowptr[d] + pos] = ei[e] | (et[e] << 20);
  }
}

// ---- RGCN aggregation: one wave per dst, lane-broadcast edges, 4-batched ----
__global__ __launch_bounds__(256)
void k_rgcn(const unsigned short* __restrict__ xr, const int* __restrict__ csr2,
            const int* __restrict__ rowptr, float* __restrict__ agg) {
  int wid = (blockIdx.x * 256 + threadIdx.x) >> 6;
  int lane = threadIdx.x & 63;
  if (wid >= NN) return;
  int c0 = lane * 2;
  float acc0[NREL], acc1[NREL], cnt[NREL];
  #pragma unroll
  for (int r = 0; r < NREL; r++) { acc0[r] = 0.f; acc1[r] = 0.f; cnt[r] = 0.f; }
  int beg = rowptr[wid], end = rowptr[wid + 1];
  for (int j0 = beg; j0 < end; j0 += 64) {
    int nv = end - j0; if (nv > 64) nv = 64;
    int pk = (lane < nv) ? csr2[j0 + lane] : 0;
    int t = 0;
    for (; t + 4 <= nv; t += 4) {
      uint32_t wv[4]; int rt[4];
      #pragma unroll
      for (int z = 0; z < 4; z++) {
        int p = __shfl(pk, t + z, 64);
        int s = p & 0xFFFFF;
        rt[z] = p >> 20;
        wv[z] = *(const uint32_t*)(xr + (size_t)s * XRLD + rt[z] * H1 + c0);
      }
      #pragma unroll
      for (int z = 0; z < 4; z++) {
        float vx = bf2f((unsigned short)(wv[z] & 0xffff));
        float vy = bf2f((unsigned short)(wv[z] >> 16));
        #pragma unroll
        for (int rr = 0; rr < NREL; rr++) {
          bool hit = (rt[z] == rr);
          acc0[rr] += hit ? vx : 0.f;
          acc1[rr] += hit ? vy : 0.f;
          cnt[rr] += hit ? 1.f : 0.f;
        }
      }
    }
    for (; t < nv; t++) {
      int p = __shfl(pk, t, 64);
      int s = p & 0xFFFFF;
      int rt = p >> 20;
      uint32_t w = *(const uint32_t*)(xr + (size_t)s * XRLD + rt * H1 + c0);
      float vx = bf2f((unsigned short)(w & 0xffff));
      float vy = bf2f((unsigned short)(w >> 16));
      #pragma unroll
      for (int rr = 0; rr < NREL; rr++) {
        bool hit = (rt == rr);
        acc0[rr] += hit ? vx : 0.f;
        acc1[rr] += hit ? vy : 0.f;
        cnt[rr] += hit ? 1.f : 0.f;
      }
    }
  }
  float o0 = 0.f, o1 = 0.f;
  #pragma unroll
  for (int rr = 0; rr < NREL; rr++) {
    float inv = 1.f / fmaxf(cnt[rr], 1.f);
    o0 += acc0[rr] * inv;
    o1 += acc1[rr] * inv;
  }
  agg[(size_t)wid * H1 + c0] = o0;
  agg[(size_t)wid * H1 + c0 + 1] = o1;
}

// ---- GATv2: one wave per dst, 4-batched edges, chunked online softmax ----
__global__ __launch_bounds__(256)
void k_gat(const unsigned short* __restrict__ xlr, const int* __restrict__ csr2,
           const int* __restrict__ rowptr, const float* __restrict__ att,
           const float* __restrict__ bias2, float* __restrict__ out) {
  int wid = (blockIdx.x * 256 + threadIdx.x) >> 6;
  int lane = threadIdx.x & 63;
  if (wid >= NN) return;
  int c0 = lane * 2;
  float att0 = att[c0], att1 = att[c0 + 1];
  uint32_t wr2 = *(const uint32_t*)(xlr + (size_t)wid * 256 + 128 + c0);
  float xr0 = bf2f((unsigned short)(wr2 & 0xffff));
  float xr1 = bf2f((unsigned short)(wr2 >> 16));
  uint32_t wv0 = *(const uint32_t*)(xlr + (size_t)wid * 256 + c0);
  float vx = bf2f((unsigned short)(wv0 & 0xffff));
  float vy = bf2f((unsigned short)(wv0 >> 16));
  float ep = lrelu(vx + xr0) * att0 + lrelu(vy + xr1) * att1;
  #pragma unroll
  for (int off = 32; off > 0; off >>= 1) ep += __shfl_xor(ep, off, 64);
  float m = ep, s = 1.f, a0 = vx, a1 = vy;
  int beg = rowptr[wid], end = rowptr[wid + 1];
  for (int j0 = beg; j0 < end; j0 += 64) {
    int nv = end - j0; if (nv > 64) nv = 64;
    int pk = (lane < nv) ? csr2[j0 + lane] : 0;
    int t = 0;
    for (; t + 4 <= nv; t += 4) {
      float ux[4], uy[4], p[4];
      #pragma unroll
      for (int z = 0; z < 4; z++) {
        int src = __shfl(pk, t + z, 64) & 0xFFFFF;
        uint32_t wu = *(const uint32_t*)(xlr + (size_t)src * 256 + c0);
        ux[z] = bf2f((unsigned short)(wu & 0xffff));
        uy[z] = bf2f((unsigned short)(wu >> 16));
      }
      #pragma unroll
      for (int z = 0; z < 4; z++)
        p[z] = lrelu(ux[z] + xr0) * att0 + lrelu(uy[z] + xr1) * att1;
      #pragma unroll
      for (int off = 32; off > 0; off >>= 1) {
        #pragma unroll
        for (int z = 0; z < 4; z++) p[z] += __shfl_xor(p[z], off, 64);
      }
      float mn = fmaxf(m, fmaxf(fmaxf(p[0], p[1]), fmaxf(p[2], p[3])));
      float sc = __expf(m - mn);
      float e0 = __expf(p[0] - mn), e1 = __expf(p[1] - mn);
      float e2 = __expf(p[2] - mn), e3 = __expf(p[3] - mn);
      s = s * sc + (e0 + e1 + e2 + e3);
      a0 = a0 * sc + e0 * ux[0] + e1 * ux[1] + e2 * ux[2] + e3 * ux[3];
      a1 = a1 * sc + e0 * uy[0] + e1 * uy[1] + e2 * uy[2] + e3 * uy[3];
      m = mn;
    }
    for (; t < nv; t++) {
      int src = __shfl(pk, t, 64) & 0xFFFFF;
      uint32_t wu = *(const uint32_t*)(xlr + (size_t)src * 256 + c0);
      float ux = bf2f((unsigned short)(wu & 0xffff));
      float uy = bf2f((unsigned short)(wu >> 16));
      float p = lrelu(ux + xr0) * att0 + lrelu(uy + xr1) * att1;
      #pragma unroll
      for (int off = 32; off > 0; off >>= 1) p += __shfl_xor(p, off, 64);
      float mn = fmaxf(m, p);
      float sc = __expf(m - mn), w = __expf(p - mn);
      s = s * sc + w;
      a0 = a0 * sc + w * ux;
      a1 = a1 * sc + w * uy;
      m = mn;
    }
  }
  float inv = 1.f / s;
  out[(size_t)wid * H1 + c0] = a0 * inv + bias2[c0];
  out[(size_t)wid * H1 + c0 + 1] = a1 * inv + bias2[c0 + 1];
}

extern "C" void kernel_launch(void* const* d_in, const int* in_sizes, int n_in,
                              void* d_out, int out_size, void* d_ws, size_t ws_size,
                              hipStream_t stream) {
  const float* nf    = (const float*)d_in[0];
  const int*   ei    = (const int*)d_in[1];
  const int*   et    = (const int*)d_in[3];
  const float* basis = (const float*)d_in[4];
  const float* comp  = (const float*)d_in[5];
  const float* root  = (const float*)d_in[6];
  const float* bias1 = (const float*)d_in[7];
  const float* w_l   = (const float*)d_in[8];
  const float* w_r   = (const float*)d_in[9];
  const float* att   = (const float*)d_in[10];
  const float* bias2 = (const float*)d_in[11];
  float* out = (float*)d_out;

  char* ws = (char*)d_ws;
  unsigned short* xr_bf  = (unsigned short*)ws;                    // [NN][1024] 102.4 MB
  unsigned short* nf_bf  = (unsigned short*)(ws + 102400000);      // [NN][256]  25.6 MB
  unsigned short* wrb_t  = (unsigned short*)(ws + 128000000);      // [1024][256]
  unsigned short* root_t = (unsigned short*)(ws + 128524288);      // [128][256]
  unsigned short* wcat_t = (unsigned short*)(ws + 128589824);      // [256][128]
  float*          agg    = (float*)(ws + 128655360);               // [NN][128] fp32
  int*            deg    = (int*)(ws + 154255360);
  int*            cursor = deg + NN;
  int*            rowptr = cursor + NN;
  int*            csr    = rowptr + NN + 1;
  int*            parts  = csr + NE;
  // overlays into xr region (dead after k_rgcn):
  unsigned short* x1_bf  = (unsigned short*)ws;                    // [NN][128] bf16
  unsigned short* xlr_bf = (unsigned short*)(ws + 12800000);       // [NN][256] bf16 = [xl|xrt]

  hipMemsetAsync(deg, 0, 2 * NN * sizeof(int), stream);

  k_cast<<<(NN * GD / 8) / 256, 256, 0, stream>>>(nf, nf_bf);
  k_wr<<<(XRLD * GD) / 256, 256, 0, stream>>>(basis, comp, wrb_t);
  k_prep<<<65536 / 256, 256, 0, stream>>>(root, w_l, w_r, root_t, wcat_t);

  const int GY = (NN + 127) / 128;  // 391
  k_mgemm<256><<<8 * GY, 256, 128 * 256 * 2, stream>>>(
      nf_bf, wrb_t, xr_bf, nullptr, nullptr, NN, XRLD, 8);

  k_deg<<<(NE + 255) / 256, 256, 0, stream>>>(ei, deg);
  k_scan_a<<<NCHUNKS, 256, 0, stream>>>(deg, parts);
  k_scan_b<<<1, 64, 0, stream>>>(parts);
  k_scan_c<<<NCHUNKS, 256, 0, stream>>>(deg, parts, rowptr);
  k_scatter<<<(NE + 255) / 256, 256, 0, stream>>>(ei, et, rowptr, cursor, csr);

  k_rgcn<<<(NN + 3) / 4, 256, 0, stream>>>(xr_bf, csr, rowptr, agg);

  k_mgemm<256><<<GY, 256, 128 * 256 * 2, stream>>>(
      nf_bf, root_t, x1_bf, agg, bias1, NN, H1, 1);

  k_mgemm<128><<<2 * GY, 256, 128 * 128 * 2, stream>>>(
      x1_bf, wcat_t, xlr_bf, nullptr, nullptr, NN, 2 * H2, 2);

  k_gat<<<(NN + 3) / 4, 256, 0, stream>>>(xlr_bf, csr, rowptr, att, bias2, out);
}

// Round 5
// 312.912 us; speedup vs baseline: 2.2354x; 1.1816x over previous
//
#include <hip/hip_runtime.h>
#include <hip/hip_bf16.h>
#include <cstdint>
#include <cstddef>

#define NN 50000
#define NE 500000
#define GD 256
#define H1 128
#define H2 128
#define NREL 8
#define NBASES 30
#define XRLD (NREL * H1)   // 1024
#define NCHUNKS ((NN + 1023) / 1024)  // 49

typedef __attribute__((ext_vector_type(8))) short bf16x8;
typedef __attribute__((ext_vector_type(4))) float f32x4;
typedef __attribute__((ext_vector_type(8))) unsigned short u16x8;

__device__ __forceinline__ float lrelu(float x) { return x > 0.f ? x : 0.2f * x; }

__device__ __forceinline__ unsigned short f2bf(float x) {
  union { float f; uint32_t u; } v; v.f = x;
  uint32_t r = v.u + 0x7FFF + ((v.u >> 16) & 1);
  return (unsigned short)(r >> 16);
}
__device__ __forceinline__ float bf2f(unsigned short u) {
  union { uint32_t u; float f; } v; v.u = ((uint32_t)u) << 16;
  return v.f;
}

// ---- cast nf fp32 -> bf16 ----
__global__ void k_cast(const float* __restrict__ in, unsigned short* __restrict__ out) {
  int i = blockIdx.x * 256 + threadIdx.x;
  const float4* p = (const float4*)(in + (size_t)i * 8);
  float4 a = p[0], b = p[1];
  u16x8 r;
  r[0] = f2bf(a.x); r[1] = f2bf(a.y); r[2] = f2bf(a.z); r[3] = f2bf(a.w);
  r[4] = f2bf(b.x); r[5] = f2bf(b.y); r[6] = f2bf(b.z); r[7] = f2bf(b.w);
  *(u16x8*)(out + (size_t)i * 8) = r;
}

// ---- wrb_t[n][k] bf16 [1024][256] ----
__global__ void k_wr(const float* __restrict__ basis, const float* __restrict__ comp,
                     unsigned short* __restrict__ wrb_t) {
  int idx = blockIdx.x * 256 + threadIdx.x;
  int n = idx >> 8;
  int k = idx & 255;
  int r = n >> 7, o = n & 127;
  float acc = 0.f;
  #pragma unroll
  for (int b = 0; b < NBASES; b++)
    acc += comp[r * NBASES + b] * basis[((size_t)b * GD + k) * H1 + o];
  wrb_t[idx] = f2bf(acc);
}

// ---- root_t[128][256] bf16; wcat_t[256][128] bf16 ([w_l|w_r] as Bt) ----
__global__ void k_prep(const float* __restrict__ root, const float* __restrict__ w_l,
                       const float* __restrict__ w_r, unsigned short* __restrict__ root_t,
                       unsigned short* __restrict__ wcat_t) {
  int idx = blockIdx.x * 256 + threadIdx.x;   // 65536
  if (idx < 32768) {
    int n = idx >> 8, k = idx & 255;
    root_t[idx] = f2bf(root[k * H1 + n]);
  } else {
    int j = idx - 32768;
    int n = j >> 7, k = j & 127;
    wcat_t[j] = f2bf(n < H2 ? w_l[k * H2 + n] : w_r[k * H2 + (n - H2)]);
  }
}

// ---- bf16 MFMA GEMM, 2-phase pipelined: dbuf LDS A+B via global_load_lds ----
// C[M][N](bf16) = A[M][K] @ Bt[N][K]^T (+addend +bias). 1D grid nwg = gx*gy.
// LDS (elems): As buf0 [0,8192) buf1 [8192,16384); Bs buf0 [16384,24576) buf1 [24576,32768)
template <int K>
__global__ __launch_bounds__(256)
void k_mgemm(const unsigned short* __restrict__ A, const unsigned short* __restrict__ Bt,
             unsigned short* __restrict__ C, const float* __restrict__ addend,
             const float* __restrict__ bias, int M, int N, int gx) {
  extern __shared__ unsigned short lds[];
  const int tid = threadIdx.x;
  const int lane = tid & 63;
  const int wave = tid >> 6;

  // bijective XCD swizzle (m204)
  const int nwg = gridDim.x;
  const int q = nwg >> 3, r = nwg & 7;
  const int xcd = blockIdx.x & 7, bi = blockIdx.x >> 3;
  const int wg = (xcd < r ? xcd * (q + 1) : r * (q + 1) + (xcd - r) * q) + bi;
  const int bx = wg % gx;
  const int by = wg / gx;
  const int row0 = by * 128;
  const int colb = bx * 128;
  const int wcol = (wave & 1) * 64;
  const int wrow = (wave >> 1) * 64;
  const int lr = lane & 15;
  const int lko = lane >> 4;

  f32x4 acc[4][4];
  #pragma unroll
  for (int i = 0; i < 4; i++)
    #pragma unroll
    for (int j = 0; j < 4; j++) acc[i][j] = (f32x4){0.f, 0.f, 0.f, 0.f};

  // stage one BK=64 slice of A[128] rows + B[128] cols into buffer b.
  // linear LDS dest (wave-uniform base + lane*16); inverse-swizzled global src.
  auto stage = [&](int k0, int b) {
    unsigned short* as = lds + b * 8192;
    unsigned short* bs = lds + 16384 + b * 8192;
    #pragma unroll
    for (int it = 0; it < 4; it++) {
      int ci = it * 256 + tid;          // 16B-chunk index, 0..1023
      int rw = ci >> 3, cs = ci & 7;
      int c = cs ^ (rw & 7);            // source chunk for this dest slot
      int gm = row0 + rw; if (gm >= M) gm = M - 1;
      const unsigned short* gpA = A + (size_t)gm * K + k0 + c * 8;
      __builtin_amdgcn_global_load_lds(
          (const __attribute__((address_space(1))) void*)gpA,
          (__attribute__((address_space(3))) void*)(as + (size_t)ci * 8), 16, 0, 0);
      const unsigned short* gpB = Bt + (size_t)(colb + rw) * K + k0 + c * 8;
      __builtin_amdgcn_global_load_lds(
          (const __attribute__((address_space(1))) void*)gpB,
          (__attribute__((address_space(3))) void*)(bs + (size_t)ci * 8), 16, 0, 0);
    }
  };

  auto compute = [&](int b) {
    const unsigned short* as = lds + b * 8192;
    const unsigned short* bs = lds + 16384 + b * 8192;
    #pragma unroll
    for (int kk = 0; kk < 64; kk += 32) {
      bf16x8 af[4], bfr[4];
      int cbase = (kk >> 3) + lko;
      #pragma unroll
      for (int mb = 0; mb < 4; mb++) {
        int rowL = wrow + mb * 16 + lr;
        af[mb] = *(const bf16x8*)&as[rowL * 64 + ((cbase ^ (rowL & 7)) << 3)];
      }
      #pragma unroll
      for (int nb = 0; nb < 4; nb++) {
        int colL = wcol + nb * 16 + lr;
        bfr[nb] = *(const bf16x8*)&bs[colL * 64 + ((cbase ^ (colL & 7)) << 3)];
      }
      #pragma unroll
      for (int mb = 0; mb < 4; mb++)
        #pragma unroll
        for (int nb = 0; nb < 4; nb++)
          acc[mb][nb] = __builtin_amdgcn_mfma_f32_16x16x32_bf16(af[mb], bfr[nb], acc[mb][nb], 0, 0, 0);
    }
  };

  constexpr int NS = K / 64;
  stage(0, 0);
  #pragma unroll
  for (int s = 0; s < NS; s++) {
    __syncthreads();                       // stage(s) complete (vmcnt drained)
    if (s + 1 < NS) stage((s + 1) * 64, (s + 1) & 1);
    compute(s & 1);
  }

  // ---- epilogue: acc (+addend +bias) -> swizzled Cs -> coalesced store ----
  __syncthreads();                         // all LDS reads done; reuse as Cs
  unsigned short* Cs = lds;                // [128][128] bf16, 32 KB
  const int orow = lko * 4;
  #pragma unroll
  for (int mb = 0; mb < 4; mb++) {
    #pragma unroll
    for (int i = 0; i < 4; i++) {
      int row = wrow + mb * 16 + orow + i;
      int grow = row0 + row;
      #pragma unroll
      for (int nb = 0; nb < 4; nb++) {
        int col = wcol + nb * 16 + lr;
        float v = acc[mb][nb][i];
        if (addend && grow < M) v += addend[(size_t)grow * N + colb + col];
        if (bias) v += bias[colb + col];
        int idx = row * 128 + col;
        Cs[idx ^ (((row >> 2) & 7) << 4)] = f2bf(v);
      }
    }
  }
  __syncthreads();
  #pragma unroll
  for (int it = 0; it < 8; it++) {
    int off = it * 256 + tid;              // 0..2047
    int row = off >> 4, jb = off & 15;
    int grow = row0 + row;
    if (grow < M) {
      int idx = (row * 128 + jb * 8) ^ (((row >> 2) & 7) << 4);
      *(u16x8*)&C[(size_t)grow * N + colb + jb * 8] = *(const u16x8*)&Cs[idx];
    }
  }
}

// ---- CSR build ----
__global__ void k_deg(const int* __restrict__ ei, int* __restrict__ deg) {
  int e = blockIdx.x * 256 + threadIdx.x;
  if (e < NE) atomicAdd(&deg[ei[NE + e]], 1);
}

__global__ void k_scan_a(const int* __restrict__ deg, int* __restrict__ parts) {
  __shared__ int lds[256];
  int t = threadIdx.x;
  int base = blockIdx.x * 1024 + t * 4;
  int s = 0;
  #pragma unroll
  for (int j = 0; j < 4; j++) s += (base + j < NN) ? deg[base + j] : 0;
  lds[t] = s;
  __syncthreads();
  for (int st = 128; st > 0; st >>= 1) {
    if (t < st) lds[t] += lds[t + st];
    __syncthreads();
  }
  if (t == 0) parts[blockIdx.x] = lds[0];
}

__global__ void k_scan_b(int* __restrict__ parts) {
  if (threadIdx.x == 0) {
    int run = 0;
    for (int i = 0; i < NCHUNKS; i++) { int v = parts[i]; parts[i] = run; run += v; }
  }
}

__global__ void k_scan_c(const int* __restrict__ deg, const int* __restrict__ parts,
                         int* __restrict__ rowptr) {
  __shared__ int lds[256];
  int t = threadIdx.x;
  int base = blockIdx.x * 1024 + t * 4;
  int v[4];
  int s = 0;
  #pragma unroll
  for (int j = 0; j < 4; j++) { v[j] = (base + j < NN) ? deg[base + j] : 0; s += v[j]; }
  lds[t] = s;
  __syncthreads();
  for (int st = 1; st < 256; st <<= 1) {
    int add = (t >= st) ? lds[t - st] : 0;
    __syncthreads();
    lds[t] += add;
    __syncthreads();
  }
  int excl = lds[t] - s;
  int off = parts[blockIdx.x];
  int run = 0;
  #pragma unroll
  for (int j = 0; j < 4; j++) {
    run += v[j];
    if (base + j < NN) rowptr[base + j + 1] = off + excl + run;
  }
  if (blockIdx.x == 0 && t == 0) rowptr[0] = 0;
}

// pack (src | type<<20) into csr entries
__global__ void k_scatter(const int* __restrict__ ei, const int* __restrict__ et,
                          const int* __restrict__ rowptr, int* __restrict__ cursor,
                          int* __restrict__ csr) {
  int e = blockIdx.x * 256 + threadIdx.x;
  if (e < NE) {
    int d = ei[NE + e];
    int pos = atomicAdd(&cursor[d], 1);
    csr[rowptr[d] + pos] = ei[e] | (et[e] << 20);
  }
}

// ---- RGCN aggregation: one wave per dst, lane-broadcast edges, 4-batched ----
__global__ __launch_bounds__(256)
void k_rgcn(const unsigned short* __restrict__ xr, const int* __restrict__ csr2,
            const int* __restrict__ rowptr, float* __restrict__ agg) {
  int wid = (blockIdx.x * 256 + threadIdx.x) >> 6;
  int lane = threadIdx.x & 63;
  if (wid >= NN) return;
  int c0 = lane * 2;
  float acc0[NREL], acc1[NREL], cnt[NREL];
  #pragma unroll
  for (int r = 0; r < NREL; r++) { acc0[r] = 0.f; acc1[r] = 0.f; cnt[r] = 0.f; }
  int beg = rowptr[wid], end = rowptr[wid + 1];
  for (int j0 = beg; j0 < end; j0 += 64) {
    int nv = end - j0; if (nv > 64) nv = 64;
    int pk = (lane < nv) ? csr2[j0 + lane] : 0;
    int t = 0;
    for (; t + 4 <= nv; t += 4) {
      uint32_t wv[4]; int rt[4];
      #pragma unroll
      for (int z = 0; z < 4; z++) {
        int p = __shfl(pk, t + z, 64);
        int s = p & 0xFFFFF;
        rt[z] = p >> 20;
        wv[z] = *(const uint32_t*)(xr + (size_t)s * XRLD + rt[z] * H1 + c0);
      }
      #pragma unroll
      for (int z = 0; z < 4; z++) {
        float vx = bf2f((unsigned short)(wv[z] & 0xffff));
        float vy = bf2f((unsigned short)(wv[z] >> 16));
        #pragma unroll
        for (int rr = 0; rr < NREL; rr++) {
          bool hit = (rt[z] == rr);
          acc0[rr] += hit ? vx : 0.f;
          acc1[rr] += hit ? vy : 0.f;
          cnt[rr] += hit ? 1.f : 0.f;
        }
      }
    }
    for (; t < nv; t++) {
      int p = __shfl(pk, t, 64);
      int s = p & 0xFFFFF;
      int rt = p >> 20;
      uint32_t w = *(const uint32_t*)(xr + (size_t)s * XRLD + rt * H1 + c0);
      float vx = bf2f((unsigned short)(w & 0xffff));
      float vy = bf2f((unsigned short)(w >> 16));
      #pragma unroll
      for (int rr = 0; rr < NREL; rr++) {
        bool hit = (rt == rr);
        acc0[rr] += hit ? vx : 0.f;
        acc1[rr] += hit ? vy : 0.f;
        cnt[rr] += hit ? 1.f : 0.f;
      }
    }
  }
  float o0 = 0.f, o1 = 0.f;
  #pragma unroll
  for (int rr = 0; rr < NREL; rr++) {
    float inv = 1.f / fmaxf(cnt[rr], 1.f);
    o0 += acc0[rr] * inv;
    o1 += acc1[rr] * inv;
  }
  agg[(size_t)wid * H1 + c0] = o0;
  agg[(size_t)wid * H1 + c0 + 1] = o1;
}

// ---- GATv2: one wave per dst, 4-batched edges, chunked online softmax ----
__global__ __launch_bounds__(256)
void k_gat(const unsigned short* __restrict__ xlr, const int* __restrict__ csr2,
           const int* __restrict__ rowptr, const float* __restrict__ att,
           const float* __restrict__ bias2, float* __restrict__ out) {
  int wid = (blockIdx.x * 256 + threadIdx.x) >> 6;
  int lane = threadIdx.x & 63;
  if (wid >= NN) return;
  int c0 = lane * 2;
  float att0 = att[c0], att1 = att[c0 + 1];
  uint32_t wr2 = *(const uint32_t*)(xlr + (size_t)wid * 256 + 128 + c0);
  float xr0 = bf2f((unsigned short)(wr2 & 0xffff));
  float xr1 = bf2f((unsigned short)(wr2 >> 16));
  uint32_t wv0 = *(const uint32_t*)(xlr + (size_t)wid * 256 + c0);
  float vx = bf2f((unsigned short)(wv0 & 0xffff));
  float vy = bf2f((unsigned short)(wv0 >> 16));
  float ep = lrelu(vx + xr0) * att0 + lrelu(vy + xr1) * att1;
  #pragma unroll
  for (int off = 32; off > 0; off >>= 1) ep += __shfl_xor(ep, off, 64);
  float m = ep, s = 1.f, a0 = vx, a1 = vy;
  int beg = rowptr[wid], end = rowptr[wid + 1];
  for (int j0 = beg; j0 < end; j0 += 64) {
    int nv = end - j0; if (nv > 64) nv = 64;
    int pk = (lane < nv) ? csr2[j0 + lane] : 0;
    int t = 0;
    for (; t + 4 <= nv; t += 4) {
      float ux[4], uy[4], p[4];
      #pragma unroll
      for (int z = 0; z < 4; z++) {
        int src = __shfl(pk, t + z, 64) & 0xFFFFF;
        uint32_t wu = *(const uint32_t*)(xlr + (size_t)src * 256 + c0);
        ux[z] = bf2f((unsigned short)(wu & 0xffff));
        uy[z] = bf2f((unsigned short)(wu >> 16));
      }
      #pragma unroll
      for (int z = 0; z < 4; z++)
        p[z] = lrelu(ux[z] + xr0) * att0 + lrelu(uy[z] + xr1) * att1;
      #pragma unroll
      for (int off = 32; off > 0; off >>= 1) {
        #pragma unroll
        for (int z = 0; z < 4; z++) p[z] += __shfl_xor(p[z], off, 64);
      }
      float mn = fmaxf(m, fmaxf(fmaxf(p[0], p[1]), fmaxf(p[2], p[3])));
      float sc = __expf(m - mn);
      float e0 = __expf(p[0] - mn), e1 = __expf(p[1] - mn);
      float e2 = __expf(p[2] - mn), e3 = __expf(p[3] - mn);
      s = s * sc + (e0 + e1 + e2 + e3);
      a0 = a0 * sc + e0 * ux[0] + e1 * ux[1] + e2 * ux[2] + e3 * ux[3];
      a1 = a1 * sc + e0 * uy[0] + e1 * uy[1] + e2 * uy[2] + e3 * uy[3];
      m = mn;
    }
    for (; t < nv; t++) {
      int src = __shfl(pk, t, 64) & 0xFFFFF;
      uint32_t wu = *(const uint32_t*)(xlr + (size_t)src * 256 + c0);
      float ux = bf2f((unsigned short)(wu & 0xffff));
      float uy = bf2f((unsigned short)(wu >> 16));
      float p = lrelu(ux + xr0) * att0 + lrelu(uy + xr1) * att1;
      #pragma unroll
      for (int off = 32; off > 0; off >>= 1) p += __shfl_xor(p, off, 64);
      float mn = fmaxf(m, p);
      float sc = __expf(m - mn), w = __expf(p - mn);
      s = s * sc + w;
      a0 = a0 * sc + w * ux;
      a1 = a1 * sc + w * uy;
      m = mn;
    }
  }
  float inv = 1.f / s;
  out[(size_t)wid * H1 + c0] = a0 * inv + bias2[c0];
  out[(size_t)wid * H1 + c0 + 1] = a1 * inv + bias2[c0 + 1];
}

extern "C" void kernel_launch(void* const* d_in, const int* in_sizes, int n_in,
                              void* d_out, int out_size, void* d_ws, size_t ws_size,
                              hipStream_t stream) {
  const float* nf    = (const float*)d_in[0];
  const int*   ei    = (const int*)d_in[1];
  const int*   et    = (const int*)d_in[3];
  const float* basis = (const float*)d_in[4];
  const float* comp  = (const float*)d_in[5];
  const float* root  = (const float*)d_in[6];
  const float* bias1 = (const float*)d_in[7];
  const float* w_l   = (const float*)d_in[8];
  const float* w_r   = (const float*)d_in[9];
  const float* att   = (const float*)d_in[10];
  const float* bias2 = (const float*)d_in[11];
  float* out = (float*)d_out;

  char* ws = (char*)d_ws;
  unsigned short* xr_bf  = (unsigned short*)ws;                    // [NN][1024] 102.4 MB
  unsigned short* nf_bf  = (unsigned short*)(ws + 102400000);      // [NN][256]  25.6 MB
  unsigned short* wrb_t  = (unsigned short*)(ws + 128000000);      // [1024][256]
  unsigned short* root_t = (unsigned short*)(ws + 128524288);      // [128][256]
  unsigned short* wcat_t = (unsigned short*)(ws + 128589824);      // [256][128]
  float*          agg    = (float*)(ws + 128655360);               // [NN][128] fp32
  int*            deg    = (int*)(ws + 154255360);
  int*            cursor = deg + NN;
  int*            rowptr = cursor + NN;
  int*            csr    = rowptr + NN + 1;
  int*            parts  = csr + NE;
  // overlays into xr region (dead after k_rgcn):
  unsigned short* x1_bf  = (unsigned short*)ws;                    // [NN][128] bf16
  unsigned short* xlr_bf = (unsigned short*)(ws + 12800000);       // [NN][256] bf16 = [xl|xrt]

  hipMemsetAsync(deg, 0, 2 * NN * sizeof(int), stream);

  k_cast<<<(NN * GD / 8) / 256, 256, 0, stream>>>(nf, nf_bf);
  k_wr<<<(XRLD * GD) / 256, 256, 0, stream>>>(basis, comp, wrb_t);
  k_prep<<<65536 / 256, 256, 0, stream>>>(root, w_l, w_r, root_t, wcat_t);

  const int GY = (NN + 127) / 128;  // 391
  k_mgemm<256><<<8 * GY, 256, 65536, stream>>>(
      nf_bf, wrb_t, xr_bf, nullptr, nullptr, NN, XRLD, 8);

  k_deg<<<(NE + 255) / 256, 256, 0, stream>>>(ei, deg);
  k_scan_a<<<NCHUNKS, 256, 0, stream>>>(deg, parts);
  k_scan_b<<<1, 64, 0, stream>>>(parts);
  k_scan_c<<<NCHUNKS, 256, 0, stream>>>(deg, parts, rowptr);
  k_scatter<<<(NE + 255) / 256, 256, 0, stream>>>(ei, et, rowptr, cursor, csr);

  k_rgcn<<<(NN + 3) / 4, 256, 0, stream>>>(xr_bf, csr, rowptr, agg);

  k_mgemm<256><<<GY, 256, 65536, stream>>>(
      nf_bf, root_t, x1_bf, agg, bias1, NN, H1, 1);

  k_mgemm<128><<<2 * GY, 256, 65536, stream>>>(
      x1_bf, wcat_t, xlr_bf, nullptr, nullptr, NN, 2 * H2, 2);

  k_gat<<<(NN + 3) / 4, 256, 0, stream>>>(xlr_bf, csr, rowptr, att, bias2, out);
}

// Round 6
// 305.304 us; speedup vs baseline: 2.2911x; 1.0249x over previous
//
#include <hip/hip_runtime.h>
#include <hip/hip_bf16.h>
#include <cstdint>
#include <cstddef>

#define NN 50000
#define NE 500000
#define GD 256
#define H1 128
#define H2 128
#define NREL 8
#define NBASES 30
#define XRLD (NREL * H1)   // 1024
#define NCHUNKS ((NN + 1023) / 1024)  // 49

typedef __attribute__((ext_vector_type(8))) short bf16x8;
typedef __attribute__((ext_vector_type(4))) float f32x4;
typedef __attribute__((ext_vector_type(8))) unsigned short u16x8;

__device__ __forceinline__ float lrelu(float x) { return x > 0.f ? x : 0.2f * x; }

__device__ __forceinline__ unsigned short f2bf(float x) {
  union { float f; uint32_t u; } v; v.f = x;
  uint32_t r = v.u + 0x7FFF + ((v.u >> 16) & 1);
  return (unsigned short)(r >> 16);
}
__device__ __forceinline__ float bf2f(unsigned short u) {
  union { uint32_t u; float f; } v; v.u = ((uint32_t)u) << 16;
  return v.f;
}

// ---- cast nf fp32 -> bf16 ----
__global__ void k_cast(const float* __restrict__ in, unsigned short* __restrict__ out) {
  int i = blockIdx.x * 256 + threadIdx.x;
  const float4* p = (const float4*)(in + (size_t)i * 8);
  float4 a = p[0], b = p[1];
  u16x8 r;
  r[0] = f2bf(a.x); r[1] = f2bf(a.y); r[2] = f2bf(a.z); r[3] = f2bf(a.w);
  r[4] = f2bf(b.x); r[5] = f2bf(b.y); r[6] = f2bf(b.z); r[7] = f2bf(b.w);
  *(u16x8*)(out + (size_t)i * 8) = r;
}

// ---- wrb_t[n][k] bf16 [1024][256] ----
__global__ void k_wr(const float* __restrict__ basis, const float* __restrict__ comp,
                     unsigned short* __restrict__ wrb_t) {
  int idx = blockIdx.x * 256 + threadIdx.x;
  int n = idx >> 8;
  int k = idx & 255;
  int r = n >> 7, o = n & 127;
  float acc = 0.f;
  #pragma unroll
  for (int b = 0; b < NBASES; b++)
    acc += comp[r * NBASES + b] * basis[((size_t)b * GD + k) * H1 + o];
  wrb_t[idx] = f2bf(acc);
}

// ---- root_t[128][256] bf16; wcat_t[256][128] bf16 ([w_l|w_r] as Bt) ----
__global__ void k_prep(const float* __restrict__ root, const float* __restrict__ w_l,
                       const float* __restrict__ w_r, unsigned short* __restrict__ root_t,
                       unsigned short* __restrict__ wcat_t) {
  int idx = blockIdx.x * 256 + threadIdx.x;   // 65536
  if (idx < 32768) {
    int n = idx >> 8, k = idx & 255;
    root_t[idx] = f2bf(root[k * H1 + n]);
  } else {
    int j = idx - 32768;
    int n = j >> 7, k = j & 127;
    wcat_t[j] = f2bf(n < H2 ? w_l[k * H2 + n] : w_r[k * H2 + (n - H2)]);
  }
}

// ---- bf16 MFMA GEMM, BK=32 double-buffered global_load_lds pipeline ----
// C[M][N](bf16) = A[M][K] @ Bt[N][K]^T (+bf16 addend +bias). 1D grid = gx*gy.
// BM = MBF*32. LDS: Abuf[2][BM*32] | Bbuf[2][128*32]; reused as Cs[BM][128].
template <int K, int MBF>
__global__ __launch_bounds__(256)
void k_mgemm(const unsigned short* __restrict__ A, const unsigned short* __restrict__ Bt,
             unsigned short* __restrict__ C, const unsigned short* __restrict__ addend,
             const float* __restrict__ bias, int M, int N, int gx) {
  constexpr int BM = MBF * 32;
  constexpr int ACH = BM * 4;          // A 16B-chunks per slice
  constexpr int ITER = (ACH + 512) / 256;
  constexpr int NS = K / 32;
  extern __shared__ unsigned short lds[];
  const int tid = threadIdx.x;
  const int lane = tid & 63;
  const int wave = tid >> 6;

  // bijective XCD swizzle (m204)
  const int nwg = gridDim.x;
  const int q = nwg >> 3, r = nwg & 7;
  const int xcd = blockIdx.x & 7, bi = blockIdx.x >> 3;
  const int wg = (xcd < r ? xcd * (q + 1) : r * (q + 1) + (xcd - r) * q) + bi;
  const int bx = wg % gx;
  const int by = wg / gx;
  const int row0 = by * BM;
  const int colb = bx * 128;
  const int wcol = (wave & 1) * 64;
  const int wrow = (wave >> 1) * (MBF * 16);
  const int lr = lane & 15;
  const int lko = lane >> 4;

  f32x4 acc[MBF][4];
  #pragma unroll
  for (int i = 0; i < MBF; i++)
    #pragma unroll
    for (int j = 0; j < 4; j++) acc[i][j] = (f32x4){0.f, 0.f, 0.f, 0.f};

  // stage one BK=32 slice; linear LDS dest, inverse-swizzled global source.
  auto stage = [&](int k0, int b) {
    unsigned short* as = lds + b * (BM * 32);
    unsigned short* bs = lds + 2 * BM * 32 + b * 4096;
    #pragma unroll
    for (int it = 0; it < ITER; it++) {
      int ci = it * 256 + tid;
      if (ci < ACH) {
        int row = ci >> 2, cs = ci & 3;
        int s = (row & 3) ^ ((row >> 2) & 3);
        int gm = row0 + row; if (gm >= M) gm = M - 1;
        const unsigned short* gp = A + (size_t)gm * K + k0 + ((cs ^ s) << 3);
        __builtin_amdgcn_global_load_lds(
            (const __attribute__((address_space(1))) void*)gp,
            (__attribute__((address_space(3))) void*)(as + (size_t)ci * 8), 16, 0, 0);
      } else {
        int cj = ci - ACH;
        int row = cj >> 2, cs = cj & 3;
        int s = (row & 3) ^ ((row >> 2) & 3);
        const unsigned short* gp = Bt + (size_t)(colb + row) * K + k0 + ((cs ^ s) << 3);
        __builtin_amdgcn_global_load_lds(
            (const __attribute__((address_space(1))) void*)gp,
            (__attribute__((address_space(3))) void*)(bs + (size_t)cj * 8), 16, 0, 0);
      }
    }
  };

  auto compute = [&](int b) {
    const unsigned short* as = lds + b * (BM * 32);
    const unsigned short* bs = lds + 2 * BM * 32 + b * 4096;
    bf16x8 af[MBF], bfr[4];
    #pragma unroll
    for (int mb = 0; mb < MBF; mb++) {
      int rowL = wrow + mb * 16 + lr;
      int s = (rowL & 3) ^ ((rowL >> 2) & 3);
      af[mb] = *(const bf16x8*)&as[rowL * 32 + ((lko ^ s) << 3)];
    }
    #pragma unroll
    for (int nb = 0; nb < 4; nb++) {
      int colL = wcol + nb * 16 + lr;
      int s = (colL & 3) ^ ((colL >> 2) & 3);
      bfr[nb] = *(const bf16x8*)&bs[colL * 32 + ((lko ^ s) << 3)];
    }
    #pragma unroll
    for (int mb = 0; mb < MBF; mb++)
      #pragma unroll
      for (int nb = 0; nb < 4; nb++)
        acc[mb][nb] = __builtin_amdgcn_mfma_f32_16x16x32_bf16(af[mb], bfr[nb], acc[mb][nb], 0, 0, 0);
  };

  stage(0, 0);
  #pragma unroll
  for (int s = 0; s < NS; s++) {
    __syncthreads();                       // stage(s) landed
    if (s + 1 < NS) stage((s + 1) * 32, (s + 1) & 1);
    compute(s & 1);
  }

  // ---- epilogue: acc (+addend +bias) -> swizzled Cs -> coalesced store ----
  __syncthreads();
  unsigned short* Cs = lds;                // [BM][128] bf16
  const int orow = lko * 4;
  #pragma unroll
  for (int mb = 0; mb < MBF; mb++) {
    #pragma unroll
    for (int i = 0; i < 4; i++) {
      int row = wrow + mb * 16 + orow + i;
      int grow = row0 + row;
      #pragma unroll
      for (int nb = 0; nb < 4; nb++) {
        int col = wcol + nb * 16 + lr;
        float v = acc[mb][nb][i];
        if (addend && grow < M) v += bf2f(addend[(size_t)grow * N + colb + col]);
        if (bias) v += bias[colb + col];
        int idx = row * 128 + col;
        Cs[idx ^ (((row >> 2) & 7) << 4)] = f2bf(v);
      }
    }
  }
  __syncthreads();
  #pragma unroll
  for (int it = 0; it < BM / 16; it++) {
    int off = it * 256 + tid;
    int row = off >> 4, jb = off & 15;
    int grow = row0 + row;
    if (grow < M) {
      int idx = (row * 128 + jb * 8) ^ (((row >> 2) & 7) << 4);
      *(u16x8*)&C[(size_t)grow * N + colb + jb * 8] = *(const u16x8*)&Cs[idx];
    }
  }
}

// ---- CSR build ----
__global__ void k_deg(const int* __restrict__ ei, int* __restrict__ deg) {
  int e = blockIdx.x * 256 + threadIdx.x;
  if (e < NE) atomicAdd(&deg[ei[NE + e]], 1);
}

__global__ void k_scan_a(const int* __restrict__ deg, int* __restrict__ parts) {
  __shared__ int lds[256];
  int t = threadIdx.x;
  int base = blockIdx.x * 1024 + t * 4;
  int s = 0;
  #pragma unroll
  for (int j = 0; j < 4; j++) s += (base + j < NN) ? deg[base + j] : 0;
  lds[t] = s;
  __syncthreads();
  for (int st = 128; st > 0; st >>= 1) {
    if (t < st) lds[t] += lds[t + st];
    __syncthreads();
  }
  if (t == 0) parts[blockIdx.x] = lds[0];
}

__global__ void k_scan_b(int* __restrict__ parts) {
  int t = threadIdx.x;   // 64 threads
  int v = (t < NCHUNKS) ? parts[t] : 0;
  int x = v;
  #pragma unroll
  for (int off = 1; off < 64; off <<= 1) {
    int y = __shfl_up(x, off, 64);
    if (t >= off) x += y;
  }
  if (t < NCHUNKS) parts[t] = x - v;
}

__global__ void k_scan_c(const int* __restrict__ deg, const int* __restrict__ parts,
                         int* __restrict__ rowptr) {
  __shared__ int lds[256];
  int t = threadIdx.x;
  int base = blockIdx.x * 1024 + t * 4;
  int v[4];
  int s = 0;
  #pragma unroll
  for (int j = 0; j < 4; j++) { v[j] = (base + j < NN) ? deg[base + j] : 0; s += v[j]; }
  lds[t] = s;
  __syncthreads();
  for (int st = 1; st < 256; st <<= 1) {
    int add = (t >= st) ? lds[t - st] : 0;
    __syncthreads();
    lds[t] += add;
    __syncthreads();
  }
  int excl = lds[t] - s;
  int off = parts[blockIdx.x];
  int run = 0;
  #pragma unroll
  for (int j = 0; j < 4; j++) {
    run += v[j];
    if (base + j < NN) rowptr[base + j + 1] = off + excl + run;
  }
  if (blockIdx.x == 0 && t == 0) rowptr[0] = 0;
}

// pack (src | type<<20) into csr entries
__global__ void k_scatter(const int* __restrict__ ei, const int* __restrict__ et,
                          const int* __restrict__ rowptr, int* __restrict__ cursor,
                          int* __restrict__ csr) {
  int e = blockIdx.x * 256 + threadIdx.x;
  if (e < NE) {
    int d = ei[NE + e];
    int pos = atomicAdd(&cursor[d], 1);
    csr[rowptr[d] + pos] = ei[e] | (et[e] << 20);
  }
}

// ---- RGCN aggregation: one wave per dst, 8-batched lane-broadcast edges ----
__global__ __launch_bounds__(256)
void k_rgcn(const unsigned short* __restrict__ xr, const int* __restrict__ csr2,
            const int* __restrict__ rowptr, unsigned short* __restrict__ agg) {
  int wid = (blockIdx.x * 256 + threadIdx.x) >> 6;
  int lane = threadIdx.x & 63;
  if (wid >= NN) return;
  int c0 = lane * 2;
  float acc0[NREL], acc1[NREL], cnt[NREL];
  #pragma unroll
  for (int r = 0; r < NREL; r++) { acc0[r] = 0.f; acc1[r] = 0.f; cnt[r] = 0.f; }
  int beg = rowptr[wid], end = rowptr[wid + 1];
  for (int j0 = beg; j0 < end; j0 += 64) {
    int nv = end - j0; if (nv > 64) nv = 64;
    int pk = (lane < nv) ? csr2[j0 + lane] : 0;
    int t = 0;
    for (; t + 8 <= nv; t += 8) {
      uint32_t wv[8]; int rt[8];
      #pragma unroll
      for (int z = 0; z < 8; z++) {
        int p = __shfl(pk, t + z, 64);
        int s = p & 0xFFFFF;
        rt[z] = p >> 20;
        wv[z] = *(const uint32_t*)(xr + (size_t)s * XRLD + rt[z] * H1 + c0);
      }
      #pragma unroll
      for (int z = 0; z < 8; z++) {
        float vx = bf2f((unsigned short)(wv[z] & 0xffff));
        float vy = bf2f((unsigned short)(wv[z] >> 16));
        #pragma unroll
        for (int rr = 0; rr < NREL; rr++) {
          bool hit = (rt[z] == rr);
          acc0[rr] += hit ? vx : 0.f;
          acc1[rr] += hit ? vy : 0.f;
          cnt[rr] += hit ? 1.f : 0.f;
        }
      }
    }
    for (; t < nv; t++) {
      int p = __shfl(pk, t, 64);
      int s = p & 0xFFFFF;
      int rt = p >> 20;
      uint32_t w = *(const uint32_t*)(xr + (size_t)s * XRLD + rt * H1 + c0);
      float vx = bf2f((unsigned short)(w & 0xffff));
      float vy = bf2f((unsigned short)(w >> 16));
      #pragma unroll
      for (int rr = 0; rr < NREL; rr++) {
        bool hit = (rt == rr);
        acc0[rr] += hit ? vx : 0.f;
        acc1[rr] += hit ? vy : 0.f;
        cnt[rr] += hit ? 1.f : 0.f;
      }
    }
  }
  float o0 = 0.f, o1 = 0.f;
  #pragma unroll
  for (int rr = 0; rr < NREL; rr++) {
    float inv = 1.f / fmaxf(cnt[rr], 1.f);
    o0 += acc0[rr] * inv;
    o1 += acc1[rr] * inv;
  }
  uint32_t packed = (uint32_t)f2bf(o0) | ((uint32_t)f2bf(o1) << 16);
  *(uint32_t*)&agg[(size_t)wid * H1 + c0] = packed;
}

// ---- GATv2: one wave per dst, 8-batched edges, chunked online softmax ----
__global__ __launch_bounds__(256)
void k_gat(const unsigned short* __restrict__ xlr, const int* __restrict__ csr2,
           const int* __restrict__ rowptr, const float* __restrict__ att,
           const float* __restrict__ bias2, float* __restrict__ out) {
  int wid = (blockIdx.x * 256 + threadIdx.x) >> 6;
  int lane = threadIdx.x & 63;
  if (wid >= NN) return;
  int c0 = lane * 2;
  float att0 = att[c0], att1 = att[c0 + 1];
  uint32_t wr2 = *(const uint32_t*)(xlr + (size_t)wid * 256 + 128 + c0);
  float xr0 = bf2f((unsigned short)(wr2 & 0xffff));
  float xr1 = bf2f((unsigned short)(wr2 >> 16));
  uint32_t wv0 = *(const uint32_t*)(xlr + (size_t)wid * 256 + c0);
  float vx = bf2f((unsigned short)(wv0 & 0xffff));
  float vy = bf2f((unsigned short)(wv0 >> 16));
  float ep = lrelu(vx + xr0) * att0 + lrelu(vy + xr1) * att1;
  #pragma unroll
  for (int off = 32; off > 0; off >>= 1) ep += __shfl_xor(ep, off, 64);
  float m = ep, s = 1.f, a0 = vx, a1 = vy;
  int beg = rowptr[wid], end = rowptr[wid + 1];
  for (int j0 = beg; j0 < end; j0 += 64) {
    int nv = end - j0; if (nv > 64) nv = 64;
    int pk = (lane < nv) ? csr2[j0 + lane] : 0;
    int t = 0;
    for (; t + 8 <= nv; t += 8) {
      float ux[8], uy[8], p[8];
      #pragma unroll
      for (int z = 0; z < 8; z++) {
        int src = __shfl(pk, t + z, 64) & 0xFFFFF;
        uint32_t wu = *(const uint32_t*)(xlr + (size_t)src * 256 + c0);
        ux[z] = bf2f((unsigned short)(wu & 0xffff));
        uy[z] = bf2f((unsigned short)(wu >> 16));
      }
      #pragma unroll
      for (int z = 0; z < 8; z++)
        p[z] = lrelu(ux[z] + xr0) * att0 + lrelu(uy[z] + xr1) * att1;
      #pragma unroll
      for (int off = 32; off > 0; off >>= 1) {
        #pragma unroll
        for (int z = 0; z < 8; z++) p[z] += __shfl_xor(p[z], off, 64);
      }
      float pm = p[0];
      #pragma unroll
      for (int z = 1; z < 8; z++) pm = fmaxf(pm, p[z]);
      float mn = fmaxf(m, pm);
      float sc = __expf(m - mn);
      float e[8];
      #pragma unroll
      for (int z = 0; z < 8; z++) e[z] = __expf(p[z] - mn);
      float es = 0.f, ea0 = 0.f, ea1 = 0.f;
      #pragma unroll
      for (int z = 0; z < 8; z++) { es += e[z]; ea0 += e[z] * ux[z]; ea1 += e[z] * uy[z]; }
      s = s * sc + es;
      a0 = a0 * sc + ea0;
      a1 = a1 * sc + ea1;
      m = mn;
    }
    for (; t < nv; t++) {
      int src = __shfl(pk, t, 64) & 0xFFFFF;
      uint32_t wu = *(const uint32_t*)(xlr + (size_t)src * 256 + c0);
      float ux = bf2f((unsigned short)(wu & 0xffff));
      float uy = bf2f((unsigned short)(wu >> 16));
      float p = lrelu(ux + xr0) * att0 + lrelu(uy + xr1) * att1;
      #pragma unroll
      for (int off = 32; off > 0; off >>= 1) p += __shfl_xor(p, off, 64);
      float mn = fmaxf(m, p);
      float sc = __expf(m - mn), w = __expf(p - mn);
      s = s * sc + w;
      a0 = a0 * sc + w * ux;
      a1 = a1 * sc + w * uy;
      m = mn;
    }
  }
  float inv = 1.f / s;
  out[(size_t)wid * H1 + c0] = a0 * inv + bias2[c0];
  out[(size_t)wid * H1 + c0 + 1] = a1 * inv + bias2[c0 + 1];
}

extern "C" void kernel_launch(void* const* d_in, const int* in_sizes, int n_in,
                              void* d_out, int out_size, void* d_ws, size_t ws_size,
                              hipStream_t stream) {
  const float* nf    = (const float*)d_in[0];
  const int*   ei    = (const int*)d_in[1];
  const int*   et    = (const int*)d_in[3];
  const float* basis = (const float*)d_in[4];
  const float* comp  = (const float*)d_in[5];
  const float* root  = (const float*)d_in[6];
  const float* bias1 = (const float*)d_in[7];
  const float* w_l   = (const float*)d_in[8];
  const float* w_r   = (const float*)d_in[9];
  const float* att   = (const float*)d_in[10];
  const float* bias2 = (const float*)d_in[11];
  float* out = (float*)d_out;

  char* ws = (char*)d_ws;
  unsigned short* xr_bf  = (unsigned short*)ws;                    // [NN][1024] 102.4 MB
  unsigned short* nf_bf  = (unsigned short*)(ws + 102400000);      // [NN][256]  25.6 MB
  unsigned short* wrb_t  = (unsigned short*)(ws + 128000000);      // [1024][256]
  unsigned short* root_t = (unsigned short*)(ws + 128524288);      // [128][256]
  unsigned short* wcat_t = (unsigned short*)(ws + 128589824);      // [256][128]
  unsigned short* agg_bf = (unsigned short*)(ws + 128655360);      // [NN][128] bf16
  int*            deg    = (int*)(ws + 154255360);
  int*            cursor = deg + NN;
  int*            rowptr = cursor + NN;
  int*            csr    = rowptr + NN + 1;
  int*            parts  = csr + NE;
  // overlays into xr region (dead after k_rgcn):
  unsigned short* x1_bf  = (unsigned short*)ws;                    // [NN][128] bf16
  unsigned short* xlr_bf = (unsigned short*)(ws + 12800000);       // [NN][256] bf16 = [xl|xrt]

  hipMemsetAsync(deg, 0, 2 * NN * sizeof(int), stream);

  k_cast<<<(NN * GD / 8) / 256, 256, 0, stream>>>(nf, nf_bf);
  k_wr<<<(XRLD * GD) / 256, 256, 0, stream>>>(basis, comp, wrb_t);
  k_prep<<<65536 / 256, 256, 0, stream>>>(root, w_l, w_r, root_t, wcat_t);

  const int GY = (NN + 127) / 128;    // 391
  const int GY64 = (NN + 63) / 64;    // 782
  k_mgemm<256, 4><<<8 * GY, 256, 32768, stream>>>(
      nf_bf, wrb_t, xr_bf, nullptr, nullptr, NN, XRLD, 8);

  k_deg<<<(NE + 255) / 256, 256, 0, stream>>>(ei, deg);
  k_scan_a<<<NCHUNKS, 256, 0, stream>>>(deg, parts);
  k_scan_b<<<1, 64, 0, stream>>>(parts);
  k_scan_c<<<NCHUNKS, 256, 0, stream>>>(deg, parts, rowptr);
  k_scatter<<<(NE + 255) / 256, 256, 0, stream>>>(ei, et, rowptr, cursor, csr);

  k_rgcn<<<(NN + 3) / 4, 256, 0, stream>>>(xr_bf, csr, rowptr, agg_bf);

  k_mgemm<256, 2><<<GY64, 256, 24576, stream>>>(
      nf_bf, root_t, x1_bf, agg_bf, bias1, NN, H1, 1);

  k_mgemm<128, 4><<<2 * GY, 256, 32768, stream>>>(
      x1_bf, wcat_t, xlr_bf, nullptr, nullptr, NN, 2 * H2, 2);

  k_gat<<<(NN + 3) / 4, 256, 0, stream>>>(xlr_bf, csr, rowptr, att, bias2, out);
}

// Round 7
// 293.767 us; speedup vs baseline: 2.3811x; 1.0393x over previous
//
#include <hip/hip_runtime.h>
#include <hip/hip_bf16.h>
#include <cstdint>
#include <cstddef>

#define NN 50000
#define NE 500000
#define GD 256
#define H1 128
#define H2 128
#define NREL 8
#define NBASES 30
#define XRLD (NREL * H1)   // 1024
#define NCHUNKS ((NN + 1023) / 1024)  // 49

typedef __attribute__((ext_vector_type(8))) short bf16x8;
typedef __attribute__((ext_vector_type(4))) float f32x4;
typedef __attribute__((ext_vector_type(8))) unsigned short u16x8;

__device__ __forceinline__ float lrelu(float x) { return x > 0.f ? x : 0.2f * x; }

__device__ __forceinline__ unsigned short f2bf(float x) {
  union { float f; uint32_t u; } v; v.f = x;
  uint32_t r = v.u + 0x7FFF + ((v.u >> 16) & 1);
  return (unsigned short)(r >> 16);
}
__device__ __forceinline__ float bf2f(unsigned short u) {
  union { uint32_t u; float f; } v; v.u = ((uint32_t)u) << 16;
  return v.f;
}

template <int N>
__device__ __forceinline__ void wait_vmcnt() {
  asm volatile("s_waitcnt vmcnt(%0)" :: "n"(N) : "memory");
}

// ---- cast nf fp32 -> bf16 ----
__global__ void k_cast(const float* __restrict__ in, unsigned short* __restrict__ out) {
  int i = blockIdx.x * 256 + threadIdx.x;
  const float4* p = (const float4*)(in + (size_t)i * 8);
  float4 a = p[0], b = p[1];
  u16x8 r;
  r[0] = f2bf(a.x); r[1] = f2bf(a.y); r[2] = f2bf(a.z); r[3] = f2bf(a.w);
  r[4] = f2bf(b.x); r[5] = f2bf(b.y); r[6] = f2bf(b.z); r[7] = f2bf(b.w);
  *(u16x8*)(out + (size_t)i * 8) = r;
}

// ---- wrb_t[n][k] bf16 [1024][256] ----
__global__ void k_wr(const float* __restrict__ basis, const float* __restrict__ comp,
                     unsigned short* __restrict__ wrb_t) {
  int idx = blockIdx.x * 256 + threadIdx.x;
  int n = idx >> 8;
  int k = idx & 255;
  int r = n >> 7, o = n & 127;
  float acc = 0.f;
  #pragma unroll
  for (int b = 0; b < NBASES; b++)
    acc += comp[r * NBASES + b] * basis[((size_t)b * GD + k) * H1 + o];
  wrb_t[idx] = f2bf(acc);
}

// ---- root_t[128][256] bf16; wcat_t[256][128] bf16 ([w_l|w_r] as Bt) ----
__global__ void k_prep(const float* __restrict__ root, const float* __restrict__ w_l,
                       const float* __restrict__ w_r, unsigned short* __restrict__ root_t,
                       unsigned short* __restrict__ wcat_t) {
  int idx = blockIdx.x * 256 + threadIdx.x;   // 65536
  if (idx < 32768) {
    int n = idx >> 8, k = idx & 255;
    root_t[idx] = f2bf(root[k * H1 + n]);
  } else {
    int j = idx - 32768;
    int n = j >> 7, k = j & 127;
    wcat_t[j] = f2bf(n < H2 ? w_l[k * H2 + n] : w_r[k * H2 + (n - H2)]);
  }
}

// ---- bf16 MFMA GEMM: BK=32, TRIPLE-buffered global_load_lds, counted vmcnt ----
// C[M][N](bf16) = A[M][K] @ Bt[N][K]^T (+bf16 addend +bias). 1D grid = gx*gy.
// BM = MBF*32 (MBF=2). LDS: A[3][BM*32] | B[3][128*32]; reused as Cs[BM][128].
template <int K, int MBF>
__global__ __launch_bounds__(256, 4)
void k_mgemm(const unsigned short* __restrict__ A, const unsigned short* __restrict__ Bt,
             unsigned short* __restrict__ C, const unsigned short* __restrict__ addend,
             const float* __restrict__ bias, int M, int N, int gx) {
  constexpr int BM = MBF * 32;
  constexpr int ACH = BM * 4;            // A 16B-chunks per slice
  constexpr int TCH = ACH + 512;         // + B chunks (128 rows x 4)
  constexpr int LPT = TCH / 256;         // loads per thread per stage
  constexpr int NS = K / 32;
  constexpr int ABUF = BM * 32;          // elems
  constexpr int BBUF = 128 * 32;
  extern __shared__ unsigned short lds[];
  const int tid = threadIdx.x;
  const int lane = tid & 63;
  const int wave = tid >> 6;

  // bijective XCD swizzle (m204)
  const int nwg = gridDim.x;
  const int q = nwg >> 3, r = nwg & 7;
  const int xcd = blockIdx.x & 7, bi = blockIdx.x >> 3;
  const int wg = (xcd < r ? xcd * (q + 1) : r * (q + 1) + (xcd - r) * q) + bi;
  const int bx = wg % gx;
  const int by = wg / gx;
  const int row0 = by * BM;
  const int colb = bx * 128;
  const int wcol = (wave & 1) * 64;
  const int wrow = (wave >> 1) * (MBF * 16);
  const int lr = lane & 15;
  const int lko = lane >> 4;

  f32x4 acc[MBF][4];
  #pragma unroll
  for (int i = 0; i < MBF; i++)
    #pragma unroll
    for (int j = 0; j < 4; j++) acc[i][j] = (f32x4){0.f, 0.f, 0.f, 0.f};

  // stage one BK=32 slice into buffer b; linear LDS dest, inv-swizzled source.
  auto stage = [&](int k0, int b) {
    unsigned short* as = lds + b * ABUF;
    unsigned short* bs = lds + 3 * ABUF + b * BBUF;
    #pragma unroll
    for (int it = 0; it < LPT; it++) {
      int ci = it * 256 + tid;
      if (ci < ACH) {
        int row = ci >> 2, cs = ci & 3;
        int s = (row & 3) ^ ((row >> 2) & 3);
        int gm = row0 + row; if (gm >= M) gm = M - 1;
        const unsigned short* gp = A + (size_t)gm * K + k0 + ((cs ^ s) << 3);
        __builtin_amdgcn_global_load_lds(
            (const __attribute__((address_space(1))) void*)gp,
            (__attribute__((address_space(3))) void*)(as + (size_t)ci * 8), 16, 0, 0);
      } else {
        int cj = ci - ACH;
        int row = cj >> 2, cs = cj & 3;
        int s = (row & 3) ^ ((row >> 2) & 3);
        const unsigned short* gp = Bt + (size_t)(colb + row) * K + k0 + ((cs ^ s) << 3);
        __builtin_amdgcn_global_load_lds(
            (const __attribute__((address_space(1))) void*)gp,
            (__attribute__((address_space(3))) void*)(bs + (size_t)cj * 8), 16, 0, 0);
      }
    }
  };

  auto compute = [&](int b) {
    const unsigned short* as = lds + b * ABUF;
    const unsigned short* bs = lds + 3 * ABUF + b * BBUF;
    bf16x8 af[MBF], bfr[4];
    #pragma unroll
    for (int mb = 0; mb < MBF; mb++) {
      int rowL = wrow + mb * 16 + lr;
      int s = (rowL & 3) ^ ((rowL >> 2) & 3);
      af[mb] = *(const bf16x8*)&as[rowL * 32 + ((lko ^ s) << 3)];
    }
    #pragma unroll
    for (int nb = 0; nb < 4; nb++) {
      int colL = wcol + nb * 16 + lr;
      int s = (colL & 3) ^ ((colL >> 2) & 3);
      bfr[nb] = *(const bf16x8*)&bs[colL * 32 + ((lko ^ s) << 3)];
    }
    #pragma unroll
    for (int mb = 0; mb < MBF; mb++)
      #pragma unroll
      for (int nb = 0; nb < 4; nb++)
        acc[mb][nb] = __builtin_amdgcn_mfma_f32_16x16x32_bf16(af[mb], bfr[nb], acc[mb][nb], 0, 0, 0);
  };

  // prologue: two stages in flight, wait for the first only
  stage(0, 0);
  stage(32, 1);
  wait_vmcnt<LPT>();
  __builtin_amdgcn_sched_barrier(0);
  __builtin_amdgcn_s_barrier();

  #pragma unroll
  for (int s = 0; s < NS; s++) {
    if (s + 2 < NS) stage((s + 2) * 32, (s + 2) % 3);
    compute(s % 3);
    if (s + 1 < NS) {
      if (s + 2 < NS) wait_vmcnt<LPT>();   // stage(s+1) landed; s+2 in flight
      else            wait_vmcnt<0>();     // drain last stage
      __builtin_amdgcn_sched_barrier(0);
      __builtin_amdgcn_s_barrier();
    }
  }

  // ---- epilogue: acc (+addend +bias) -> swizzled Cs -> coalesced store ----
  __syncthreads();
  unsigned short* Cs = lds;                // [BM][128] bf16
  const int orow = lko * 4;
  #pragma unroll
  for (int mb = 0; mb < MBF; mb++) {
    #pragma unroll
    for (int i = 0; i < 4; i++) {
      int row = wrow + mb * 16 + orow + i;
      int grow = row0 + row;
      #pragma unroll
      for (int nb = 0; nb < 4; nb++) {
        int col = wcol + nb * 16 + lr;
        float v = acc[mb][nb][i];
        if (addend && grow < M) v += bf2f(addend[(size_t)grow * N + colb + col]);
        if (bias) v += bias[colb + col];
        int idx = row * 128 + col;
        Cs[idx ^ (((row >> 2) & 7) << 4)] = f2bf(v);
      }
    }
  }
  __syncthreads();
  #pragma unroll
  for (int it = 0; it < BM / 16; it++) {
    int off = it * 256 + tid;
    int row = off >> 4, jb = off & 15;
    int grow = row0 + row;
    if (grow < M) {
      int idx = (row * 128 + jb * 8) ^ (((row >> 2) & 7) << 4);
      *(u16x8*)&C[(size_t)grow * N + colb + jb * 8] = *(const u16x8*)&Cs[idx];
    }
  }
}

// ---- CSR build ----
__global__ void k_deg(const int* __restrict__ ei, int* __restrict__ deg) {
  int e = blockIdx.x * 256 + threadIdx.x;
  if (e < NE) atomicAdd(&deg[ei[NE + e]], 1);
}

__global__ void k_scan_a(const int* __restrict__ deg, int* __restrict__ parts) {
  __shared__ int lds[256];
  int t = threadIdx.x;
  int base = blockIdx.x * 1024 + t * 4;
  int s = 0;
  #pragma unroll
  for (int j = 0; j < 4; j++) s += (base + j < NN) ? deg[base + j] : 0;
  lds[t] = s;
  __syncthreads();
  for (int st = 128; st > 0; st >>= 1) {
    if (t < st) lds[t] += lds[t + st];
    __syncthreads();
  }
  if (t == 0) parts[blockIdx.x] = lds[0];
}

__global__ void k_scan_b(int* __restrict__ parts) {
  int t = threadIdx.x;   // 64 threads
  int v = (t < NCHUNKS) ? parts[t] : 0;
  int x = v;
  #pragma unroll
  for (int off = 1; off < 64; off <<= 1) {
    int y = __shfl_up(x, off, 64);
    if (t >= off) x += y;
  }
  if (t < NCHUNKS) parts[t] = x - v;
}

__global__ void k_scan_c(const int* __restrict__ deg, const int* __restrict__ parts,
                         int* __restrict__ rowptr) {
  __shared__ int lds[256];
  int t = threadIdx.x;
  int base = blockIdx.x * 1024 + t * 4;
  int v[4];
  int s = 0;
  #pragma unroll
  for (int j = 0; j < 4; j++) { v[j] = (base + j < NN) ? deg[base + j] : 0; s += v[j]; }
  lds[t] = s;
  __syncthreads();
  for (int st = 1; st < 256; st <<= 1) {
    int add = (t >= st) ? lds[t - st] : 0;
    __syncthreads();
    lds[t] += add;
    __syncthreads();
  }
  int excl = lds[t] - s;
  int off = parts[blockIdx.x];
  int run = 0;
  #pragma unroll
  for (int j = 0; j < 4; j++) {
    run += v[j];
    if (base + j < NN) rowptr[base + j + 1] = off + excl + run;
  }
  if (blockIdx.x == 0 && t == 0) rowptr[0] = 0;
}

// pack (src | type<<20) into csr entries
__global__ void k_scatter(const int* __restrict__ ei, const int* __restrict__ et,
                          const int* __restrict__ rowptr, int* __restrict__ cursor,
                          int* __restrict__ csr) {
  int e = blockIdx.x * 256 + threadIdx.x;
  if (e < NE) {
    int d = ei[NE + e];
    int pos = atomicAdd(&cursor[d], 1);
    csr[rowptr[d] + pos] = ei[e] | (et[e] << 20);
  }
}

// ---- RGCN aggregation: one wave per dst, 8-batched lane-broadcast edges ----
__global__ __launch_bounds__(256)
void k_rgcn(const unsigned short* __restrict__ xr, const int* __restrict__ csr2,
            const int* __restrict__ rowptr, unsigned short* __restrict__ agg) {
  int wid = (blockIdx.x * 256 + threadIdx.x) >> 6;
  int lane = threadIdx.x & 63;
  if (wid >= NN) return;
  int c0 = lane * 2;
  float acc0[NREL], acc1[NREL], cnt[NREL];
  #pragma unroll
  for (int r = 0; r < NREL; r++) { acc0[r] = 0.f; acc1[r] = 0.f; cnt[r] = 0.f; }
  int beg = rowptr[wid], end = rowptr[wid + 1];
  for (int j0 = beg; j0 < end; j0 += 64) {
    int nv = end - j0; if (nv > 64) nv = 64;
    int pk = (lane < nv) ? csr2[j0 + lane] : 0;
    int t = 0;
    for (; t + 8 <= nv; t += 8) {
      uint32_t wv[8]; int rt[8];
      #pragma unroll
      for (int z = 0; z < 8; z++) {
        int p = __shfl(pk, t + z, 64);
        int s = p & 0xFFFFF;
        rt[z] = p >> 20;
        wv[z] = *(const uint32_t*)(xr + (size_t)s * XRLD + rt[z] * H1 + c0);
      }
      #pragma unroll
      for (int z = 0; z < 8; z++) {
        float vx = bf2f((unsigned short)(wv[z] & 0xffff));
        float vy = bf2f((unsigned short)(wv[z] >> 16));
        #pragma unroll
        for (int rr = 0; rr < NREL; rr++) {
          bool hit = (rt[z] == rr);
          acc0[rr] += hit ? vx : 0.f;
          acc1[rr] += hit ? vy : 0.f;
          cnt[rr] += hit ? 1.f : 0.f;
        }
      }
    }
    for (; t < nv; t++) {
      int p = __shfl(pk, t, 64);
      int s = p & 0xFFFFF;
      int rt = p >> 20;
      uint32_t w = *(const uint32_t*)(xr + (size_t)s * XRLD + rt * H1 + c0);
      float vx = bf2f((unsigned short)(w & 0xffff));
      float vy = bf2f((unsigned short)(w >> 16));
      #pragma unroll
      for (int rr = 0; rr < NREL; rr++) {
        bool hit = (rt == rr);
        acc0[rr] += hit ? vx : 0.f;
        acc1[rr] += hit ? vy : 0.f;
        cnt[rr] += hit ? 1.f : 0.f;
      }
    }
  }
  float o0 = 0.f, o1 = 0.f;
  #pragma unroll
  for (int rr = 0; rr < NREL; rr++) {
    float inv = 1.f / fmaxf(cnt[rr], 1.f);
    o0 += acc0[rr] * inv;
    o1 += acc1[rr] * inv;
  }
  uint32_t packed = (uint32_t)f2bf(o0) | ((uint32_t)f2bf(o1) << 16);
  *(uint32_t*)&agg[(size_t)wid * H1 + c0] = packed;
}

// ---- GATv2: one wave per dst, 8-batched edges, chunked online softmax ----
__global__ __launch_bounds__(256)
void k_gat(const unsigned short* __restrict__ xlr, const int* __restrict__ csr2,
           const int* __restrict__ rowptr, const float* __restrict__ att,
           const float* __restrict__ bias2, float* __restrict__ out) {
  int wid = (blockIdx.x * 256 + threadIdx.x) >> 6;
  int lane = threadIdx.x & 63;
  if (wid >= NN) return;
  int c0 = lane * 2;
  float att0 = att[c0], att1 = att[c0 + 1];
  uint32_t wr2 = *(const uint32_t*)(xlr + (size_t)wid * 256 + 128 + c0);
  float xr0 = bf2f((unsigned short)(wr2 & 0xffff));
  float xr1 = bf2f((unsigned short)(wr2 >> 16));
  uint32_t wv0 = *(const uint32_t*)(xlr + (size_t)wid * 256 + c0);
  float vx = bf2f((unsigned short)(wv0 & 0xffff));
  float vy = bf2f((unsigned short)(wv0 >> 16));
  float ep = lrelu(vx + xr0) * att0 + lrelu(vy + xr1) * att1;
  #pragma unroll
  for (int off = 32; off > 0; off >>= 1) ep += __shfl_xor(ep, off, 64);
  float m = ep, s = 1.f, a0 = vx, a1 = vy;
  int beg = rowptr[wid], end = rowptr[wid + 1];
  for (int j0 = beg; j0 < end; j0 += 64) {
    int nv = end - j0; if (nv > 64) nv = 64;
    int pk = (lane < nv) ? csr2[j0 + lane] : 0;
    int t = 0;
    for (; t + 8 <= nv; t += 8) {
      float ux[8], uy[8], p[8];
      #pragma unroll
      for (int z = 0; z < 8; z++) {
        int src = __shfl(pk, t + z, 64) & 0xFFFFF;
        uint32_t wu = *(const uint32_t*)(xlr + (size_t)src * 256 + c0);
        ux[z] = bf2f((unsigned short)(wu & 0xffff));
        uy[z] = bf2f((unsigned short)(wu >> 16));
      }
      #pragma unroll
      for (int z = 0; z < 8; z++)
        p[z] = lrelu(ux[z] + xr0) * att0 + lrelu(uy[z] + xr1) * att1;
      #pragma unroll
      for (int off = 32; off > 0; off >>= 1) {
        #pragma unroll
        for (int z = 0; z < 8; z++) p[z] += __shfl_xor(p[z], off, 64);
      }
      float pm = p[0];
      #pragma unroll
      for (int z = 1; z < 8; z++) pm = fmaxf(pm, p[z]);
      float mn = fmaxf(m, pm);
      float sc = __expf(m - mn);
      float e[8];
      #pragma unroll
      for (int z = 0; z < 8; z++) e[z] = __expf(p[z] - mn);
      float es = 0.f, ea0 = 0.f, ea1 = 0.f;
      #pragma unroll
      for (int z = 0; z < 8; z++) { es += e[z]; ea0 += e[z] * ux[z]; ea1 += e[z] * uy[z]; }
      s = s * sc + es;
      a0 = a0 * sc + ea0;
      a1 = a1 * sc + ea1;
      m = mn;
    }
    for (; t < nv; t++) {
      int src = __shfl(pk, t, 64) & 0xFFFFF;
      uint32_t wu = *(const uint32_t*)(xlr + (size_t)src * 256 + c0);
      float ux = bf2f((unsigned short)(wu & 0xffff));
      float uy = bf2f((unsigned short)(wu >> 16));
      float p = lrelu(ux + xr0) * att0 + lrelu(uy + xr1) * att1;
      #pragma unroll
      for (int off = 32; off > 0; off >>= 1) p += __shfl_xor(p, off, 64);
      float mn = fmaxf(m, p);
      float sc = __expf(m - mn), w = __expf(p - mn);
      s = s * sc + w;
      a0 = a0 * sc + w * ux;
      a1 = a1 * sc + w * uy;
      m = mn;
    }
  }
  float inv = 1.f / s;
  out[(size_t)wid * H1 + c0] = a0 * inv + bias2[c0];
  out[(size_t)wid * H1 + c0 + 1] = a1 * inv + bias2[c0 + 1];
}

extern "C" void kernel_launch(void* const* d_in, const int* in_sizes, int n_in,
                              void* d_out, int out_size, void* d_ws, size_t ws_size,
                              hipStream_t stream) {
  const float* nf    = (const float*)d_in[0];
  const int*   ei    = (const int*)d_in[1];
  const int*   et    = (const int*)d_in[3];
  const float* basis = (const float*)d_in[4];
  const float* comp  = (const float*)d_in[5];
  const float* root  = (const float*)d_in[6];
  const float* bias1 = (const float*)d_in[7];
  const float* w_l   = (const float*)d_in[8];
  const float* w_r   = (const float*)d_in[9];
  const float* att   = (const float*)d_in[10];
  const float* bias2 = (const float*)d_in[11];
  float* out = (float*)d_out;

  char* ws = (char*)d_ws;
  unsigned short* xr_bf  = (unsigned short*)ws;                    // [NN][1024] 102.4 MB
  unsigned short* nf_bf  = (unsigned short*)(ws + 102400000);      // [NN][256]  25.6 MB
  unsigned short* wrb_t  = (unsigned short*)(ws + 128000000);      // [1024][256]
  unsigned short* root_t = (unsigned short*)(ws + 128524288);      // [128][256]
  unsigned short* wcat_t = (unsigned short*)(ws + 128589824);      // [256][128]
  unsigned short* agg_bf = (unsigned short*)(ws + 128655360);      // [NN][128] bf16
  int*            deg    = (int*)(ws + 154255360);
  int*            cursor = deg + NN;
  int*            rowptr = cursor + NN;
  int*            csr    = rowptr + NN + 1;
  int*            parts  = csr + NE;
  // overlays into xr region (dead after k_rgcn):
  unsigned short* x1_bf  = (unsigned short*)ws;                    // [NN][128] bf16
  unsigned short* xlr_bf = (unsigned short*)(ws + 12800000);       // [NN][256] bf16 = [xl|xrt]

  hipMemsetAsync(deg, 0, 2 * NN * sizeof(int), stream);

  k_cast<<<(NN * GD / 8) / 256, 256, 0, stream>>>(nf, nf_bf);
  k_wr<<<(XRLD * GD) / 256, 256, 0, stream>>>(basis, comp, wrb_t);
  k_prep<<<65536 / 256, 256, 0, stream>>>(root, w_l, w_r, root_t, wcat_t);

  const int GY64 = (NN + 63) / 64;    // 782
  const size_t LDSZ2 = (3 * 64 * 32 + 3 * 128 * 32) * 2;  // 36864 B

  k_mgemm<256, 2><<<8 * GY64, 256, LDSZ2, stream>>>(
      nf_bf, wrb_t, xr_bf, nullptr, nullptr, NN, XRLD, 8);

  k_deg<<<(NE + 255) / 256, 256, 0, stream>>>(ei, deg);
  k_scan_a<<<NCHUNKS, 256, 0, stream>>>(deg, parts);
  k_scan_b<<<1, 64, 0, stream>>>(parts);
  k_scan_c<<<NCHUNKS, 256, 0, stream>>>(deg, parts, rowptr);
  k_scatter<<<(NE + 255) / 256, 256, 0, stream>>>(ei, et, rowptr, cursor, csr);

  k_rgcn<<<(NN + 3) / 4, 256, 0, stream>>>(xr_bf, csr, rowptr, agg_bf);

  k_mgemm<256, 2><<<GY64, 256, LDSZ2, stream>>>(
      nf_bf, root_t, x1_bf, agg_bf, bias1, NN, H1, 1);

  k_mgemm<128, 2><<<2 * GY64, 256, LDSZ2, stream>>>(
      x1_bf, wcat_t, xlr_bf, nullptr, nullptr, NN, 2 * H2, 2);

  k_gat<<<(NN + 3) / 4, 256, 0, stream>>>(xlr_bf, csr, rowptr, att, bias2, out);
}

// Round 8
// 289.835 us; speedup vs baseline: 2.4134x; 1.0136x over previous
//
#include <hip/hip_runtime.h>
#include <hip/hip_bf16.h>
#include <cstdint>
#include <cstddef>

#define NN 50000
#define NE 500000
#define GD 256
#define H1 128
#define H2 128
#define NREL 8
#define NBASES 30
#define XRLD (NREL * H1)   // 1024
#define NCHUNKS ((NN + 1023) / 1024)  // 49

typedef __attribute__((ext_vector_type(8))) short bf16x8;
typedef __attribute__((ext_vector_type(4))) float f32x4;
typedef __attribute__((ext_vector_type(8))) unsigned short u16x8;

__device__ __forceinline__ float lrelu(float x) { return x > 0.f ? x : 0.2f * x; }

__device__ __forceinline__ unsigned short f2bf(float x) {
  union { float f; uint32_t u; } v; v.f = x;
  uint32_t r = v.u + 0x7FFF + ((v.u >> 16) & 1);
  return (unsigned short)(r >> 16);
}
__device__ __forceinline__ float bf2f(unsigned short u) {
  union { uint32_t u; float f; } v; v.u = ((uint32_t)u) << 16;
  return v.f;
}

template <int N>
__device__ __forceinline__ void wait_vmcnt() {
  asm volatile("s_waitcnt vmcnt(%0)" :: "n"(N) : "memory");
}

// ---- cast nf fp32 -> bf16 ----
__global__ void k_cast(const float* __restrict__ in, unsigned short* __restrict__ out) {
  int i = blockIdx.x * 256 + threadIdx.x;
  const float4* p = (const float4*)(in + (size_t)i * 8);
  float4 a = p[0], b = p[1];
  u16x8 r;
  r[0] = f2bf(a.x); r[1] = f2bf(a.y); r[2] = f2bf(a.z); r[3] = f2bf(a.w);
  r[4] = f2bf(b.x); r[5] = f2bf(b.y); r[6] = f2bf(b.z); r[7] = f2bf(b.w);
  *(u16x8*)(out + (size_t)i * 8) = r;
}

// ---- wrb_t[n][k] bf16 [1024][256] ----
__global__ void k_wr(const float* __restrict__ basis, const float* __restrict__ comp,
                     unsigned short* __restrict__ wrb_t) {
  int idx = blockIdx.x * 256 + threadIdx.x;
  int n = idx >> 8;
  int k = idx & 255;
  int r = n >> 7, o = n & 127;
  float acc = 0.f;
  #pragma unroll
  for (int b = 0; b < NBASES; b++)
    acc += comp[r * NBASES + b] * basis[((size_t)b * GD + k) * H1 + o];
  wrb_t[idx] = f2bf(acc);
}

// ---- root_t[128][256] bf16; wcat_t[256][128] bf16 ([w_l|w_r] as Bt) ----
__global__ void k_prep(const float* __restrict__ root, const float* __restrict__ w_l,
                       const float* __restrict__ w_r, unsigned short* __restrict__ root_t,
                       unsigned short* __restrict__ wcat_t) {
  int idx = blockIdx.x * 256 + threadIdx.x;   // 65536
  if (idx < 32768) {
    int n = idx >> 8, k = idx & 255;
    root_t[idx] = f2bf(root[k * H1 + n]);
  } else {
    int j = idx - 32768;
    int n = j >> 7, k = j & 127;
    wcat_t[j] = f2bf(n < H2 ? w_l[k * H2 + n] : w_r[k * H2 + (n - H2)]);
  }
}

// ---- bf16 MFMA GEMM: BK=32, TRIPLE-buffered global_load_lds, counted vmcnt ----
template <int K, int MBF>
__global__ __launch_bounds__(256, 4)
void k_mgemm(const unsigned short* __restrict__ A, const unsigned short* __restrict__ Bt,
             unsigned short* __restrict__ C, const unsigned short* __restrict__ addend,
             const float* __restrict__ bias, int M, int N, int gx) {
  constexpr int BM = MBF * 32;
  constexpr int ACH = BM * 4;            // A 16B-chunks per slice
  constexpr int TCH = ACH + 512;         // + B chunks (128 rows x 4)
  constexpr int LPT = TCH / 256;         // loads per thread per stage
  constexpr int NS = K / 32;
  constexpr int ABUF = BM * 32;          // elems
  constexpr int BBUF = 128 * 32;
  extern __shared__ unsigned short lds[];
  const int tid = threadIdx.x;
  const int lane = tid & 63;
  const int wave = tid >> 6;

  // bijective XCD swizzle (m204)
  const int nwg = gridDim.x;
  const int q = nwg >> 3, r = nwg & 7;
  const int xcd = blockIdx.x & 7, bi = blockIdx.x >> 3;
  const int wg = (xcd < r ? xcd * (q + 1) : r * (q + 1) + (xcd - r) * q) + bi;
  const int bx = wg % gx;
  const int by = wg / gx;
  const int row0 = by * BM;
  const int colb = bx * 128;
  const int wcol = (wave & 1) * 64;
  const int wrow = (wave >> 1) * (MBF * 16);
  const int lr = lane & 15;
  const int lko = lane >> 4;

  f32x4 acc[MBF][4];
  #pragma unroll
  for (int i = 0; i < MBF; i++)
    #pragma unroll
    for (int j = 0; j < 4; j++) acc[i][j] = (f32x4){0.f, 0.f, 0.f, 0.f};

  auto stage = [&](int k0, int b) {
    unsigned short* as = lds + b * ABUF;
    unsigned short* bs = lds + 3 * ABUF + b * BBUF;
    #pragma unroll
    for (int it = 0; it < LPT; it++) {
      int ci = it * 256 + tid;
      if (ci < ACH) {
        int row = ci >> 2, cs = ci & 3;
        int s = (row & 3) ^ ((row >> 2) & 3);
        int gm = row0 + row; if (gm >= M) gm = M - 1;
        const unsigned short* gp = A + (size_t)gm * K + k0 + ((cs ^ s) << 3);
        __builtin_amdgcn_global_load_lds(
            (const __attribute__((address_space(1))) void*)gp,
            (__attribute__((address_space(3))) void*)(as + (size_t)ci * 8), 16, 0, 0);
      } else {
        int cj = ci - ACH;
        int row = cj >> 2, cs = cj & 3;
        int s = (row & 3) ^ ((row >> 2) & 3);
        const unsigned short* gp = Bt + (size_t)(colb + row) * K + k0 + ((cs ^ s) << 3);
        __builtin_amdgcn_global_load_lds(
            (const __attribute__((address_space(1))) void*)gp,
            (__attribute__((address_space(3))) void*)(bs + (size_t)cj * 8), 16, 0, 0);
      }
    }
  };

  auto compute = [&](int b) {
    const unsigned short* as = lds + b * ABUF;
    const unsigned short* bs = lds + 3 * ABUF + b * BBUF;
    bf16x8 af[MBF], bfr[4];
    #pragma unroll
    for (int mb = 0; mb < MBF; mb++) {
      int rowL = wrow + mb * 16 + lr;
      int s = (rowL & 3) ^ ((rowL >> 2) & 3);
      af[mb] = *(const bf16x8*)&as[rowL * 32 + ((lko ^ s) << 3)];
    }
    #pragma unroll
    for (int nb = 0; nb < 4; nb++) {
      int colL = wcol + nb * 16 + lr;
      int s = (colL & 3) ^ ((colL >> 2) & 3);
      bfr[nb] = *(const bf16x8*)&bs[colL * 32 + ((lko ^ s) << 3)];
    }
    #pragma unroll
    for (int mb = 0; mb < MBF; mb++)
      #pragma unroll
      for (int nb = 0; nb < 4; nb++)
        acc[mb][nb] = __builtin_amdgcn_mfma_f32_16x16x32_bf16(af[mb], bfr[nb], acc[mb][nb], 0, 0, 0);
  };

  stage(0, 0);
  stage(32, 1);
  wait_vmcnt<LPT>();
  __builtin_amdgcn_sched_barrier(0);
  __builtin_amdgcn_s_barrier();

  #pragma unroll
  for (int s = 0; s < NS; s++) {
    if (s + 2 < NS) stage((s + 2) * 32, (s + 2) % 3);
    compute(s % 3);
    if (s + 1 < NS) {
      if (s + 2 < NS) wait_vmcnt<LPT>();
      else            wait_vmcnt<0>();
      __builtin_amdgcn_sched_barrier(0);
      __builtin_amdgcn_s_barrier();
    }
  }

  __syncthreads();
  unsigned short* Cs = lds;                // [BM][128] bf16
  const int orow = lko * 4;
  #pragma unroll
  for (int mb = 0; mb < MBF; mb++) {
    #pragma unroll
    for (int i = 0; i < 4; i++) {
      int row = wrow + mb * 16 + orow + i;
      int grow = row0 + row;
      #pragma unroll
      for (int nb = 0; nb < 4; nb++) {
        int col = wcol + nb * 16 + lr;
        float v = acc[mb][nb][i];
        if (addend && grow < M) v += bf2f(addend[(size_t)grow * N + colb + col]);
        if (bias) v += bias[colb + col];
        int idx = row * 128 + col;
        Cs[idx ^ (((row >> 2) & 7) << 4)] = f2bf(v);
      }
    }
  }
  __syncthreads();
  #pragma unroll
  for (int it = 0; it < BM / 16; it++) {
    int off = it * 256 + tid;
    int row = off >> 4, jb = off & 15;
    int grow = row0 + row;
    if (grow < M) {
      int idx = (row * 128 + jb * 8) ^ (((row >> 2) & 7) << 4);
      *(u16x8*)&C[(size_t)grow * N + colb + jb * 8] = *(const u16x8*)&Cs[idx];
    }
  }
}

// ---- CSR build: degree + per-(dst,rel) counts ----
__global__ void k_deg(const int* __restrict__ ei, const int* __restrict__ et,
                      int* __restrict__ deg, int* __restrict__ cnt2) {
  int e = blockIdx.x * 256 + threadIdx.x;
  if (e < NE) {
    int d = ei[NE + e];
    atomicAdd(&deg[d], 1);
    atomicAdd(&cnt2[d * NREL + et[e]], 1);
  }
}

__global__ void k_scan_a(const int* __restrict__ deg, int* __restrict__ parts) {
  __shared__ int lds[256];
  int t = threadIdx.x;
  int base = blockIdx.x * 1024 + t * 4;
  int s = 0;
  #pragma unroll
  for (int j = 0; j < 4; j++) s += (base + j < NN) ? deg[base + j] : 0;
  lds[t] = s;
  __syncthreads();
  for (int st = 128; st > 0; st >>= 1) {
    if (t < st) lds[t] += lds[t + st];
    __syncthreads();
  }
  if (t == 0) parts[blockIdx.x] = lds[0];
}

__global__ void k_scan_b(int* __restrict__ parts) {
  int t = threadIdx.x;   // 64 threads
  int v = (t < NCHUNKS) ? parts[t] : 0;
  int x = v;
  #pragma unroll
  for (int off = 1; off < 64; off <<= 1) {
    int y = __shfl_up(x, off, 64);
    if (t >= off) x += y;
  }
  if (t < NCHUNKS) parts[t] = x - v;
}

__global__ void k_scan_c(const int* __restrict__ deg, const int* __restrict__ parts,
                         int* __restrict__ rowptr) {
  __shared__ int lds[256];
  int t = threadIdx.x;
  int base = blockIdx.x * 1024 + t * 4;
  int v[4];
  int s = 0;
  #pragma unroll
  for (int j = 0; j < 4; j++) { v[j] = (base + j < NN) ? deg[base + j] : 0; s += v[j]; }
  lds[t] = s;
  __syncthreads();
  for (int st = 1; st < 256; st <<= 1) {
    int add = (t >= st) ? lds[t - st] : 0;
    __syncthreads();
    lds[t] += add;
    __syncthreads();
  }
  int excl = lds[t] - s;
  int off = parts[blockIdx.x];
  int run = 0;
  #pragma unroll
  for (int j = 0; j < 4; j++) {
    run += v[j];
    if (base + j < NN) rowptr[base + j + 1] = off + excl + run;
  }
  if (blockIdx.x == 0 && t == 0) rowptr[0] = 0;
}

// pack (src | type<<20) and per-edge weight 1/cnt[dst,rel]
__global__ void k_scatter(const int* __restrict__ ei, const int* __restrict__ et,
                          const int* __restrict__ rowptr, const int* __restrict__ cnt2,
                          int* __restrict__ cursor, int* __restrict__ csr,
                          float* __restrict__ wgt) {
  int e = blockIdx.x * 256 + threadIdx.x;
  if (e < NE) {
    int d = ei[NE + e];
    int r = et[e];
    int pos = atomicAdd(&cursor[d], 1);
    int slot = rowptr[d] + pos;
    csr[slot] = ei[e] | (r << 20);
    wgt[slot] = 1.0f / (float)cnt2[d * NREL + r];
  }
}

// ---- RGCN aggregation: weighted sum (weights fold per-rel mean), 8-batched ----
__global__ __launch_bounds__(256)
void k_rgcn(const unsigned short* __restrict__ xr, const int* __restrict__ csr2,
            const float* __restrict__ wgt, const int* __restrict__ rowptr,
            unsigned short* __restrict__ agg) {
  int wid = (blockIdx.x * 256 + threadIdx.x) >> 6;
  int lane = threadIdx.x & 63;
  if (wid >= NN) return;
  int c0 = lane * 2;
  float acc0 = 0.f, acc1 = 0.f;
  int beg = rowptr[wid], end = rowptr[wid + 1];
  for (int j0 = beg; j0 < end; j0 += 64) {
    int nv = end - j0; if (nv > 64) nv = 64;
    int pk = (lane < nv) ? csr2[j0 + lane] : 0;
    float wk = (lane < nv) ? wgt[j0 + lane] : 0.f;
    int t = 0;
    for (; t + 8 <= nv; t += 8) {
      uint32_t wv[8]; float wz[8];
      #pragma unroll
      for (int z = 0; z < 8; z++) {
        int p = __shfl(pk, t + z, 64);
        wz[z] = __shfl(wk, t + z, 64);
        int off = (p & 0xFFFFF) * XRLD + (p >> 20) * H1;
        wv[z] = *(const uint32_t*)(xr + off + c0);
      }
      #pragma unroll
      for (int z = 0; z < 8; z++) {
        acc0 += wz[z] * bf2f((unsigned short)(wv[z] & 0xffff));
        acc1 += wz[z] * bf2f((unsigned short)(wv[z] >> 16));
      }
    }
    for (; t < nv; t++) {
      int p = __shfl(pk, t, 64);
      float w = __shfl(wk, t, 64);
      int off = (p & 0xFFFFF) * XRLD + (p >> 20) * H1;
      uint32_t wv = *(const uint32_t*)(xr + off + c0);
      acc0 += w * bf2f((unsigned short)(wv & 0xffff));
      acc1 += w * bf2f((unsigned short)(wv >> 16));
    }
  }
  uint32_t packed = (uint32_t)f2bf(acc0) | ((uint32_t)f2bf(acc1) << 16);
  *(uint32_t*)&agg[(size_t)wid * H1 + c0] = packed;
}

// ---- GATv2: one wave per dst, 8-batched edges, chunked online softmax ----
__global__ __launch_bounds__(256)
void k_gat(const unsigned short* __restrict__ xlr, const int* __restrict__ csr2,
           const int* __restrict__ rowptr, const float* __restrict__ att,
           const float* __restrict__ bias2, float* __restrict__ out) {
  int wid = (blockIdx.x * 256 + threadIdx.x) >> 6;
  int lane = threadIdx.x & 63;
  if (wid >= NN) return;
  int c0 = lane * 2;
  float att0 = att[c0], att1 = att[c0 + 1];
  uint32_t wr2 = *(const uint32_t*)(xlr + (size_t)wid * 256 + 128 + c0);
  float xr0 = bf2f((unsigned short)(wr2 & 0xffff));
  float xr1 = bf2f((unsigned short)(wr2 >> 16));
  uint32_t wv0 = *(const uint32_t*)(xlr + (size_t)wid * 256 + c0);
  float vx = bf2f((unsigned short)(wv0 & 0xffff));
  float vy = bf2f((unsigned short)(wv0 >> 16));
  float ep = lrelu(vx + xr0) * att0 + lrelu(vy + xr1) * att1;
  #pragma unroll
  for (int off = 32; off > 0; off >>= 1) ep += __shfl_xor(ep, off, 64);
  float m = ep, s = 1.f, a0 = vx, a1 = vy;
  int beg = rowptr[wid], end = rowptr[wid + 1];
  for (int j0 = beg; j0 < end; j0 += 64) {
    int nv = end - j0; if (nv > 64) nv = 64;
    int pk = (lane < nv) ? csr2[j0 + lane] : 0;
    int t = 0;
    for (; t + 8 <= nv; t += 8) {
      float ux[8], uy[8], p[8];
      #pragma unroll
      for (int z = 0; z < 8; z++) {
        int src = __shfl(pk, t + z, 64) & 0xFFFFF;
        uint32_t wu = *(const uint32_t*)(xlr + (size_t)src * 256 + c0);
        ux[z] = bf2f((unsigned short)(wu & 0xffff));
        uy[z] = bf2f((unsigned short)(wu >> 16));
      }
      #pragma unroll
      for (int z = 0; z < 8; z++)
        p[z] = lrelu(ux[z] + xr0) * att0 + lrelu(uy[z] + xr1) * att1;
      #pragma unroll
      for (int off = 32; off > 0; off >>= 1) {
        #pragma unroll
        for (int z = 0; z < 8; z++) p[z] += __shfl_xor(p[z], off, 64);
      }
      float pm = p[0];
      #pragma unroll
      for (int z = 1; z < 8; z++) pm = fmaxf(pm, p[z]);
      float mn = fmaxf(m, pm);
      float sc = __expf(m - mn);
      float e[8];
      #pragma unroll
      for (int z = 0; z < 8; z++) e[z] = __expf(p[z] - mn);
      float es = 0.f, ea0 = 0.f, ea1 = 0.f;
      #pragma unroll
      for (int z = 0; z < 8; z++) { es += e[z]; ea0 += e[z] * ux[z]; ea1 += e[z] * uy[z]; }
      s = s * sc + es;
      a0 = a0 * sc + ea0;
      a1 = a1 * sc + ea1;
      m = mn;
    }
    for (; t < nv; t++) {
      int src = __shfl(pk, t, 64) & 0xFFFFF;
      uint32_t wu = *(const uint32_t*)(xlr + (size_t)src * 256 + c0);
      float ux = bf2f((unsigned short)(wu & 0xffff));
      float uy = bf2f((unsigned short)(wu >> 16));
      float p = lrelu(ux + xr0) * att0 + lrelu(uy + xr1) * att1;
      #pragma unroll
      for (int off = 32; off > 0; off >>= 1) p += __shfl_xor(p, off, 64);
      float mn = fmaxf(m, p);
      float sc = __expf(m - mn), w = __expf(p - mn);
      s = s * sc + w;
      a0 = a0 * sc + w * ux;
      a1 = a1 * sc + w * uy;
      m = mn;
    }
  }
  float inv = 1.f / s;
  out[(size_t)wid * H1 + c0] = a0 * inv + bias2[c0];
  out[(size_t)wid * H1 + c0 + 1] = a1 * inv + bias2[c0 + 1];
}

extern "C" void kernel_launch(void* const* d_in, const int* in_sizes, int n_in,
                              void* d_out, int out_size, void* d_ws, size_t ws_size,
                              hipStream_t stream) {
  const float* nf    = (const float*)d_in[0];
  const int*   ei    = (const int*)d_in[1];
  const int*   et    = (const int*)d_in[3];
  const float* basis = (const float*)d_in[4];
  const float* comp  = (const float*)d_in[5];
  const float* root  = (const float*)d_in[6];
  const float* bias1 = (const float*)d_in[7];
  const float* w_l   = (const float*)d_in[8];
  const float* w_r   = (const float*)d_in[9];
  const float* att   = (const float*)d_in[10];
  const float* bias2 = (const float*)d_in[11];
  float* out = (float*)d_out;

  char* ws = (char*)d_ws;
  unsigned short* xr_bf  = (unsigned short*)ws;                    // [NN][1024] 102.4 MB
  unsigned short* nf_bf  = (unsigned short*)(ws + 102400000);      // [NN][256]  25.6 MB
  unsigned short* wrb_t  = (unsigned short*)(ws + 128000000);      // [1024][256]
  unsigned short* root_t = (unsigned short*)(ws + 128524288);      // [128][256]
  unsigned short* wcat_t = (unsigned short*)(ws + 128589824);      // [256][128]
  unsigned short* agg_bf = (unsigned short*)(ws + 128655360);      // [NN][128] bf16
  int*            deg    = (int*)(ws + 154255360);                 // [NN]
  int*            cursor = deg + NN;                               // [NN]
  int*            cnt2   = cursor + NN;                            // [NN*8]
  int*            rowptr = cnt2 + NN * NREL;                       // [NN+1]
  int*            csr    = rowptr + NN + 1;                        // [NE]
  int*            parts  = csr + NE;                               // [NCHUNKS]
  float*          wgt    = (float*)(parts + 64);                   // [NE]
  // overlays into xr region (dead after k_rgcn):
  unsigned short* x1_bf  = (unsigned short*)ws;                    // [NN][128] bf16
  unsigned short* xlr_bf = (unsigned short*)(ws + 12800000);       // [NN][256] bf16

  hipMemsetAsync(deg, 0, (2 + NREL) * NN * sizeof(int), stream);   // deg+cursor+cnt2

  k_cast<<<(NN * GD / 8) / 256, 256, 0, stream>>>(nf, nf_bf);
  k_wr<<<(XRLD * GD) / 256, 256, 0, stream>>>(basis, comp, wrb_t);
  k_prep<<<65536 / 256, 256, 0, stream>>>(root, w_l, w_r, root_t, wcat_t);

  const int GY64 = (NN + 63) / 64;    // 782
  const size_t LDSZ2 = (3 * 64 * 32 + 3 * 128 * 32) * 2;  // 36864 B

  k_mgemm<256, 2><<<8 * GY64, 256, LDSZ2, stream>>>(
      nf_bf, wrb_t, xr_bf, nullptr, nullptr, NN, XRLD, 8);

  k_deg<<<(NE + 255) / 256, 256, 0, stream>>>(ei, et, deg, cnt2);
  k_scan_a<<<NCHUNKS, 256, 0, stream>>>(deg, parts);
  k_scan_b<<<1, 64, 0, stream>>>(parts);
  k_scan_c<<<NCHUNKS, 256, 0, stream>>>(deg, parts, rowptr);
  k_scatter<<<(NE + 255) / 256, 256, 0, stream>>>(ei, et, rowptr, cnt2, cursor, csr, wgt);

  k_rgcn<<<(NN + 3) / 4, 256, 0, stream>>>(xr_bf, csr, wgt, rowptr, agg_bf);

  k_mgemm<256, 2><<<GY64, 256, LDSZ2, stream>>>(
      nf_bf, root_t, x1_bf, agg_bf, bias1, NN, H1, 1);

  k_mgemm<128, 2><<<2 * GY64, 256, LDSZ2, stream>>>(
      x1_bf, wcat_t, xlr_bf, nullptr, nullptr, NN, 2 * H2, 2);

  k_gat<<<(NN + 3) / 4, 256, 0, stream>>>(xlr_bf, csr, rowptr, att, bias2, out);
}

// Round 10
// 285.299 us; speedup vs baseline: 2.4518x; 1.0159x over previous
//
#include <hip/hip_runtime.h>
#include <hip/hip_bf16.h>
#include <cstdint>
#include <cstddef>

#define NN 50000
#define NE 500000
#define GD 256
#define H1 128
#define H2 128
#define NREL 8
#define NBASES 30
#define XRLD (NREL * H1)   // 1024
#define NCHUNKS ((NN + 1023) / 1024)  // 49

typedef __attribute__((ext_vector_type(8))) short bf16x8;
typedef __attribute__((ext_vector_type(4))) float f32x4;
typedef __attribute__((ext_vector_type(8))) unsigned short u16x8;

__device__ __forceinline__ float lrelu(float x) { return x > 0.f ? x : 0.2f * x; }

__device__ __forceinline__ unsigned short f2bf(float x) {
  union { float f; uint32_t u; } v; v.f = x;
  uint32_t r = v.u + 0x7FFF + ((v.u >> 16) & 1);
  return (unsigned short)(r >> 16);
}
__device__ __forceinline__ float bf2f(unsigned short u) {
  union { uint32_t u; float f; } v; v.u = ((uint32_t)u) << 16;
  return v.f;
}

template <int N>
__device__ __forceinline__ void wait_vmcnt() {
  asm volatile("s_waitcnt vmcnt(%0)" :: "n"(N) : "memory");
}

__device__ __forceinline__ void gload_lds(const unsigned short* gp, unsigned short* lp) {
  __builtin_amdgcn_global_load_lds(
      (const __attribute__((address_space(1))) void*)gp,
      (__attribute__((address_space(3))) void*)lp, 16, 0, 0);
}

// ---- cast nf fp32 -> bf16 ----
__global__ void k_cast(const float* __restrict__ in, unsigned short* __restrict__ out) {
  int i = blockIdx.x * 256 + threadIdx.x;
  const float4* p = (const float4*)(in + (size_t)i * 8);
  float4 a = p[0], b = p[1];
  u16x8 r;
  r[0] = f2bf(a.x); r[1] = f2bf(a.y); r[2] = f2bf(a.z); r[3] = f2bf(a.w);
  r[4] = f2bf(b.x); r[5] = f2bf(b.y); r[6] = f2bf(b.z); r[7] = f2bf(b.w);
  *(u16x8*)(out + (size_t)i * 8) = r;
}

// ---- wrb_t[n][k] bf16 [1024][256] ----
__global__ void k_wr(const float* __restrict__ basis, const float* __restrict__ comp,
                     unsigned short* __restrict__ wrb_t) {
  int idx = blockIdx.x * 256 + threadIdx.x;
  int n = idx >> 8;
  int k = idx & 255;
  int r = n >> 7, o = n & 127;
  float acc = 0.f;
  #pragma unroll
  for (int b = 0; b < NBASES; b++)
    acc += comp[r * NBASES + b] * basis[((size_t)b * GD + k) * H1 + o];
  wrb_t[idx] = f2bf(acc);
}

// ---- fused-B prep: btf[c][0:128]=wcat[k][c]; btf[c][128+g]=(root@wcat)[g][c];
//      biasv[c]=bias1@wcat.  wcat[j][c] = c<128 ? w_l[j][c] : w_r[j][c-128]
__global__ void k_prep(const float* __restrict__ root, const float* __restrict__ w_l,
                       const float* __restrict__ w_r, const float* __restrict__ bias1,
                       unsigned short* __restrict__ btf, float* __restrict__ biasv) {
  int idx = blockIdx.x * 256 + threadIdx.x;   // 98560 total
  if (idx < 32768) {
    int c = idx >> 7, k = idx & 127;
    float v = (c < H2) ? w_l[k * H2 + c] : w_r[k * H2 + (c - H2)];
    btf[c * 384 + k] = f2bf(v);
  } else if (idx < 98304) {
    int j2 = idx - 32768;
    int c = j2 >> 8, g = j2 & 255;
    float acc = 0.f;
    for (int j = 0; j < H1; j++) {
      float w = (c < H2) ? w_l[j * H2 + c] : w_r[j * H2 + (c - H2)];
      acc += root[g * H1 + j] * w;
    }
    btf[c * 384 + 128 + g] = f2bf(acc);
  } else if (idx < 98560) {
    int c = idx - 98304;
    float acc = 0.f;
    for (int j = 0; j < H1; j++) {
      float w = (c < H2) ? w_l[j * H2 + c] : w_r[j * H2 + (c - H2)];
      acc += bias1[j] * w;
    }
    biasv[c] = acc;
  }
}

// ---- xr GEMM: wave tile 64x64 (WM=4), block 128x128, 3-buf BK=32, counted vmcnt ----
// PROVEN ordering: wait own vmcnt THEN s_barrier (vmcnt is per-wave!).
template <int K, int WM>
__global__ __launch_bounds__(256, 3)
void k_mgemm(const unsigned short* __restrict__ A, const unsigned short* __restrict__ Bt,
             unsigned short* __restrict__ C, int M, int N, int gx) {
  constexpr int BM = WM * 32;           // 128
  constexpr int ACH = BM * 4;           // 512
  constexpr int TCH = ACH + 512;        // 1024
  constexpr int LPT = TCH / 256;        // 4
  constexpr int NS = K / 32;
  constexpr int ABUF = BM * 32;
  constexpr int BBUF = 128 * 32;
  extern __shared__ unsigned short lds[];
  const int tid = threadIdx.x;
  const int lane = tid & 63;
  const int wave = tid >> 6;

  const int nwg = gridDim.x;
  const int q = nwg >> 3, r = nwg & 7;
  const int xcd = blockIdx.x & 7, bi = blockIdx.x >> 3;
  const int wg = (xcd < r ? xcd * (q + 1) : r * (q + 1) + (xcd - r) * q) + bi;
  const int bx = wg % gx;
  const int by = wg / gx;
  const int row0 = by * BM;
  const int colb = bx * 128;
  const int wcol = (wave & 1) * 64;
  const int wrow = (wave >> 1) * (WM * 16);
  const int lr = lane & 15;
  const int lko = lane >> 4;

  f32x4 acc[WM][4];
  #pragma unroll
  for (int i = 0; i < WM; i++)
    #pragma unroll
    for (int j = 0; j < 4; j++) acc[i][j] = (f32x4){0.f, 0.f, 0.f, 0.f};

  auto stage = [&](int k0, int b) {
    unsigned short* as = lds + b * ABUF;
    unsigned short* bs = lds + 3 * ABUF + b * BBUF;
    #pragma unroll
    for (int it = 0; it < LPT; it++) {
      int ci = it * 256 + tid;
      if (ci < ACH) {
        int row = ci >> 2, cs = ci & 3;
        int s = (row & 3) ^ ((row >> 2) & 3);
        int gm = row0 + row; if (gm >= M) gm = M - 1;
        gload_lds(A + (size_t)gm * K + k0 + ((cs ^ s) << 3), as + (size_t)ci * 8);
      } else {
        int cj = ci - ACH;
        int row = cj >> 2, cs = cj & 3;
        int s = (row & 3) ^ ((row >> 2) & 3);
        gload_lds(Bt + (size_t)(colb + row) * K + k0 + ((cs ^ s) << 3), bs + (size_t)cj * 8);
      }
    }
  };

  auto compute = [&](int b) {
    const unsigned short* as = lds + b * ABUF;
    const unsigned short* bs = lds + 3 * ABUF + b * BBUF;
    bf16x8 af[WM], bfr[4];
    #pragma unroll
    for (int mb = 0; mb < WM; mb++) {
      int rowL = wrow + mb * 16 + lr;
      int s = (rowL & 3) ^ ((rowL >> 2) & 3);
      af[mb] = *(const bf16x8*)&as[rowL * 32 + ((lko ^ s) << 3)];
    }
    #pragma unroll
    for (int nb = 0; nb < 4; nb++) {
      int colL = wcol + nb * 16 + lr;
      int s = (colL & 3) ^ ((colL >> 2) & 3);
      bfr[nb] = *(const bf16x8*)&bs[colL * 32 + ((lko ^ s) << 3)];
    }
    #pragma unroll
    for (int mb = 0; mb < WM; mb++)
      #pragma unroll
      for (int nb = 0; nb < 4; nb++)
        acc[mb][nb] = __builtin_amdgcn_mfma_f32_16x16x32_bf16(af[mb], bfr[nb], acc[mb][nb], 0, 0, 0);
  };

  stage(0, 0);
  stage(32, 1);
  wait_vmcnt<LPT>();
  __builtin_amdgcn_sched_barrier(0);
  __builtin_amdgcn_s_barrier();
  #pragma unroll
  for (int s = 0; s < NS; s++) {
    if (s + 2 < NS) stage((s + 2) * 32, (s + 2) % 3);
    compute(s % 3);
    if (s + 1 < NS) {
      if (s + 2 < NS) wait_vmcnt<LPT>();
      else            wait_vmcnt<0>();
      __builtin_amdgcn_sched_barrier(0);
      __builtin_amdgcn_s_barrier();
    }
  }

  // epilogue: acc -> swizzled Cs -> coalesced b128 stores
  __syncthreads();
  unsigned short* Cs = lds;                // [BM][128]
  const int orow = lko * 4;
  #pragma unroll
  for (int mb = 0; mb < WM; mb++) {
    #pragma unroll
    for (int i = 0; i < 4; i++) {
      int row = wrow + mb * 16 + orow + i;
      int sw = (row & 7) << 3;
      #pragma unroll
      for (int nb = 0; nb < 4; nb++) {
        int col = wcol + nb * 16 + lr;
        Cs[row * 128 + (col ^ sw)] = f2bf(acc[mb][nb][i]);
      }
    }
  }
  __syncthreads();
  #pragma unroll
  for (int it = 0; it < BM / 16; it++) {
    int off = it * 256 + tid;
    int row = off >> 4, jb = off & 15;
    int grow = row0 + row;
    if (grow < M) {
      int idx = row * 128 + ((jb * 8) ^ ((row & 7) << 3));
      *(u16x8*)&C[(size_t)grow * N + colb + jb * 8] = *(const u16x8*)&Cs[idx];
    }
  }
}

// ---- fused GEMM: xlr[M][256] = [agg|nf] @ btf^T + biasv. K=384, block 128x128 ----
__global__ __launch_bounds__(256, 3)
void k_fused(const unsigned short* __restrict__ A1, const unsigned short* __restrict__ A2,
             const unsigned short* __restrict__ Bt, const float* __restrict__ biasv,
             unsigned short* __restrict__ C, int M) {
  constexpr int K = 384, NS = 12, LPT = 4;
  extern __shared__ unsigned short lds[];
  const int tid = threadIdx.x;
  const int lane = tid & 63;
  const int wave = tid >> 6;

  const int nwg = gridDim.x;
  const int q = nwg >> 3, r = nwg & 7;
  const int xcd = blockIdx.x & 7, bi = blockIdx.x >> 3;
  const int wg = (xcd < r ? xcd * (q + 1) : r * (q + 1) + (xcd - r) * q) + bi;
  const int bx = wg & 1;
  const int by = wg >> 1;
  const int row0 = by * 128;
  const int colb = bx * 128;
  const int wcol = (wave & 1) * 64;
  const int wrow = (wave >> 1) * 64;
  const int lr = lane & 15;
  const int lko = lane >> 4;

  f32x4 acc[4][4];
  #pragma unroll
  for (int i = 0; i < 4; i++)
    #pragma unroll
    for (int j = 0; j < 4; j++) acc[i][j] = (f32x4){0.f, 0.f, 0.f, 0.f};

  auto stage = [&](int k0, int b) {
    unsigned short* as = lds + b * 4096;
    unsigned short* bs = lds + 3 * 4096 + b * 4096;
    #pragma unroll
    for (int it = 0; it < LPT; it++) {
      int ci = it * 256 + tid;
      if (ci < 512) {
        int row = ci >> 2, cs = ci & 3;
        int s = (row & 3) ^ ((row >> 2) & 3);
        int gm = row0 + row; if (gm >= M) gm = M - 1;
        const unsigned short* gp;
        if (k0 < 128) gp = A1 + (size_t)gm * 128 + k0 + ((cs ^ s) << 3);
        else          gp = A2 + (size_t)gm * 256 + (k0 - 128) + ((cs ^ s) << 3);
        gload_lds(gp, as + (size_t)ci * 8);
      } else {
        int cj = ci - 512;
        int row = cj >> 2, cs = cj & 3;
        int s = (row & 3) ^ ((row >> 2) & 3);
        gload_lds(Bt + (size_t)(colb + row) * K + k0 + ((cs ^ s) << 3), bs + (size_t)cj * 8);
      }
    }
  };

  auto compute = [&](int b) {
    const unsigned short* as = lds + b * 4096;
    const unsigned short* bs = lds + 3 * 4096 + b * 4096;
    bf16x8 af[4], bfr[4];
    #pragma unroll
    for (int mb = 0; mb < 4; mb++) {
      int rowL = wrow + mb * 16 + lr;
      int s = (rowL & 3) ^ ((rowL >> 2) & 3);
      af[mb] = *(const bf16x8*)&as[rowL * 32 + ((lko ^ s) << 3)];
    }
    #pragma unroll
    for (int nb = 0; nb < 4; nb++) {
      int colL = wcol + nb * 16 + lr;
      int s = (colL & 3) ^ ((colL >> 2) & 3);
      bfr[nb] = *(const bf16x8*)&bs[colL * 32 + ((lko ^ s) << 3)];
    }
    #pragma unroll
    for (int mb = 0; mb < 4; mb++)
      #pragma unroll
      for (int nb = 0; nb < 4; nb++)
        acc[mb][nb] = __builtin_amdgcn_mfma_f32_16x16x32_bf16(af[mb], bfr[nb], acc[mb][nb], 0, 0, 0);
  };

  stage(0, 0);
  stage(32, 1);
  wait_vmcnt<LPT>();
  __builtin_amdgcn_sched_barrier(0);
  __builtin_amdgcn_s_barrier();
  #pragma unroll
  for (int s = 0; s < NS; s++) {
    if (s + 2 < NS) stage((s + 2) * 32, (s + 2) % 3);
    compute(s % 3);
    if (s + 1 < NS) {
      if (s + 2 < NS) wait_vmcnt<LPT>();
      else            wait_vmcnt<0>();
      __builtin_amdgcn_sched_barrier(0);
      __builtin_amdgcn_s_barrier();
    }
  }

  __syncthreads();
  unsigned short* Cs = lds;                // [128][128]
  const int orow = lko * 4;
  #pragma unroll
  for (int mb = 0; mb < 4; mb++) {
    #pragma unroll
    for (int i = 0; i < 4; i++) {
      int row = wrow + mb * 16 + orow + i;
      int sw = (row & 7) << 3;
      #pragma unroll
      for (int nb = 0; nb < 4; nb++) {
        int col = wcol + nb * 16 + lr;
        Cs[row * 128 + (col ^ sw)] = f2bf(acc[mb][nb][i] + biasv[colb + col]);
      }
    }
  }
  __syncthreads();
  #pragma unroll
  for (int it = 0; it < 8; it++) {
    int off = it * 256 + tid;
    int row = off >> 4, jb = off & 15;
    int grow = row0 + row;
    if (grow < M) {
      int idx = row * 128 + ((jb * 8) ^ ((row & 7) << 3));
      *(u16x8*)&C[(size_t)grow * 256 + colb + jb * 8] = *(const u16x8*)&Cs[idx];
    }
  }
}

// ---- CSR build: degree + per-(dst,rel) counts ----
__global__ void k_deg(const int* __restrict__ ei, const int* __restrict__ et,
                      int* __restrict__ deg, int* __restrict__ cnt2) {
  int e = blockIdx.x * 256 + threadIdx.x;
  if (e < NE) {
    int d = ei[NE + e];
    atomicAdd(&deg[d], 1);
    atomicAdd(&cnt2[d * NREL + et[e]], 1);
  }
}

__global__ void k_scan_a(const int* __restrict__ deg, int* __restrict__ parts) {
  __shared__ int lds[256];
  int t = threadIdx.x;
  int base = blockIdx.x * 1024 + t * 4;
  int s = 0;
  #pragma unroll
  for (int j = 0; j < 4; j++) s += (base + j < NN) ? deg[base + j] : 0;
  lds[t] = s;
  __syncthreads();
  for (int st = 128; st > 0; st >>= 1) {
    if (t < st) lds[t] += lds[t + st];
    __syncthreads();
  }
  if (t == 0) parts[blockIdx.x] = lds[0];
}

__global__ void k_scan_b(int* __restrict__ parts) {
  int t = threadIdx.x;   // 64 threads
  int v = (t < NCHUNKS) ? parts[t] : 0;
  int x = v;
  #pragma unroll
  for (int off = 1; off < 64; off <<= 1) {
    int y = __shfl_up(x, off, 64);
    if (t >= off) x += y;
  }
  if (t < NCHUNKS) parts[t] = x - v;
}

__global__ void k_scan_c(const int* __restrict__ deg, const int* __restrict__ parts,
                         int* __restrict__ rowptr) {
  __shared__ int lds[256];
  int t = threadIdx.x;
  int base = blockIdx.x * 1024 + t * 4;
  int v[4];
  int s = 0;
  #pragma unroll
  for (int j = 0; j < 4; j++) { v[j] = (base + j < NN) ? deg[base + j] : 0; s += v[j]; }
  lds[t] = s;
  __syncthreads();
  for (int st = 1; st < 256; st <<= 1) {
    int add = (t >= st) ? lds[t - st] : 0;
    __syncthreads();
    lds[t] += add;
    __syncthreads();
  }
  int excl = lds[t] - s;
  int off = parts[blockIdx.x];
  int run = 0;
  #pragma unroll
  for (int j = 0; j < 4; j++) {
    run += v[j];
    if (base + j < NN) rowptr[base + j + 1] = off + excl + run;
  }
  if (blockIdx.x == 0 && t == 0) rowptr[0] = 0;
}

__global__ void k_scatter(const int* __restrict__ ei, const int* __restrict__ et,
                          const int* __restrict__ rowptr, const int* __restrict__ cnt2,
                          int* __restrict__ cursor, int* __restrict__ csr,
                          float* __restrict__ wgt) {
  int e = blockIdx.x * 256 + threadIdx.x;
  if (e < NE) {
    int d = ei[NE + e];
    int r = et[e];
    int pos = atomicAdd(&cursor[d], 1);
    int slot = rowptr[d] + pos;
    csr[slot] = ei[e] | (r << 20);
    wgt[slot] = 1.0f / (float)cnt2[d * NREL + r];
  }
}

// ---- RGCN aggregation: weighted sum, 8-batched lane-broadcast gathers ----
__global__ __launch_bounds__(256)
void k_rgcn(const unsigned short* __restrict__ xr, const int* __restrict__ csr2,
            const float* __restrict__ wgt, const int* __restrict__ rowptr,
            unsigned short* __restrict__ agg) {
  int wid = (blockIdx.x * 256 + threadIdx.x) >> 6;
  int lane = threadIdx.x & 63;
  if (wid >= NN) return;
  int c0 = lane * 2;
  float acc0 = 0.f, acc1 = 0.f;
  int beg = rowptr[wid], end = rowptr[wid + 1];
  for (int j0 = beg; j0 < end; j0 += 64) {
    int nv = end - j0; if (nv > 64) nv = 64;
    int pk = (lane < nv) ? csr2[j0 + lane] : 0;
    float wk = (lane < nv) ? wgt[j0 + lane] : 0.f;
    int t = 0;
    for (; t + 8 <= nv; t += 8) {
      uint32_t wv[8]; float wz[8];
      #pragma unroll
      for (int z = 0; z < 8; z++) {
        int p = __shfl(pk, t + z, 64);
        wz[z] = __shfl(wk, t + z, 64);
        int off = (p & 0xFFFFF) * XRLD + (p >> 20) * H1;
        wv[z] = *(const uint32_t*)(xr + off + c0);
      }
      #pragma unroll
      for (int z = 0; z < 8; z++) {
        acc0 += wz[z] * bf2f((unsigned short)(wv[z] & 0xffff));
        acc1 += wz[z] * bf2f((unsigned short)(wv[z] >> 16));
      }
    }
    for (; t < nv; t++) {
      int p = __shfl(pk, t, 64);
      float w = __shfl(wk, t, 64);
      int off = (p & 0xFFFFF) * XRLD + (p >> 20) * H1;
      uint32_t wv = *(const uint32_t*)(xr + off + c0);
      acc0 += w * bf2f((unsigned short)(wv & 0xffff));
      acc1 += w * bf2f((unsigned short)(wv >> 16));
    }
  }
  uint32_t packed = (uint32_t)f2bf(acc0) | ((uint32_t)f2bf(acc1) << 16);
  *(uint32_t*)&agg[(size_t)wid * H1 + c0] = packed;
}

// ---- GATv2: one wave per dst, 8-batched edges, chunked online softmax ----
__global__ __launch_bounds__(256)
void k_gat(const unsigned short* __restrict__ xlr, const int* __restrict__ csr2,
           const int* __restrict__ rowptr, const float* __restrict__ att,
           const float* __restrict__ bias2, float* __restrict__ out) {
  int wid = (blockIdx.x * 256 + threadIdx.x) >> 6;
  int lane = threadIdx.x & 63;
  if (wid >= NN) return;
  int c0 = lane * 2;
  float att0 = att[c0], att1 = att[c0 + 1];
  uint32_t wr2 = *(const uint32_t*)(xlr + (size_t)wid * 256 + 128 + c0);
  float xr0 = bf2f((unsigned short)(wr2 & 0xffff));
  float xr1 = bf2f((unsigned short)(wr2 >> 16));
  uint32_t wv0 = *(const uint32_t*)(xlr + (size_t)wid * 256 + c0);
  float vx = bf2f((unsigned short)(wv0 & 0xffff));
  float vy = bf2f((unsigned short)(wv0 >> 16));
  float ep = lrelu(vx + xr0) * att0 + lrelu(vy + xr1) * att1;
  #pragma unroll
  for (int off = 32; off > 0; off >>= 1) ep += __shfl_xor(ep, off, 64);
  float m = ep, s = 1.f, a0 = vx, a1 = vy;
  int beg = rowptr[wid], end = rowptr[wid + 1];
  for (int j0 = beg; j0 < end; j0 += 64) {
    int nv = end - j0; if (nv > 64) nv = 64;
    int pk = (lane < nv) ? csr2[j0 + lane] : 0;
    int t = 0;
    for (; t + 8 <= nv; t += 8) {
      float ux[8], uy[8], p[8];
      #pragma unroll
      for (int z = 0; z < 8; z++) {
        int src = __shfl(pk, t + z, 64) & 0xFFFFF;
        uint32_t wu = *(const uint32_t*)(xlr + (size_t)src * 256 + c0);
        ux[z] = bf2f((unsigned short)(wu & 0xffff));
        uy[z] = bf2f((unsigned short)(wu >> 16));
      }
      #pragma unroll
      for (int z = 0; z < 8; z++)
        p[z] = lrelu(ux[z] + xr0) * att0 + lrelu(uy[z] + xr1) * att1;
      #pragma unroll
      for (int off = 32; off > 0; off >>= 1) {
        #pragma unroll
        for (int z = 0; z < 8; z++) p[z] += __shfl_xor(p[z], off, 64);
      }
      float pm = p[0];
      #pragma unroll
      for (int z = 1; z < 8; z++) pm = fmaxf(pm, p[z]);
      float mn = fmaxf(m, pm);
      float sc = __expf(m - mn);
      float e[8];
      #pragma unroll
      for (int z = 0; z < 8; z++) e[z] = __expf(p[z] - mn);
      float es = 0.f, ea0 = 0.f, ea1 = 0.f;
      #pragma unroll
      for (int z = 0; z < 8; z++) { es += e[z]; ea0 += e[z] * ux[z]; ea1 += e[z] * uy[z]; }
      s = s * sc + es;
      a0 = a0 * sc + ea0;
      a1 = a1 * sc + ea1;
      m = mn;
    }
    for (; t < nv; t++) {
      int src = __shfl(pk, t, 64) & 0xFFFFF;
      uint32_t wu = *(const uint32_t*)(xlr + (size_t)src * 256 + c0);
      float ux = bf2f((unsigned short)(wu & 0xffff));
      float uy = bf2f((unsigned short)(wu >> 16));
      float p = lrelu(ux + xr0) * att0 + lrelu(uy + xr1) * att1;
      #pragma unroll
      for (int off = 32; off > 0; off >>= 1) p += __shfl_xor(p, off, 64);
      float mn = fmaxf(m, p);
      float sc = __expf(m - mn), w = __expf(p - mn);
      s = s * sc + w;
      a0 = a0 * sc + w * ux;
      a1 = a1 * sc + w * uy;
      m = mn;
    }
  }
  float inv = 1.f / s;
  out[(size_t)wid * H1 + c0] = a0 * inv + bias2[c0];
  out[(size_t)wid * H1 + c0 + 1] = a1 * inv + bias2[c0 + 1];
}

extern "C" void kernel_launch(void* const* d_in, const int* in_sizes, int n_in,
                              void* d_out, int out_size, void* d_ws, size_t ws_size,
                              hipStream_t stream) {
  const float* nf    = (const float*)d_in[0];
  const int*   ei    = (const int*)d_in[1];
  const int*   et    = (const int*)d_in[3];
  const float* basis = (const float*)d_in[4];
  const float* comp  = (const float*)d_in[5];
  const float* root  = (const float*)d_in[6];
  const float* bias1 = (const float*)d_in[7];
  const float* w_l   = (const float*)d_in[8];
  const float* w_r   = (const float*)d_in[9];
  const float* att   = (const float*)d_in[10];
  const float* bias2 = (const float*)d_in[11];
  float* out = (float*)d_out;

  char* ws = (char*)d_ws;
  unsigned short* xr_bf  = (unsigned short*)ws;                    // [NN][1024] 102.4 MB
  unsigned short* nf_bf  = (unsigned short*)(ws + 102400000);      // [NN][256]  25.6 MB
  unsigned short* wrb_t  = (unsigned short*)(ws + 128000000);      // [1024][256]
  unsigned short* btf    = (unsigned short*)(ws + 128524288);      // [256][384] bf16
  float*          biasv  = (float*)(ws + 128720896);               // [256]
  unsigned short* agg_bf = (unsigned short*)(ws + 128721920);      // [NN][128] bf16
  int*            deg    = (int*)(ws + 141521920);                 // [NN]
  int*            cursor = deg + NN;                               // [NN]
  int*            cnt2   = cursor + NN;                            // [NN*8]
  int*            rowptr = cnt2 + NN * NREL;                       // [NN+1]
  int*            csr    = rowptr + NN + 1;                        // [NE]
  int*            parts  = csr + NE;                               // [64]
  float*          wgt    = (float*)(parts + 64);                   // [NE]
  // overlay into xr region (dead after k_rgcn):
  unsigned short* xlr_bf = (unsigned short*)ws;                    // [NN][256] bf16

  hipMemsetAsync(deg, 0, (2 + NREL) * NN * sizeof(int), stream);   // deg+cursor+cnt2

  k_cast<<<(NN * GD / 8) / 256, 256, 0, stream>>>(nf, nf_bf);
  k_wr<<<(XRLD * GD) / 256, 256, 0, stream>>>(basis, comp, wrb_t);
  k_prep<<<(98560 + 255) / 256, 256, 0, stream>>>(root, w_l, w_r, bias1, btf, biasv);

  const int GY128 = (NN + 127) / 128;   // 391
  k_mgemm<256, 4><<<8 * GY128, 256, 49152, stream>>>(
      nf_bf, wrb_t, xr_bf, NN, XRLD, 8);

  k_deg<<<(NE + 255) / 256, 256, 0, stream>>>(ei, et, deg, cnt2);
  k_scan_a<<<NCHUNKS, 256, 0, stream>>>(deg, parts);
  k_scan_b<<<1, 64, 0, stream>>>(parts);
  k_scan_c<<<NCHUNKS, 256, 0, stream>>>(deg, parts, rowptr);
  k_scatter<<<(NE + 255) / 256, 256, 0, stream>>>(ei, et, rowptr, cnt2, cursor, csr, wgt);

  k_rgcn<<<(NN + 3) / 4, 256, 0, stream>>>(xr_bf, csr, wgt, rowptr, agg_bf);

  k_fused<<<2 * GY128, 256, 49152, stream>>>(agg_bf, nf_bf, btf, biasv, xlr_bf, NN);

  k_gat<<<(NN + 3) / 4, 256, 0, stream>>>(xlr_bf, csr, rowptr, att, bias2, out);
}

// Round 11
// 258.550 us; speedup vs baseline: 2.7055x; 1.1035x over previous
//
#include <hip/hip_runtime.h>
#include <hip/hip_bf16.h>
#include <cstdint>
#include <cstddef>

#define NN 50000
#define NE 500000
#define GD 256
#define H1 128
#define H2 128
#define NREL 8
#define NBASES 30
#define XRLD (NREL * H1)   // 1024
#define NCHUNKS ((NN + 1023) / 1024)  // 49

typedef __attribute__((ext_vector_type(8))) short bf16x8;
typedef __attribute__((ext_vector_type(4))) float f32x4;
typedef __attribute__((ext_vector_type(8))) unsigned short u16x8;

__device__ __forceinline__ float lrelu(float x) { return x > 0.f ? x : 0.2f * x; }

__device__ __forceinline__ unsigned short f2bf(float x) {
  union { float f; uint32_t u; } v; v.f = x;
  uint32_t r = v.u + 0x7FFF + ((v.u >> 16) & 1);
  return (unsigned short)(r >> 16);
}
__device__ __forceinline__ float bf2f(unsigned short u) {
  union { uint32_t u; float f; } v; v.u = ((uint32_t)u) << 16;
  return v.f;
}

template <int N>
__device__ __forceinline__ void wait_vmcnt() {
  asm volatile("s_waitcnt vmcnt(%0)" :: "n"(N) : "memory");
}

__device__ __forceinline__ void gload_lds(const unsigned short* gp, unsigned short* lp) {
  __builtin_amdgcn_global_load_lds(
      (const __attribute__((address_space(1))) void*)gp,
      (__attribute__((address_space(3))) void*)lp, 16, 0, 0);
}

// ---- cast nf fp32 -> bf16 ----
__global__ void k_cast(const float* __restrict__ in, unsigned short* __restrict__ out) {
  int i = blockIdx.x * 256 + threadIdx.x;
  const float4* p = (const float4*)(in + (size_t)i * 8);
  float4 a = p[0], b = p[1];
  u16x8 r;
  r[0] = f2bf(a.x); r[1] = f2bf(a.y); r[2] = f2bf(a.z); r[3] = f2bf(a.w);
  r[4] = f2bf(b.x); r[5] = f2bf(b.y); r[6] = f2bf(b.z); r[7] = f2bf(b.w);
  *(u16x8*)(out + (size_t)i * 8) = r;
}

// ---- wrb_t[n][k] bf16 [1024][256] ----
__global__ void k_wr(const float* __restrict__ basis, const float* __restrict__ comp,
                     unsigned short* __restrict__ wrb_t) {
  int idx = blockIdx.x * 256 + threadIdx.x;
  int n = idx >> 8;
  int k = idx & 255;
  int r = n >> 7, o = n & 127;
  float acc = 0.f;
  #pragma unroll
  for (int b = 0; b < NBASES; b++)
    acc += comp[r * NBASES + b] * basis[((size_t)b * GD + k) * H1 + o];
  wrb_t[idx] = f2bf(acc);
}

// ---- fused-B prep: btf[c][0:128]=wcat[k][c]; btf[c][128+g]=(root@wcat)[g][c];
//      biasv[c]=bias1@wcat.  wcat[j][c] = c<128 ? w_l[j][c] : w_r[j][c-128]
__global__ void k_prep(const float* __restrict__ root, const float* __restrict__ w_l,
                       const float* __restrict__ w_r, const float* __restrict__ bias1,
                       unsigned short* __restrict__ btf, float* __restrict__ biasv) {
  int idx = blockIdx.x * 256 + threadIdx.x;   // 98560 total
  if (idx < 32768) {
    int c = idx >> 7, k = idx & 127;
    float v = (c < H2) ? w_l[k * H2 + c] : w_r[k * H2 + (c - H2)];
    btf[c * 384 + k] = f2bf(v);
  } else if (idx < 98304) {
    int j2 = idx - 32768;
    int c = j2 >> 8, g = j2 & 255;
    float acc = 0.f;
    for (int j = 0; j < H1; j++) {
      float w = (c < H2) ? w_l[j * H2 + c] : w_r[j * H2 + (c - H2)];
      acc += root[g * H1 + j] * w;
    }
    btf[c * 384 + 128 + g] = f2bf(acc);
  } else if (idx < 98560) {
    int c = idx - 98304;
    float acc = 0.f;
    for (int j = 0; j < H1; j++) {
      float w = (c < H2) ? w_l[j * H2 + c] : w_r[j * H2 + (c - H2)];
      acc += bias1[j] * w;
    }
    biasv[c] = acc;
  }
}

// ---- xr GEMM: wave tile 64x64 (WM=4), block 128x128, 3-buf BK=32, counted vmcnt ----
template <int K, int WM>
__global__ __launch_bounds__(256, 3)
void k_mgemm(const unsigned short* __restrict__ A, const unsigned short* __restrict__ Bt,
             unsigned short* __restrict__ C, int M, int N, int gx) {
  constexpr int BM = WM * 32;
  constexpr int ACH = BM * 4;
  constexpr int TCH = ACH + 512;
  constexpr int LPT = TCH / 256;
  constexpr int NS = K / 32;
  constexpr int ABUF = BM * 32;
  constexpr int BBUF = 128 * 32;
  extern __shared__ unsigned short lds[];
  const int tid = threadIdx.x;
  const int lane = tid & 63;
  const int wave = tid >> 6;

  const int nwg = gridDim.x;
  const int q = nwg >> 3, r = nwg & 7;
  const int xcd = blockIdx.x & 7, bi = blockIdx.x >> 3;
  const int wg = (xcd < r ? xcd * (q + 1) : r * (q + 1) + (xcd - r) * q) + bi;
  const int bx = wg % gx;
  const int by = wg / gx;
  const int row0 = by * BM;
  const int colb = bx * 128;
  const int wcol = (wave & 1) * 64;
  const int wrow = (wave >> 1) * (WM * 16);
  const int lr = lane & 15;
  const int lko = lane >> 4;

  f32x4 acc[WM][4];
  #pragma unroll
  for (int i = 0; i < WM; i++)
    #pragma unroll
    for (int j = 0; j < 4; j++) acc[i][j] = (f32x4){0.f, 0.f, 0.f, 0.f};

  auto stage = [&](int k0, int b) {
    unsigned short* as = lds + b * ABUF;
    unsigned short* bs = lds + 3 * ABUF + b * BBUF;
    #pragma unroll
    for (int it = 0; it < LPT; it++) {
      int ci = it * 256 + tid;
      if (ci < ACH) {
        int row = ci >> 2, cs = ci & 3;
        int s = (row & 3) ^ ((row >> 2) & 3);
        int gm = row0 + row; if (gm >= M) gm = M - 1;
        gload_lds(A + (size_t)gm * K + k0 + ((cs ^ s) << 3), as + (size_t)ci * 8);
      } else {
        int cj = ci - ACH;
        int row = cj >> 2, cs = cj & 3;
        int s = (row & 3) ^ ((row >> 2) & 3);
        gload_lds(Bt + (size_t)(colb + row) * K + k0 + ((cs ^ s) << 3), bs + (size_t)cj * 8);
      }
    }
  };

  auto compute = [&](int b) {
    const unsigned short* as = lds + b * ABUF;
    const unsigned short* bs = lds + 3 * ABUF + b * BBUF;
    bf16x8 af[WM], bfr[4];
    #pragma unroll
    for (int mb = 0; mb < WM; mb++) {
      int rowL = wrow + mb * 16 + lr;
      int s = (rowL & 3) ^ ((rowL >> 2) & 3);
      af[mb] = *(const bf16x8*)&as[rowL * 32 + ((lko ^ s) << 3)];
    }
    #pragma unroll
    for (int nb = 0; nb < 4; nb++) {
      int colL = wcol + nb * 16 + lr;
      int s = (colL & 3) ^ ((colL >> 2) & 3);
      bfr[nb] = *(const bf16x8*)&bs[colL * 32 + ((lko ^ s) << 3)];
    }
    #pragma unroll
    for (int mb = 0; mb < WM; mb++)
      #pragma unroll
      for (int nb = 0; nb < 4; nb++)
        acc[mb][nb] = __builtin_amdgcn_mfma_f32_16x16x32_bf16(af[mb], bfr[nb], acc[mb][nb], 0, 0, 0);
  };

  stage(0, 0);
  stage(32, 1);
  wait_vmcnt<LPT>();
  __builtin_amdgcn_sched_barrier(0);
  __builtin_amdgcn_s_barrier();
  #pragma unroll
  for (int s = 0; s < NS; s++) {
    if (s + 2 < NS) stage((s + 2) * 32, (s + 2) % 3);
    compute(s % 3);
    if (s + 1 < NS) {
      if (s + 2 < NS) wait_vmcnt<LPT>();
      else            wait_vmcnt<0>();
      __builtin_amdgcn_sched_barrier(0);
      __builtin_amdgcn_s_barrier();
    }
  }

  __syncthreads();
  unsigned short* Cs = lds;                // [BM][128]
  const int orow = lko * 4;
  #pragma unroll
  for (int mb = 0; mb < WM; mb++) {
    #pragma unroll
    for (int i = 0; i < 4; i++) {
      int row = wrow + mb * 16 + orow + i;
      int sw = (row & 7) << 3;
      #pragma unroll
      for (int nb = 0; nb < 4; nb++) {
        int col = wcol + nb * 16 + lr;
        Cs[row * 128 + (col ^ sw)] = f2bf(acc[mb][nb][i]);
      }
    }
  }
  __syncthreads();
  #pragma unroll
  for (int it = 0; it < BM / 16; it++) {
    int off = it * 256 + tid;
    int row = off >> 4, jb = off & 15;
    int grow = row0 + row;
    if (grow < M) {
      int idx = row * 128 + ((jb * 8) ^ ((row & 7) << 3));
      *(u16x8*)&C[(size_t)grow * N + colb + jb * 8] = *(const u16x8*)&Cs[idx];
    }
  }
}

// ---- fused GEMM: xlr[M][256] = [agg|nf] @ btf^T + biasv. K=384, block 128x128 ----
__global__ __launch_bounds__(256, 3)
void k_fused(const unsigned short* __restrict__ A1, const unsigned short* __restrict__ A2,
             const unsigned short* __restrict__ Bt, const float* __restrict__ biasv,
             unsigned short* __restrict__ C, int M) {
  constexpr int K = 384, NS = 12, LPT = 4;
  extern __shared__ unsigned short lds[];
  const int tid = threadIdx.x;
  const int lane = tid & 63;
  const int wave = tid >> 6;

  const int nwg = gridDim.x;
  const int q = nwg >> 3, r = nwg & 7;
  const int xcd = blockIdx.x & 7, bi = blockIdx.x >> 3;
  const int wg = (xcd < r ? xcd * (q + 1) : r * (q + 1) + (xcd - r) * q) + bi;
  const int bx = wg & 1;
  const int by = wg >> 1;
  const int row0 = by * 128;
  const int colb = bx * 128;
  const int wcol = (wave & 1) * 64;
  const int wrow = (wave >> 1) * 64;
  const int lr = lane & 15;
  const int lko = lane >> 4;

  f32x4 acc[4][4];
  #pragma unroll
  for (int i = 0; i < 4; i++)
    #pragma unroll
    for (int j = 0; j < 4; j++) acc[i][j] = (f32x4){0.f, 0.f, 0.f, 0.f};

  auto stage = [&](int k0, int b) {
    unsigned short* as = lds + b * 4096;
    unsigned short* bs = lds + 3 * 4096 + b * 4096;
    #pragma unroll
    for (int it = 0; it < LPT; it++) {
      int ci = it * 256 + tid;
      if (ci < 512) {
        int row = ci >> 2, cs = ci & 3;
        int s = (row & 3) ^ ((row >> 2) & 3);
        int gm = row0 + row; if (gm >= M) gm = M - 1;
        const unsigned short* gp;
        if (k0 < 128) gp = A1 + (size_t)gm * 128 + k0 + ((cs ^ s) << 3);
        else          gp = A2 + (size_t)gm * 256 + (k0 - 128) + ((cs ^ s) << 3);
        gload_lds(gp, as + (size_t)ci * 8);
      } else {
        int cj = ci - 512;
        int row = cj >> 2, cs = cj & 3;
        int s = (row & 3) ^ ((row >> 2) & 3);
        gload_lds(Bt + (size_t)(colb + row) * K + k0 + ((cs ^ s) << 3), bs + (size_t)cj * 8);
      }
    }
  };

  auto compute = [&](int b) {
    const unsigned short* as = lds + b * 4096;
    const unsigned short* bs = lds + 3 * 4096 + b * 4096;
    bf16x8 af[4], bfr[4];
    #pragma unroll
    for (int mb = 0; mb < 4; mb++) {
      int rowL = wrow + mb * 16 + lr;
      int s = (rowL & 3) ^ ((rowL >> 2) & 3);
      af[mb] = *(const bf16x8*)&as[rowL * 32 + ((lko ^ s) << 3)];
    }
    #pragma unroll
    for (int nb = 0; nb < 4; nb++) {
      int colL = wcol + nb * 16 + lr;
      int s = (colL & 3) ^ ((colL >> 2) & 3);
      bfr[nb] = *(const bf16x8*)&bs[colL * 32 + ((lko ^ s) << 3)];
    }
    #pragma unroll
    for (int mb = 0; mb < 4; mb++)
      #pragma unroll
      for (int nb = 0; nb < 4; nb++)
        acc[mb][nb] = __builtin_amdgcn_mfma_f32_16x16x32_bf16(af[mb], bfr[nb], acc[mb][nb], 0, 0, 0);
  };

  stage(0, 0);
  stage(32, 1);
  wait_vmcnt<LPT>();
  __builtin_amdgcn_sched_barrier(0);
  __builtin_amdgcn_s_barrier();
  #pragma unroll
  for (int s = 0; s < NS; s++) {
    if (s + 2 < NS) stage((s + 2) * 32, (s + 2) % 3);
    compute(s % 3);
    if (s + 1 < NS) {
      if (s + 2 < NS) wait_vmcnt<LPT>();
      else            wait_vmcnt<0>();
      __builtin_amdgcn_sched_barrier(0);
      __builtin_amdgcn_s_barrier();
    }
  }

  __syncthreads();
  unsigned short* Cs = lds;                // [128][128]
  const int orow = lko * 4;
  #pragma unroll
  for (int mb = 0; mb < 4; mb++) {
    #pragma unroll
    for (int i = 0; i < 4; i++) {
      int row = wrow + mb * 16 + orow + i;
      int sw = (row & 7) << 3;
      #pragma unroll
      for (int nb = 0; nb < 4; nb++) {
        int col = wcol + nb * 16 + lr;
        Cs[row * 128 + (col ^ sw)] = f2bf(acc[mb][nb][i] + biasv[colb + col]);
      }
    }
  }
  __syncthreads();
  #pragma unroll
  for (int it = 0; it < 8; it++) {
    int off = it * 256 + tid;
    int row = off >> 4, jb = off & 15;
    int grow = row0 + row;
    if (grow < M) {
      int idx = row * 128 + ((jb * 8) ^ ((row & 7) << 3));
      *(u16x8*)&C[(size_t)grow * 256 + colb + jb * 8] = *(const u16x8*)&Cs[idx];
    }
  }
}

// ---- per-(dst,rel) counts only (deg derived in scans) ----
__global__ void k_deg(const int* __restrict__ ei, const int* __restrict__ et,
                      int* __restrict__ cnt2) {
  int e = blockIdx.x * 256 + threadIdx.x;
  if (e < NE) atomicAdd(&cnt2[ei[NE + e] * NREL + et[e]], 1);
}

__device__ __forceinline__ int node_deg(const int* cnt2, int n) {
  const int4* p = (const int4*)(cnt2 + n * NREL);
  int4 a = p[0], b = p[1];
  return a.x + a.y + a.z + a.w + b.x + b.y + b.z + b.w;
}

__global__ void k_scan_a(const int* __restrict__ cnt2, int* __restrict__ parts) {
  __shared__ int lds[256];
  int t = threadIdx.x;
  int base = blockIdx.x * 1024 + t * 4;
  int s = 0;
  #pragma unroll
  for (int j = 0; j < 4; j++) s += (base + j < NN) ? node_deg(cnt2, base + j) : 0;
  lds[t] = s;
  __syncthreads();
  for (int st = 128; st > 0; st >>= 1) {
    if (t < st) lds[t] += lds[t + st];
    __syncthreads();
  }
  if (t == 0) parts[blockIdx.x] = lds[0];
}

__global__ void k_scan_b(int* __restrict__ parts) {
  int t = threadIdx.x;   // 64 threads
  int v = (t < NCHUNKS) ? parts[t] : 0;
  int x = v;
  #pragma unroll
  for (int off = 1; off < 64; off <<= 1) {
    int y = __shfl_up(x, off, 64);
    if (t >= off) x += y;
  }
  if (t < NCHUNKS) parts[t] = x - v;
}

__global__ void k_scan_c(const int* __restrict__ cnt2, const int* __restrict__ parts,
                         int* __restrict__ rowptr) {
  __shared__ int lds[256];
  int t = threadIdx.x;
  int base = blockIdx.x * 1024 + t * 4;
  int v[4];
  int s = 0;
  #pragma unroll
  for (int j = 0; j < 4; j++) { v[j] = (base + j < NN) ? node_deg(cnt2, base + j) : 0; s += v[j]; }
  lds[t] = s;
  __syncthreads();
  for (int st = 1; st < 256; st <<= 1) {
    int add = (t >= st) ? lds[t - st] : 0;
    __syncthreads();
    lds[t] += add;
    __syncthreads();
  }
  int excl = lds[t] - s;
  int off = parts[blockIdx.x];
  int run = 0;
  #pragma unroll
  for (int j = 0; j < 4; j++) {
    run += v[j];
    if (base + j < NN) rowptr[base + j + 1] = off + excl + run;
  }
  if (blockIdx.x == 0 && t == 0) rowptr[0] = 0;
}

__global__ void k_scatter(const int* __restrict__ ei, const int* __restrict__ et,
                          const int* __restrict__ rowptr, const int* __restrict__ cnt2,
                          int* __restrict__ cursor, int* __restrict__ csr,
                          float* __restrict__ wgt) {
  int e = blockIdx.x * 256 + threadIdx.x;
  if (e < NE) {
    int d = ei[NE + e];
    int r = et[e];
    int pos = atomicAdd(&cursor[d], 1);
    int slot = rowptr[d] + pos;
    csr[slot] = ei[e] | (r << 20);
    wgt[slot] = 1.0f / (float)cnt2[d * NREL + r];
  }
}

// ---- RGCN aggregation: HALF-WAVE per dst, 4 ch/lane, 8-batched gathers ----
__global__ __launch_bounds__(256)
void k_rgcn(const unsigned short* __restrict__ xr, const int* __restrict__ csr2,
            const float* __restrict__ wgt, const int* __restrict__ rowptr,
            unsigned short* __restrict__ agg) {
  int wpair = (blockIdx.x * 256 + threadIdx.x) >> 6;
  int lane = threadIdx.x & 63;
  int hb = lane & 32;            // half base (0 or 32)
  int l = lane & 31;
  int wid = wpair * 2 + (hb >> 5);
  if (wid >= NN) return;
  int c0 = l * 4;
  float a0 = 0.f, a1 = 0.f, a2 = 0.f, a3 = 0.f;
  int beg = rowptr[wid], end = rowptr[wid + 1];
  for (int j0 = beg; j0 < end; j0 += 32) {
    int nv = end - j0; if (nv > 32) nv = 32;
    int pk = (l < nv) ? csr2[j0 + l] : 0;
    float wk = (l < nv) ? wgt[j0 + l] : 0.f;
    int t = 0;
    for (; t + 8 <= nv; t += 8) {
      uint2 wv[8]; float wz[8];
      #pragma unroll
      for (int z = 0; z < 8; z++) {
        int p = __shfl(pk, hb + t + z, 64);
        wz[z] = __shfl(wk, hb + t + z, 64);
        size_t off = (size_t)(p & 0xFFFFF) * XRLD + (p >> 20) * H1 + c0;
        wv[z] = *(const uint2*)(xr + off);
      }
      #pragma unroll
      for (int z = 0; z < 8; z++) {
        a0 += wz[z] * bf2f((unsigned short)(wv[z].x & 0xffff));
        a1 += wz[z] * bf2f((unsigned short)(wv[z].x >> 16));
        a2 += wz[z] * bf2f((unsigned short)(wv[z].y & 0xffff));
        a3 += wz[z] * bf2f((unsigned short)(wv[z].y >> 16));
      }
    }
    for (; t < nv; t++) {
      int p = __shfl(pk, hb + t, 64);
      float w = __shfl(wk, hb + t, 64);
      size_t off = (size_t)(p & 0xFFFFF) * XRLD + (p >> 20) * H1 + c0;
      uint2 wv = *(const uint2*)(xr + off);
      a0 += w * bf2f((unsigned short)(wv.x & 0xffff));
      a1 += w * bf2f((unsigned short)(wv.x >> 16));
      a2 += w * bf2f((unsigned short)(wv.y & 0xffff));
      a3 += w * bf2f((unsigned short)(wv.y >> 16));
    }
  }
  uint2 packed;
  packed.x = (uint32_t)f2bf(a0) | ((uint32_t)f2bf(a1) << 16);
  packed.y = (uint32_t)f2bf(a2) | ((uint32_t)f2bf(a3) << 16);
  *(uint2*)&agg[(size_t)wid * H1 + c0] = packed;
}

// ---- GATv2: HALF-WAVE per dst, 4 ch/lane, 5-stage reduce, online softmax ----
__global__ __launch_bounds__(256)
void k_gat(const unsigned short* __restrict__ xlr, const int* __restrict__ csr2,
           const int* __restrict__ rowptr, const float* __restrict__ att,
           const float* __restrict__ bias2, float* __restrict__ out) {
  int wpair = (blockIdx.x * 256 + threadIdx.x) >> 6;
  int lane = threadIdx.x & 63;
  int hb = lane & 32;
  int l = lane & 31;
  int wid = wpair * 2 + (hb >> 5);
  if (wid >= NN) return;
  int c0 = l * 4;
  float4 at = *(const float4*)(att + c0);
  // xrt 4 ch
  uint2 wr2 = *(const uint2*)(xlr + (size_t)wid * 256 + 128 + c0);
  float xr0 = bf2f((unsigned short)(wr2.x & 0xffff));
  float xr1 = bf2f((unsigned short)(wr2.x >> 16));
  float xr2 = bf2f((unsigned short)(wr2.y & 0xffff));
  float xr3 = bf2f((unsigned short)(wr2.y >> 16));
  // self xl 4 ch
  uint2 wv0 = *(const uint2*)(xlr + (size_t)wid * 256 + c0);
  float v0 = bf2f((unsigned short)(wv0.x & 0xffff));
  float v1 = bf2f((unsigned short)(wv0.x >> 16));
  float v2 = bf2f((unsigned short)(wv0.y & 0xffff));
  float v3 = bf2f((unsigned short)(wv0.y >> 16));
  float ep = lrelu(v0 + xr0) * at.x + lrelu(v1 + xr1) * at.y +
             lrelu(v2 + xr2) * at.z + lrelu(v3 + xr3) * at.w;
  #pragma unroll
  for (int off = 16; off > 0; off >>= 1) ep += __shfl_xor(ep, off, 64);
  float m = ep, s = 1.f, o0 = v0, o1 = v1, o2 = v2, o3 = v3;
  int beg = rowptr[wid], end = rowptr[wid + 1];
  for (int j0 = beg; j0 < end; j0 += 32) {
    int nv = end - j0; if (nv > 32) nv = 32;
    int pk = (l < nv) ? csr2[j0 + l] : 0;
    int t = 0;
    for (; t + 8 <= nv; t += 8) {
      float u0[8], u1[8], u2[8], u3[8], p[8];
      #pragma unroll
      for (int z = 0; z < 8; z++) {
        int src = __shfl(pk, hb + t + z, 64) & 0xFFFFF;
        uint2 wu = *(const uint2*)(xlr + (size_t)src * 256 + c0);
        u0[z] = bf2f((unsigned short)(wu.x & 0xffff));
        u1[z] = bf2f((unsigned short)(wu.x >> 16));
        u2[z] = bf2f((unsigned short)(wu.y & 0xffff));
        u3[z] = bf2f((unsigned short)(wu.y >> 16));
      }
      #pragma unroll
      for (int z = 0; z < 8; z++)
        p[z] = lrelu(u0[z] + xr0) * at.x + lrelu(u1[z] + xr1) * at.y +
               lrelu(u2[z] + xr2) * at.z + lrelu(u3[z] + xr3) * at.w;
      #pragma unroll
      for (int off = 16; off > 0; off >>= 1) {
        #pragma unroll
        for (int z = 0; z < 8; z++) p[z] += __shfl_xor(p[z], off, 64);
      }
      float pm = p[0];
      #pragma unroll
      for (int z = 1; z < 8; z++) pm = fmaxf(pm, p[z]);
      float mn = fmaxf(m, pm);
      float sc = __expf(m - mn);
      float e[8];
      #pragma unroll
      for (int z = 0; z < 8; z++) e[z] = __expf(p[z] - mn);
      float es = 0.f, e0 = 0.f, e1 = 0.f, e2 = 0.f, e3 = 0.f;
      #pragma unroll
      for (int z = 0; z < 8; z++) {
        es += e[z]; e0 += e[z] * u0[z]; e1 += e[z] * u1[z];
        e2 += e[z] * u2[z]; e3 += e[z] * u3[z];
      }
      s = s * sc + es;
      o0 = o0 * sc + e0; o1 = o1 * sc + e1;
      o2 = o2 * sc + e2; o3 = o3 * sc + e3;
      m = mn;
    }
    for (; t < nv; t++) {
      int src = __shfl(pk, hb + t, 64) & 0xFFFFF;
      uint2 wu = *(const uint2*)(xlr + (size_t)src * 256 + c0);
      float u0 = bf2f((unsigned short)(wu.x & 0xffff));
      float u1 = bf2f((unsigned short)(wu.x >> 16));
      float u2 = bf2f((unsigned short)(wu.y & 0xffff));
      float u3 = bf2f((unsigned short)(wu.y >> 16));
      float p = lrelu(u0 + xr0) * at.x + lrelu(u1 + xr1) * at.y +
                lrelu(u2 + xr2) * at.z + lrelu(u3 + xr3) * at.w;
      #pragma unroll
      for (int off = 16; off > 0; off >>= 1) p += __shfl_xor(p, off, 64);
      float mn = fmaxf(m, p);
      float sc = __expf(m - mn), w = __expf(p - mn);
      s = s * sc + w;
      o0 = o0 * sc + w * u0; o1 = o1 * sc + w * u1;
      o2 = o2 * sc + w * u2; o3 = o3 * sc + w * u3;
      m = mn;
    }
  }
  float inv = 1.f / s;
  float4 b2 = *(const float4*)(bias2 + c0);
  float4 res = make_float4(o0 * inv + b2.x, o1 * inv + b2.y,
                           o2 * inv + b2.z, o3 * inv + b2.w);
  *(float4*)&out[(size_t)wid * H1 + c0] = res;
}

extern "C" void kernel_launch(void* const* d_in, const int* in_sizes, int n_in,
                              void* d_out, int out_size, void* d_ws, size_t ws_size,
                              hipStream_t stream) {
  const float* nf    = (const float*)d_in[0];
  const int*   ei    = (const int*)d_in[1];
  const int*   et    = (const int*)d_in[3];
  const float* basis = (const float*)d_in[4];
  const float* comp  = (const float*)d_in[5];
  const float* root  = (const float*)d_in[6];
  const float* bias1 = (const float*)d_in[7];
  const float* w_l   = (const float*)d_in[8];
  const float* w_r   = (const float*)d_in[9];
  const float* att   = (const float*)d_in[10];
  const float* bias2 = (const float*)d_in[11];
  float* out = (float*)d_out;

  char* ws = (char*)d_ws;
  unsigned short* xr_bf  = (unsigned short*)ws;                    // [NN][1024] 102.4 MB
  unsigned short* nf_bf  = (unsigned short*)(ws + 102400000);      // [NN][256]  25.6 MB
  unsigned short* wrb_t  = (unsigned short*)(ws + 128000000);      // [1024][256]
  unsigned short* btf    = (unsigned short*)(ws + 128524288);      // [256][384] bf16
  float*          biasv  = (float*)(ws + 128720896);               // [256]
  unsigned short* agg_bf = (unsigned short*)(ws + 128721920);      // [NN][128] bf16
  int*            cursor = (int*)(ws + 141521920);                 // [NN]
  int*            cnt2   = cursor + NN;                            // [NN*8]
  int*            rowptr = cnt2 + NN * NREL;                       // [NN+1]
  int*            csr    = rowptr + NN + 1;                        // [NE]
  int*            parts  = csr + NE;                               // [64]
  float*          wgt    = (float*)(parts + 64);                   // [NE]
  // overlay into xr region (dead after k_rgcn):
  unsigned short* xlr_bf = (unsigned short*)ws;                    // [NN][256] bf16

  hipMemsetAsync(cursor, 0, (1 + NREL) * NN * sizeof(int), stream);   // cursor+cnt2

  k_cast<<<(NN * GD / 8) / 256, 256, 0, stream>>>(nf, nf_bf);
  k_wr<<<(XRLD * GD) / 256, 256, 0, stream>>>(basis, comp, wrb_t);
  k_prep<<<(98560 + 255) / 256, 256, 0, stream>>>(root, w_l, w_r, bias1, btf, biasv);

  const int GY128 = (NN + 127) / 128;   // 391
  k_mgemm<256, 4><<<8 * GY128, 256, 49152, stream>>>(
      nf_bf, wrb_t, xr_bf, NN, XRLD, 8);

  k_deg<<<(NE + 255) / 256, 256, 0, stream>>>(ei, et, cnt2);
  k_scan_a<<<NCHUNKS, 256, 0, stream>>>(cnt2, parts);
  k_scan_b<<<1, 64, 0, stream>>>(parts);
  k_scan_c<<<NCHUNKS, 256, 0, stream>>>(cnt2, parts, rowptr);
  k_scatter<<<(NE + 255) / 256, 256, 0, stream>>>(ei, et, rowptr, cnt2, cursor, csr, wgt);

  k_rgcn<<<(NN + 7) / 8, 256, 0, stream>>>(xr_bf, csr, wgt, rowptr, agg_bf);

  k_fused<<<2 * GY128, 256, 49152, stream>>>(agg_bf, nf_bf, btf, biasv, xlr_bf, NN);

  k_gat<<<(NN + 7) / 8, 256, 0, stream>>>(xlr_bf, csr, rowptr, att, bias2, out);
}

// Round 12
// 251.404 us; speedup vs baseline: 2.7824x; 1.0284x over previous
//
#include <hip/hip_runtime.h>
#include <hip/hip_bf16.h>
#include <cstdint>
#include <cstddef>

#define NN 50000
#define NE 500000
#define GD 256
#define H1 128
#define H2 128
#define NREL 8
#define NBASES 30
#define XRLD (NREL * H1)   // 1024
#define NCHUNKS ((NN + 1023) / 1024)  // 49

typedef __attribute__((ext_vector_type(8))) short bf16x8;
typedef __attribute__((ext_vector_type(4))) float f32x4;
typedef __attribute__((ext_vector_type(8))) unsigned short u16x8;

__device__ __forceinline__ float lrelu(float x) { return x > 0.f ? x : 0.2f * x; }

__device__ __forceinline__ unsigned short f2bf(float x) {
  union { float f; uint32_t u; } v; v.f = x;
  uint32_t r = v.u + 0x7FFF + ((v.u >> 16) & 1);
  return (unsigned short)(r >> 16);
}
__device__ __forceinline__ float bf2f(unsigned short u) {
  union { uint32_t u; float f; } v; v.u = ((uint32_t)u) << 16;
  return v.f;
}

template <int N>
__device__ __forceinline__ void wait_vmcnt() {
  asm volatile("s_waitcnt vmcnt(%0)" :: "n"(N) : "memory");
}

__device__ __forceinline__ void gload_lds(const unsigned short* gp, unsigned short* lp) {
  __builtin_amdgcn_global_load_lds(
      (const __attribute__((address_space(1))) void*)gp,
      (__attribute__((address_space(3))) void*)lp, 16, 0, 0);
}

// ---- cast nf fp32 -> bf16 ----
__global__ void k_cast(const float* __restrict__ in, unsigned short* __restrict__ out) {
  int i = blockIdx.x * 256 + threadIdx.x;
  const float4* p = (const float4*)(in + (size_t)i * 8);
  float4 a = p[0], b = p[1];
  u16x8 r;
  r[0] = f2bf(a.x); r[1] = f2bf(a.y); r[2] = f2bf(a.z); r[3] = f2bf(a.w);
  r[4] = f2bf(b.x); r[5] = f2bf(b.y); r[6] = f2bf(b.z); r[7] = f2bf(b.w);
  *(u16x8*)(out + (size_t)i * 8) = r;
}

// ---- wrb_t[n][k] bf16 [1024][256] ----
__global__ void k_wr(const float* __restrict__ basis, const float* __restrict__ comp,
                     unsigned short* __restrict__ wrb_t) {
  int idx = blockIdx.x * 256 + threadIdx.x;
  int n = idx >> 8;
  int k = idx & 255;
  int r = n >> 7, o = n & 127;
  float acc = 0.f;
  #pragma unroll
  for (int b = 0; b < NBASES; b++)
    acc += comp[r * NBASES + b] * basis[((size_t)b * GD + k) * H1 + o];
  wrb_t[idx] = f2bf(acc);
}

// ---- fused-B prep ----
__global__ void k_prep(const float* __restrict__ root, const float* __restrict__ w_l,
                       const float* __restrict__ w_r, const float* __restrict__ bias1,
                       unsigned short* __restrict__ btf, float* __restrict__ biasv) {
  int idx = blockIdx.x * 256 + threadIdx.x;   // 98560 total
  if (idx < 32768) {
    int c = idx >> 7, k = idx & 127;
    float v = (c < H2) ? w_l[k * H2 + c] : w_r[k * H2 + (c - H2)];
    btf[c * 384 + k] = f2bf(v);
  } else if (idx < 98304) {
    int j2 = idx - 32768;
    int c = j2 >> 8, g = j2 & 255;
    float acc = 0.f;
    for (int j = 0; j < H1; j++) {
      float w = (c < H2) ? w_l[j * H2 + c] : w_r[j * H2 + (c - H2)];
      acc += root[g * H1 + j] * w;
    }
    btf[c * 384 + 128 + g] = f2bf(acc);
  } else if (idx < 98560) {
    int c = idx - 98304;
    float acc = 0.f;
    for (int j = 0; j < H1; j++) {
      float w = (c < H2) ? w_l[j * H2 + c] : w_r[j * H2 + (c - H2)];
      acc += bias1[j] * w;
    }
    biasv[c] = acc;
  }
}

// ---- xr GEMM: wave tile 64x64 (WM=4), block 128x128, 3-buf BK=32, counted vmcnt ----
template <int K, int WM>
__global__ __launch_bounds__(256, 3)
void k_mgemm(const unsigned short* __restrict__ A, const unsigned short* __restrict__ Bt,
             unsigned short* __restrict__ C, int M, int N, int gx) {
  constexpr int BM = WM * 32;
  constexpr int ACH = BM * 4;
  constexpr int TCH = ACH + 512;
  constexpr int LPT = TCH / 256;
  constexpr int NS = K / 32;
  constexpr int ABUF = BM * 32;
  constexpr int BBUF = 128 * 32;
  extern __shared__ unsigned short lds[];
  const int tid = threadIdx.x;
  const int lane = tid & 63;
  const int wave = tid >> 6;

  const int nwg = gridDim.x;
  const int q = nwg >> 3, r = nwg & 7;
  const int xcd = blockIdx.x & 7, bi = blockIdx.x >> 3;
  const int wg = (xcd < r ? xcd * (q + 1) : r * (q + 1) + (xcd - r) * q) + bi;
  const int bx = wg % gx;
  const int by = wg / gx;
  const int row0 = by * BM;
  const int colb = bx * 128;
  const int wcol = (wave & 1) * 64;
  const int wrow = (wave >> 1) * (WM * 16);
  const int lr = lane & 15;
  const int lko = lane >> 4;

  f32x4 acc[WM][4];
  #pragma unroll
  for (int i = 0; i < WM; i++)
    #pragma unroll
    for (int j = 0; j < 4; j++) acc[i][j] = (f32x4){0.f, 0.f, 0.f, 0.f};

  auto stage = [&](int k0, int b) {
    unsigned short* as = lds + b * ABUF;
    unsigned short* bs = lds + 3 * ABUF + b * BBUF;
    #pragma unroll
    for (int it = 0; it < LPT; it++) {
      int ci = it * 256 + tid;
      if (ci < ACH) {
        int row = ci >> 2, cs = ci & 3;
        int s = (row & 3) ^ ((row >> 2) & 3);
        int gm = row0 + row; if (gm >= M) gm = M - 1;
        gload_lds(A + (size_t)gm * K + k0 + ((cs ^ s) << 3), as + (size_t)ci * 8);
      } else {
        int cj = ci - ACH;
        int row = cj >> 2, cs = cj & 3;
        int s = (row & 3) ^ ((row >> 2) & 3);
        gload_lds(Bt + (size_t)(colb + row) * K + k0 + ((cs ^ s) << 3), bs + (size_t)cj * 8);
      }
    }
  };

  auto compute = [&](int b) {
    const unsigned short* as = lds + b * ABUF;
    const unsigned short* bs = lds + 3 * ABUF + b * BBUF;
    bf16x8 af[WM], bfr[4];
    #pragma unroll
    for (int mb = 0; mb < WM; mb++) {
      int rowL = wrow + mb * 16 + lr;
      int s = (rowL & 3) ^ ((rowL >> 2) & 3);
      af[mb] = *(const bf16x8*)&as[rowL * 32 + ((lko ^ s) << 3)];
    }
    #pragma unroll
    for (int nb = 0; nb < 4; nb++) {
      int colL = wcol + nb * 16 + lr;
      int s = (colL & 3) ^ ((colL >> 2) & 3);
      bfr[nb] = *(const bf16x8*)&bs[colL * 32 + ((lko ^ s) << 3)];
    }
    #pragma unroll
    for (int mb = 0; mb < WM; mb++)
      #pragma unroll
      for (int nb = 0; nb < 4; nb++)
        acc[mb][nb] = __builtin_amdgcn_mfma_f32_16x16x32_bf16(af[mb], bfr[nb], acc[mb][nb], 0, 0, 0);
  };

  stage(0, 0);
  stage(32, 1);
  wait_vmcnt<LPT>();
  __builtin_amdgcn_sched_barrier(0);
  __builtin_amdgcn_s_barrier();
  #pragma unroll
  for (int s = 0; s < NS; s++) {
    if (s + 2 < NS) stage((s + 2) * 32, (s + 2) % 3);
    compute(s % 3);
    if (s + 1 < NS) {
      if (s + 2 < NS) wait_vmcnt<LPT>();
      else            wait_vmcnt<0>();
      __builtin_amdgcn_sched_barrier(0);
      __builtin_amdgcn_s_barrier();
    }
  }

  __syncthreads();
  unsigned short* Cs = lds;                // [BM][128]
  const int orow = lko * 4;
  #pragma unroll
  for (int mb = 0; mb < WM; mb++) {
    #pragma unroll
    for (int i = 0; i < 4; i++) {
      int row = wrow + mb * 16 + orow + i;
      int sw = (row & 7) << 3;
      #pragma unroll
      for (int nb = 0; nb < 4; nb++) {
        int col = wcol + nb * 16 + lr;
        Cs[row * 128 + (col ^ sw)] = f2bf(acc[mb][nb][i]);
      }
    }
  }
  __syncthreads();
  #pragma unroll
  for (int it = 0; it < BM / 16; it++) {
    int off = it * 256 + tid;
    int row = off >> 4, jb = off & 15;
    int grow = row0 + row;
    if (grow < M) {
      int idx = row * 128 + ((jb * 8) ^ ((row & 7) << 3));
      *(u16x8*)&C[(size_t)grow * N + colb + jb * 8] = *(const u16x8*)&Cs[idx];
    }
  }
}

// ---- fused GEMM: [xl|xrt] = [agg|nf] @ btf^T + biasv; SPLIT compact outputs ----
__global__ __launch_bounds__(256, 3)
void k_fused(const unsigned short* __restrict__ A1, const unsigned short* __restrict__ A2,
             const unsigned short* __restrict__ Bt, const float* __restrict__ biasv,
             unsigned short* __restrict__ xl, unsigned short* __restrict__ xrt, int M) {
  constexpr int K = 384, NS = 12, LPT = 4;
  extern __shared__ unsigned short lds[];
  const int tid = threadIdx.x;
  const int lane = tid & 63;
  const int wave = tid >> 6;

  const int nwg = gridDim.x;
  const int q = nwg >> 3, r = nwg & 7;
  const int xcd = blockIdx.x & 7, bi = blockIdx.x >> 3;
  const int wg = (xcd < r ? xcd * (q + 1) : r * (q + 1) + (xcd - r) * q) + bi;
  const int bx = wg & 1;
  const int by = wg >> 1;
  const int row0 = by * 128;
  const int colb = bx * 128;
  const int wcol = (wave & 1) * 64;
  const int wrow = (wave >> 1) * 64;
  const int lr = lane & 15;
  const int lko = lane >> 4;

  f32x4 acc[4][4];
  #pragma unroll
  for (int i = 0; i < 4; i++)
    #pragma unroll
    for (int j = 0; j < 4; j++) acc[i][j] = (f32x4){0.f, 0.f, 0.f, 0.f};

  auto stage = [&](int k0, int b) {
    unsigned short* as = lds + b * 4096;
    unsigned short* bs = lds + 3 * 4096 + b * 4096;
    #pragma unroll
    for (int it = 0; it < LPT; it++) {
      int ci = it * 256 + tid;
      if (ci < 512) {
        int row = ci >> 2, cs = ci & 3;
        int s = (row & 3) ^ ((row >> 2) & 3);
        int gm = row0 + row; if (gm >= M) gm = M - 1;
        const unsigned short* gp;
        if (k0 < 128) gp = A1 + (size_t)gm * 128 + k0 + ((cs ^ s) << 3);
        else          gp = A2 + (size_t)gm * 256 + (k0 - 128) + ((cs ^ s) << 3);
        gload_lds(gp, as + (size_t)ci * 8);
      } else {
        int cj = ci - 512;
        int row = cj >> 2, cs = cj & 3;
        int s = (row & 3) ^ ((row >> 2) & 3);
        gload_lds(Bt + (size_t)(colb + row) * K + k0 + ((cs ^ s) << 3), bs + (size_t)cj * 8);
      }
    }
  };

  auto compute = [&](int b) {
    const unsigned short* as = lds + b * 4096;
    const unsigned short* bs = lds + 3 * 4096 + b * 4096;
    bf16x8 af[4], bfr[4];
    #pragma unroll
    for (int mb = 0; mb < 4; mb++) {
      int rowL = wrow + mb * 16 + lr;
      int s = (rowL & 3) ^ ((rowL >> 2) & 3);
      af[mb] = *(const bf16x8*)&as[rowL * 32 + ((lko ^ s) << 3)];
    }
    #pragma unroll
    for (int nb = 0; nb < 4; nb++) {
      int colL = wcol + nb * 16 + lr;
      int s = (colL & 3) ^ ((colL >> 2) & 3);
      bfr[nb] = *(const bf16x8*)&bs[colL * 32 + ((lko ^ s) << 3)];
    }
    #pragma unroll
    for (int mb = 0; mb < 4; mb++)
      #pragma unroll
      for (int nb = 0; nb < 4; nb++)
        acc[mb][nb] = __builtin_amdgcn_mfma_f32_16x16x32_bf16(af[mb], bfr[nb], acc[mb][nb], 0, 0, 0);
  };

  stage(0, 0);
  stage(32, 1);
  wait_vmcnt<LPT>();
  __builtin_amdgcn_sched_barrier(0);
  __builtin_amdgcn_s_barrier();
  #pragma unroll
  for (int s = 0; s < NS; s++) {
    if (s + 2 < NS) stage((s + 2) * 32, (s + 2) % 3);
    compute(s % 3);
    if (s + 1 < NS) {
      if (s + 2 < NS) wait_vmcnt<LPT>();
      else            wait_vmcnt<0>();
      __builtin_amdgcn_sched_barrier(0);
      __builtin_amdgcn_s_barrier();
    }
  }

  __syncthreads();
  unsigned short* Cs = lds;                // [128][128]
  const int orow = lko * 4;
  #pragma unroll
  for (int mb = 0; mb < 4; mb++) {
    #pragma unroll
    for (int i = 0; i < 4; i++) {
      int row = wrow + mb * 16 + orow + i;
      int sw = (row & 7) << 3;
      #pragma unroll
      for (int nb = 0; nb < 4; nb++) {
        int col = wcol + nb * 16 + lr;
        Cs[row * 128 + (col ^ sw)] = f2bf(acc[mb][nb][i] + biasv[colb + col]);
      }
    }
  }
  __syncthreads();
  unsigned short* Cout = bx ? xrt : xl;    // compact [NN][128] each
  #pragma unroll
  for (int it = 0; it < 8; it++) {
    int off = it * 256 + tid;
    int row = off >> 4, jb = off & 15;
    int grow = row0 + row;
    if (grow < M) {
      int idx = row * 128 + ((jb * 8) ^ ((row & 7) << 3));
      *(u16x8*)&Cout[(size_t)grow * 128 + jb * 8] = *(const u16x8*)&Cs[idx];
    }
  }
}

// ---- per-(dst,rel) counts only (deg derived in scans) ----
__global__ void k_deg(const int* __restrict__ ei, const int* __restrict__ et,
                      int* __restrict__ cnt2) {
  int e = blockIdx.x * 256 + threadIdx.x;
  if (e < NE) atomicAdd(&cnt2[ei[NE + e] * NREL + et[e]], 1);
}

__device__ __forceinline__ int node_deg(const int* cnt2, int n) {
  const int4* p = (const int4*)(cnt2 + n * NREL);
  int4 a = p[0], b = p[1];
  return a.x + a.y + a.z + a.w + b.x + b.y + b.z + b.w;
}

__global__ void k_scan_a(const int* __restrict__ cnt2, int* __restrict__ parts) {
  __shared__ int lds[256];
  int t = threadIdx.x;
  int base = blockIdx.x * 1024 + t * 4;
  int s = 0;
  #pragma unroll
  for (int j = 0; j < 4; j++) s += (base + j < NN) ? node_deg(cnt2, base + j) : 0;
  lds[t] = s;
  __syncthreads();
  for (int st = 128; st > 0; st >>= 1) {
    if (t < st) lds[t] += lds[t + st];
    __syncthreads();
  }
  if (t == 0) parts[blockIdx.x] = lds[0];
}

__global__ void k_scan_b(int* __restrict__ parts) {
  int t = threadIdx.x;   // 64 threads
  int v = (t < NCHUNKS) ? parts[t] : 0;
  int x = v;
  #pragma unroll
  for (int off = 1; off < 64; off <<= 1) {
    int y = __shfl_up(x, off, 64);
    if (t >= off) x += y;
  }
  if (t < NCHUNKS) parts[t] = x - v;
}

__global__ void k_scan_c(const int* __restrict__ cnt2, const int* __restrict__ parts,
                         int* __restrict__ rowptr) {
  __shared__ int lds[256];
  int t = threadIdx.x;
  int base = blockIdx.x * 1024 + t * 4;
  int v[4];
  int s = 0;
  #pragma unroll
  for (int j = 0; j < 4; j++) { v[j] = (base + j < NN) ? node_deg(cnt2, base + j) : 0; s += v[j]; }
  lds[t] = s;
  __syncthreads();
  for (int st = 1; st < 256; st <<= 1) {
    int add = (t >= st) ? lds[t - st] : 0;
    __syncthreads();
    lds[t] += add;
    __syncthreads();
  }
  int excl = lds[t] - s;
  int off = parts[blockIdx.x];
  int run = 0;
  #pragma unroll
  for (int j = 0; j < 4; j++) {
    run += v[j];
    if (base + j < NN) rowptr[base + j + 1] = off + excl + run;
  }
  if (blockIdx.x == 0 && t == 0) rowptr[0] = 0;
}

__global__ void k_scatter(const int* __restrict__ ei, const int* __restrict__ et,
                          const int* __restrict__ rowptr, const int* __restrict__ cnt2,
                          int* __restrict__ cursor, int* __restrict__ csr,
                          float* __restrict__ wgt) {
  int e = blockIdx.x * 256 + threadIdx.x;
  if (e < NE) {
    int d = ei[NE + e];
    int r = et[e];
    int pos = atomicAdd(&cursor[d], 1);
    int slot = rowptr[d] + pos;
    csr[slot] = ei[e] | (r << 20);
    wgt[slot] = 1.0f / (float)cnt2[d * NREL + r];
  }
}

// ---- RGCN aggregation: half-wave per dst, masked batch-8, no serial tail ----
__global__ __launch_bounds__(256)
void k_rgcn(const unsigned short* __restrict__ xr, const int* __restrict__ csr2,
            const float* __restrict__ wgt, const int* __restrict__ rowptr,
            unsigned short* __restrict__ agg) {
  int wpair = (blockIdx.x * 256 + threadIdx.x) >> 6;
  int lane = threadIdx.x & 63;
  int hb = lane & 32;
  int l = lane & 31;
  int wid = wpair * 2 + (hb >> 5);
  if (wid >= NN) return;
  int c0 = l * 4;
  float a0 = 0.f, a1 = 0.f, a2 = 0.f, a3 = 0.f;
  int beg = rowptr[wid], end = rowptr[wid + 1];
  for (int j0 = beg; j0 < end; j0 += 32) {
    int nv = end - j0; if (nv > 32) nv = 32;
    int pk = (l < nv) ? csr2[j0 + l] : 0;
    float wk = (l < nv) ? wgt[j0 + l] : 0.f;
    for (int t = 0; t < nv; t += 8) {
      uint2 wv[8]; float wz[8];
      #pragma unroll
      for (int z = 0; z < 8; z++) {
        int p = __shfl(pk, hb + t + z, 64);
        wz[z] = __shfl(wk, hb + t + z, 64);
        if (t + z < nv) {
          size_t off = (size_t)(p & 0xFFFFF) * XRLD + (p >> 20) * H1 + c0;
          wv[z] = *(const uint2*)(xr + off);
        } else {
          wv[z] = make_uint2(0, 0);
        }
      }
      #pragma unroll
      for (int z = 0; z < 8; z++) {
        a0 += wz[z] * bf2f((unsigned short)(wv[z].x & 0xffff));
        a1 += wz[z] * bf2f((unsigned short)(wv[z].x >> 16));
        a2 += wz[z] * bf2f((unsigned short)(wv[z].y & 0xffff));
        a3 += wz[z] * bf2f((unsigned short)(wv[z].y >> 16));
      }
    }
  }
  uint2 packed;
  packed.x = (uint32_t)f2bf(a0) | ((uint32_t)f2bf(a1) << 16);
  packed.y = (uint32_t)f2bf(a2) | ((uint32_t)f2bf(a3) << 16);
  *(uint2*)&agg[(size_t)wid * H1 + c0] = packed;
}

// ---- GATv2: half-wave per dst, compact xl gathers, masked batch-8 ----
__global__ __launch_bounds__(256)
void k_gat(const unsigned short* __restrict__ xl, const unsigned short* __restrict__ xrt,
           const int* __restrict__ csr2, const int* __restrict__ rowptr,
           const float* __restrict__ att, const float* __restrict__ bias2,
           float* __restrict__ out) {
  int wpair = (blockIdx.x * 256 + threadIdx.x) >> 6;
  int lane = threadIdx.x & 63;
  int hb = lane & 32;
  int l = lane & 31;
  int wid = wpair * 2 + (hb >> 5);
  if (wid >= NN) return;
  int c0 = l * 4;
  float4 at = *(const float4*)(att + c0);
  uint2 wr2 = *(const uint2*)(xrt + (size_t)wid * 128 + c0);
  float xr0 = bf2f((unsigned short)(wr2.x & 0xffff));
  float xr1 = bf2f((unsigned short)(wr2.x >> 16));
  float xr2 = bf2f((unsigned short)(wr2.y & 0xffff));
  float xr3 = bf2f((unsigned short)(wr2.y >> 16));
  uint2 wv0 = *(const uint2*)(xl + (size_t)wid * 128 + c0);
  float v0 = bf2f((unsigned short)(wv0.x & 0xffff));
  float v1 = bf2f((unsigned short)(wv0.x >> 16));
  float v2 = bf2f((unsigned short)(wv0.y & 0xffff));
  float v3 = bf2f((unsigned short)(wv0.y >> 16));
  float ep = lrelu(v0 + xr0) * at.x + lrelu(v1 + xr1) * at.y +
             lrelu(v2 + xr2) * at.z + lrelu(v3 + xr3) * at.w;
  #pragma unroll
  for (int off = 16; off > 0; off >>= 1) ep += __shfl_xor(ep, off, 64);
  float m = ep, s = 1.f, o0 = v0, o1 = v1, o2 = v2, o3 = v3;
  int beg = rowptr[wid], end = rowptr[wid + 1];
  for (int j0 = beg; j0 < end; j0 += 32) {
    int nv = end - j0; if (nv > 32) nv = 32;
    int pk = (l < nv) ? csr2[j0 + l] : 0;
    for (int t = 0; t < nv; t += 8) {
      float u0[8], u1[8], u2[8], u3[8], p[8];
      #pragma unroll
      for (int z = 0; z < 8; z++) {
        int src = __shfl(pk, hb + t + z, 64) & 0xFFFFF;
        uint2 wu;
        if (t + z < nv) wu = *(const uint2*)(xl + (size_t)src * 128 + c0);
        else            wu = make_uint2(0, 0);
        u0[z] = bf2f((unsigned short)(wu.x & 0xffff));
        u1[z] = bf2f((unsigned short)(wu.x >> 16));
        u2[z] = bf2f((unsigned short)(wu.y & 0xffff));
        u3[z] = bf2f((unsigned short)(wu.y >> 16));
      }
      #pragma unroll
      for (int z = 0; z < 8; z++)
        p[z] = lrelu(u0[z] + xr0) * at.x + lrelu(u1[z] + xr1) * at.y +
               lrelu(u2[z] + xr2) * at.z + lrelu(u3[z] + xr3) * at.w;
      #pragma unroll
      for (int off = 16; off > 0; off >>= 1) {
        #pragma unroll
        for (int z = 0; z < 8; z++) p[z] += __shfl_xor(p[z], off, 64);
      }
      #pragma unroll
      for (int z = 0; z < 8; z++) if (t + z >= nv) p[z] = -1e30f;
      float pm = p[0];
      #pragma unroll
      for (int z = 1; z < 8; z++) pm = fmaxf(pm, p[z]);
      float mn = fmaxf(m, pm);
      float sc = __expf(m - mn);
      float e[8];
      #pragma unroll
      for (int z = 0; z < 8; z++) e[z] = __expf(p[z] - mn);
      float es = 0.f, e0 = 0.f, e1 = 0.f, e2 = 0.f, e3 = 0.f;
      #pragma unroll
      for (int z = 0; z < 8; z++) {
        es += e[z]; e0 += e[z] * u0[z]; e1 += e[z] * u1[z];
        e2 += e[z] * u2[z]; e3 += e[z] * u3[z];
      }
      s = s * sc + es;
      o0 = o0 * sc + e0; o1 = o1 * sc + e1;
      o2 = o2 * sc + e2; o3 = o3 * sc + e3;
      m = mn;
    }
  }
  float inv = 1.f / s;
  float4 b2 = *(const float4*)(bias2 + c0);
  float4 res = make_float4(o0 * inv + b2.x, o1 * inv + b2.y,
                           o2 * inv + b2.z, o3 * inv + b2.w);
  *(float4*)&out[(size_t)wid * H1 + c0] = res;
}

extern "C" void kernel_launch(void* const* d_in, const int* in_sizes, int n_in,
                              void* d_out, int out_size, void* d_ws, size_t ws_size,
                              hipStream_t stream) {
  const float* nf    = (const float*)d_in[0];
  const int*   ei    = (const int*)d_in[1];
  const int*   et    = (const int*)d_in[3];
  const float* basis = (const float*)d_in[4];
  const float* comp  = (const float*)d_in[5];
  const float* root  = (const float*)d_in[6];
  const float* bias1 = (const float*)d_in[7];
  const float* w_l   = (const float*)d_in[8];
  const float* w_r   = (const float*)d_in[9];
  const float* att   = (const float*)d_in[10];
  const float* bias2 = (const float*)d_in[11];
  float* out = (float*)d_out;

  char* ws = (char*)d_ws;
  unsigned short* xr_bf  = (unsigned short*)ws;                    // [NN][1024] 102.4 MB
  unsigned short* nf_bf  = (unsigned short*)(ws + 102400000);      // [NN][256]  25.6 MB
  unsigned short* wrb_t  = (unsigned short*)(ws + 128000000);      // [1024][256]
  unsigned short* btf    = (unsigned short*)(ws + 128524288);      // [256][384] bf16
  float*          biasv  = (float*)(ws + 128720896);               // [256]
  unsigned short* agg_bf = (unsigned short*)(ws + 128721920);      // [NN][128] bf16
  int*            cursor = (int*)(ws + 141521920);                 // [NN]
  int*            cnt2   = cursor + NN;                            // [NN*8]
  int*            rowptr = cnt2 + NN * NREL;                       // [NN+1]
  int*            csr    = rowptr + NN + 1;                        // [NE]
  int*            parts  = csr + NE;                               // [64]
  float*          wgt    = (float*)(parts + 64);                   // [NE]
  // overlays into xr region (dead after k_rgcn): compact split outputs
  unsigned short* xl_bf  = (unsigned short*)ws;                    // [NN][128] 12.8 MB
  unsigned short* xrt_bf = (unsigned short*)(ws + 12800000);       // [NN][128] 12.8 MB

  hipMemsetAsync(cursor, 0, (1 + NREL) * NN * sizeof(int), stream);

  k_cast<<<(NN * GD / 8) / 256, 256, 0, stream>>>(nf, nf_bf);
  k_wr<<<(XRLD * GD) / 256, 256, 0, stream>>>(basis, comp, wrb_t);
  k_prep<<<(98560 + 255) / 256, 256, 0, stream>>>(root, w_l, w_r, bias1, btf, biasv);

  const int GY128 = (NN + 127) / 128;   // 391
  k_mgemm<256, 4><<<8 * GY128, 256, 49152, stream>>>(
      nf_bf, wrb_t, xr_bf, NN, XRLD, 8);

  k_deg<<<(NE + 255) / 256, 256, 0, stream>>>(ei, et, cnt2);
  k_scan_a<<<NCHUNKS, 256, 0, stream>>>(cnt2, parts);
  k_scan_b<<<1, 64, 0, stream>>>(parts);
  k_scan_c<<<NCHUNKS, 256, 0, stream>>>(cnt2, parts, rowptr);
  k_scatter<<<(NE + 255) / 256, 256, 0, stream>>>(ei, et, rowptr, cnt2, cursor, csr, wgt);

  k_rgcn<<<(NN + 7) / 8, 256, 0, stream>>>(xr_bf, csr, wgt, rowptr, agg_bf);

  k_fused<<<2 * GY128, 256, 49152, stream>>>(agg_bf, nf_bf, btf, biasv, xl_bf, xrt_bf, NN);

  k_gat<<<(NN + 7) / 8, 256, 0, stream>>>(xl_bf, xrt_bf, csr, rowptr, att, bias2, out);
}